// Round 1
// baseline (375.438 us; speedup 1.0000x reference)
//
#include <hip/hip_runtime.h>
#include <hip/hip_bf16.h>
#include <math.h>

// Problem constants
#define BB 8
#define DD 64
#define N1 16384
#define HWD 128
#define N2 4096
#define NQ 16
#define NH 8
#define DK 8
#define PP 16

// Workspace layout (in floats)
#define OFF_KEY   0L                       // 8,388,608  key [B][N1][64]
#define OFF_KPH   8388608L                 // 2,097,152  kp head-major [B][H][N2][8]
#define OFF_VPH   10485760L                // 2,097,152  vp head-major
#define OFF_LOG   12582912L                // 2,097,152  logits/probs [B][P][N1]
#define OFF_POOL  14680064L                // 512   (zeroed)
#define OFF_PROT  14680576L                // 8192  (zeroed)
#define OFF_GLO   14688768L                // 512
#define OFF_M     14689280L                // 128
#define OFF_Z     14689408L                // 128
#define OFF_QP    14689536L                // 8192
#define OFF_QB    14697728L                // 8192
#define OFF_O     14705920L                // 8192

__device__ __forceinline__ float sigmoidf_(float x) {
    return 1.0f / (1.0f + __expf(-x));
}

// ---------------------------------------------------------------- K1: key = memory + pos
__global__ __launch_bounds__(256) void k_key(const float* __restrict__ mem,
                                             const float* __restrict__ pos,
                                             float* __restrict__ key) {
    long i = (long)blockIdx.x * blockDim.x + threadIdx.x;   // float4 index, total 2,097,152
    int c4 = (int)(i & 15);
    long nb = i >> 4;               // b*16384 + n
    int b = (int)(nb >> 14);
    long n = nb & 16383;
    long src = (n * 8 + b) * 16 + c4;
    float4 m = ((const float4*)mem)[src];
    float4 p = ((const float4*)pos)[src];
    float4 k;
    k.x = m.x + p.x; k.y = m.y + p.y; k.z = m.z + p.z; k.w = m.w + p.w;
    ((float4*)key)[nb * 16 + c4] = k;
}

// ---------------------------------------------------------------- K2: pool1 raw sum (sum of d-pixels)
__global__ __launch_bounds__(256) void k_pool1(const float* __restrict__ key,
                                               float* __restrict__ pool1raw) {
    int b = blockIdx.x >> 6;
    int i = blockIdx.x & 63;
    int g = threadIdx.x >> 6;
    int c = threadIdx.x & 63;
    float s = 0.f;
    for (int j = g; j < 64; j += 4) {
        int n = (2 * i + 1) * 128 + 2 * j + 1;
        s += key[((long)b * N1 + n) * 64 + c];
    }
    __shared__ float red[4][64];
    red[g][c] = s;
    __syncthreads();
    if (g == 0) {
        atomicAdd(&pool1raw[b * 64 + c], red[0][c] + red[1][c] + red[2][c] + red[3][c]);
    }
}

// ---------------------------------------------------------------- K2b: glo1 = MLP(pool1)
__global__ __launch_bounds__(64) void k_glo1(const float* __restrict__ pool1raw,
                                             const float* __restrict__ gw1, const float* __restrict__ gb1,
                                             const float* __restrict__ gw2, const float* __restrict__ gb2,
                                             float* __restrict__ glo1) {
    int b = blockIdx.x;
    int t = threadIdx.x;
    __shared__ float pl[64], hid[64];
    pl[t] = pool1raw[b * 64 + t] * (2.0f / 4096.0f);   // pool of x = 2*d
    __syncthreads();
    float h = gb1[t];
    for (int c = 0; c < 64; c++) h += pl[c] * gw1[t * 64 + c];
    hid[t] = fmaxf(h, 0.f);
    __syncthreads();
    float gl = gb2[t];
    for (int hh = 0; hh < 64; hh++) gl += hid[hh] * gw2[t * 64 + hh];
    glo1[b * 64 + t] = gl;
}

// ---------------------------------------------------------------- K2c: qp = query @ Wq^T + bq ; queryb = tgt+query_pos
__global__ __launch_bounds__(64) void k_qp(const float* __restrict__ tgt,
                                           const float* __restrict__ qpos,
                                           const float* __restrict__ w_in,
                                           const float* __restrict__ b_in,
                                           float* __restrict__ qp,
                                           float* __restrict__ queryb) {
    int b = blockIdx.x >> 4;
    int q = blockIdx.x & 15;
    int k = threadIdx.x;
    __shared__ float qv[64];
    long src = ((long)q * 8 + b) * 64 + k;
    float v = tgt[src] + qpos[src];
    qv[k] = v;
    queryb[(b * 16 + q) * 64 + k] = v;
    __syncthreads();
    float acc = b_in[k];
    for (int c = 0; c < 64; c++) acc += qv[c] * w_in[k * 64 + c];
    qp[(b * 16 + q) * 64 + k] = acc;
}

// ---------------------------------------------------------------- K3: mscw1 + fre + K/V projection
// grid 512 (8 b x 64), 256 threads; each wave handles 4 positions per round, 4 rounds.
__global__ __launch_bounds__(256) void k_mscw1(
        const float* __restrict__ key, const float* __restrict__ glo1,
        const float* __restrict__ lw1, const float* __restrict__ lb1,
        const float* __restrict__ lw2, const float* __restrict__ lb2,
        const float* __restrict__ w_in, const float* __restrict__ b_in,
        float* __restrict__ kph, float* __restrict__ vph) {
    __shared__ float w1T[4096], w2T[4096], wkT[4096], wvT[4096];
    __shared__ float b1s[64], b2s[64], bks[64], bvs[64];
    __shared__ float4 xq[4][64], hq[4][64], fq[4][64];
    int tid = threadIdx.x;
    for (int idx = tid; idx < 4096; idx += 256) {
        int r = idx >> 6, cc = idx & 63;
        w1T[cc * 64 + r] = lw1[idx];
        w2T[cc * 64 + r] = lw2[idx];
        wkT[cc * 64 + r] = w_in[4096 + idx];
        wvT[cc * 64 + r] = w_in[8192 + idx];
    }
    if (tid < 64) {
        b1s[tid] = lb1[tid]; b2s[tid] = lb2[tid];
        bks[tid] = b_in[64 + tid]; bvs[tid] = b_in[128 + tid];
    }
    __syncthreads();
    int w = tid >> 6, c = tid & 63;
    int b = blockIdx.x >> 6;
    const float* kb = key + (long)b * N1 * 64;
    float gl = glo1[b * 64 + c];
    for (int round = 0; round < 4; round++) {
        __syncthreads();
        int n2base = (blockIdx.x & 63) * 64 + round * 16 + w * 4;
        int i = n2base >> 6, j0 = n2base & 63;
        float fa[4], fb[4], fc[4], fd[4];
        #pragma unroll
        for (int p = 0; p < 4; p++) {
            int na = (2 * i) * 128 + 2 * (j0 + p);
            fa[p] = kb[(long)na * 64 + c];
            fb[p] = kb[(long)(na + 1) * 64 + c];
            fc[p] = kb[(long)(na + 128) * 64 + c];
            fd[p] = kb[(long)(na + 129) * 64 + c];
        }
        float4 xv;
        xv.x = 2.f * fd[0]; xv.y = 2.f * fd[1]; xv.z = 2.f * fd[2]; xv.w = 2.f * fd[3];
        xq[w][c] = xv;
        __syncthreads();
        // hidden[h] for 4 positions (lane role h = c)
        float4 acc;
        acc.x = acc.y = acc.z = acc.w = b1s[c];
        for (int cc = 0; cc < 64; cc++) {
            float4 x4 = xq[w][cc];
            float wv = w1T[cc * 64 + c];
            acc.x += x4.x * wv; acc.y += x4.y * wv; acc.z += x4.z * wv; acc.w += x4.w * wv;
        }
        acc.x = fmaxf(acc.x, 0.f); acc.y = fmaxf(acc.y, 0.f);
        acc.z = fmaxf(acc.z, 0.f); acc.w = fmaxf(acc.w, 0.f);
        hq[w][c] = acc;
        __syncthreads();
        // loc[c], wei, fre
        float4 lc;
        lc.x = lc.y = lc.z = lc.w = b2s[c];
        for (int hh = 0; hh < 64; hh++) {
            float4 h4 = hq[w][hh];
            float wv = w2T[hh * 64 + c];
            lc.x += h4.x * wv; lc.y += h4.y * wv; lc.z += h4.z * wv; lc.w += h4.w * wv;
        }
        float lcv[4] = {lc.x, lc.y, lc.z, lc.w};
        float frev[4];
        #pragma unroll
        for (int p = 0; p < 4; p++) {
            float wei = sigmoidf_(lcv[p] + gl);
            float high = 0.5f * (3.f * fd[p] - fa[p] - fb[p] - fc[p]);
            float low  = 0.5f * (fa[p] + fb[p] + fc[p] + fd[p]);
            frev[p] = wei * high + low;
        }
        float4 f4s;
        f4s.x = frev[0]; f4s.y = frev[1]; f4s.z = frev[2]; f4s.w = frev[3];
        fq[w][c] = f4s;
        __syncthreads();
        // K/V projection (lane role k = c)
        float ak[4], av[4];
        #pragma unroll
        for (int p = 0; p < 4; p++) { ak[p] = bks[c]; av[p] = bvs[c]; }
        for (int cc = 0; cc < 64; cc++) {
            float4 f4 = fq[w][cc];
            float wk = wkT[cc * 64 + c];
            float wv2 = wvT[cc * 64 + c];
            ak[0] += f4.x * wk; ak[1] += f4.y * wk; ak[2] += f4.z * wk; ak[3] += f4.w * wk;
            av[0] += f4.x * wv2; av[1] += f4.y * wv2; av[2] += f4.z * wv2; av[3] += f4.w * wv2;
        }
        int hh = c >> 3, d = c & 7;
        long base = ((long)b * NH + hh) * N2;
        #pragma unroll
        for (int p = 0; p < 4; p++) {
            kph[(base + n2base + p) * 8 + d] = ak[p];
            vph[(base + n2base + p) * 8 + d] = av[p];
        }
    }
}

// ---------------------------------------------------------------- K4: dsconv (dw3x3+BN+ReLU, pw+BN+ReLU) + mask logits
// grid 1024 (8 b x 128 rows), 256 threads; wave handles 4 w-positions, 8 rounds.
__global__ __launch_bounds__(256) void k_dsconv(
        const float* __restrict__ key, const float* __restrict__ dw_w,
        const float* __restrict__ bn1_g, const float* __restrict__ bn1_b,
        const float* __restrict__ bn1_m, const float* __restrict__ bn1_v,
        const float* __restrict__ pw_w,
        const float* __restrict__ bn2_g, const float* __restrict__ bn2_b,
        const float* __restrict__ bn2_m, const float* __restrict__ bn2_v,
        const float* __restrict__ mheads, float* __restrict__ logits) {
    __shared__ float pwT[4096];      // [c_in][c_out]
    __shared__ float mhT[1024];      // [c2][p]
    __shared__ float dws[576];       // [k][c]
    __shared__ float s1[64], o1[64], s2[64], o2[64];
    __shared__ float4 y1q[4][64], y2q[4][64];
    int tid = threadIdx.x;
    for (int idx = tid; idx < 4096; idx += 256) {
        int r = idx >> 6, cc = idx & 63;
        pwT[cc * 64 + r] = pw_w[idx];
    }
    for (int idx = tid; idx < 1024; idx += 256) {
        int p = idx >> 6, cc = idx & 63;
        mhT[cc * 16 + p] = mheads[idx];
    }
    for (int idx = tid; idx < 576; idx += 256) {
        int cch = idx / 9, k = idx % 9;
        dws[k * 64 + cch] = dw_w[idx];
    }
    if (tid < 64) {
        float sc = bn1_g[tid] * rsqrtf(bn1_v[tid] + 1e-5f);
        s1[tid] = sc; o1[tid] = bn1_b[tid] - bn1_m[tid] * sc;
        float sc2 = bn2_g[tid] * rsqrtf(bn2_v[tid] + 1e-5f);
        s2[tid] = sc2; o2[tid] = bn2_b[tid] - bn2_m[tid] * sc2;
    }
    __syncthreads();
    int w = tid >> 6, c = tid & 63;
    int b = blockIdx.x >> 7, h = blockIdx.x & 127;
    const float* kb = key + (long)b * N1 * 64;
    for (int round = 0; round < 8; round++) {
        int w0 = round * 16 + w * 4;
        float val[3][6];
        #pragma unroll
        for (int r = 0; r < 3; r++) {
            int hr = h - 1 + r;
            #pragma unroll
            for (int t = 0; t < 6; t++) {
                int wc = w0 - 1 + t;
                val[r][t] = (hr >= 0 && hr < 128 && wc >= 0 && wc < 128)
                            ? kb[((long)hr * 128 + wc) * 64 + c] : 0.f;
            }
        }
        float4 y1;
        float* y1a = (float*)&y1;
        #pragma unroll
        for (int p = 0; p < 4; p++) {
            float a = 0.f;
            #pragma unroll
            for (int r = 0; r < 3; r++)
                #pragma unroll
                for (int kk = 0; kk < 3; kk++)
                    a += val[r][p + kk] * dws[(r * 3 + kk) * 64 + c];
            y1a[p] = fmaxf(a * s1[c] + o1[c], 0.f);
        }
        y1q[w][c] = y1;
        __syncthreads();
        float4 a2;
        a2.x = a2.y = a2.z = a2.w = 0.f;
        for (int cc = 0; cc < 64; cc++) {
            float4 v = y1q[w][cc];
            float pwv = pwT[cc * 64 + c];
            a2.x += v.x * pwv; a2.y += v.y * pwv; a2.z += v.z * pwv; a2.w += v.w * pwv;
        }
        float4 y2;
        y2.x = fmaxf(s2[c] * a2.x + o2[c], 0.f);
        y2.y = fmaxf(s2[c] * a2.y + o2[c], 0.f);
        y2.z = fmaxf(s2[c] * a2.z + o2[c], 0.f);
        y2.w = fmaxf(s2[c] * a2.w + o2[c], 0.f);
        y2q[w][c] = y2;
        __syncthreads();
        if (c < 16) {
            float4 lg;
            lg.x = lg.y = lg.z = lg.w = 0.f;
            for (int cc = 0; cc < 64; cc++) {
                float4 v = y2q[w][cc];
                float mv = mhT[cc * 16 + c];
                lg.x += v.x * mv; lg.y += v.y * mv; lg.z += v.z * mv; lg.w += v.w * mv;
            }
            *((float4*)(logits + (long)(b * 16 + c) * N1 + h * 128 + w0)) = lg;
        }
        __syncthreads();
    }
}

// ---------------------------------------------------------------- K5: column softmax stats (max, sumexp) per (b,p)
__global__ __launch_bounds__(1024) void k_stats(const float* __restrict__ logits,
                                                float* __restrict__ M, float* __restrict__ Z) {
    int row = blockIdx.x;
    const float* L = logits + (long)row * N1;
    int tid = threadIdx.x;
    float m = -1e30f, s = 0.f;
    for (int n = tid; n < N1; n += 1024) {
        float v = L[n];
        if (v > m) { s = s * __expf(m - v) + 1.f; m = v; }
        else s += __expf(v - m);
    }
    for (int off = 32; off; off >>= 1) {
        float om = __shfl_down(m, off);
        float os = __shfl_down(s, off);
        float nm = fmaxf(m, om);
        s = s * __expf(m - nm) + os * __expf(om - nm);
        m = nm;
    }
    __shared__ float sm[16], ss[16];
    if ((tid & 63) == 0) { sm[tid >> 6] = m; ss[tid >> 6] = s; }
    __syncthreads();
    if (tid == 0) {
        float fm = sm[0], fs = ss[0];
        for (int i = 1; i < 16; i++) {
            float nm = fmaxf(fm, sm[i]);
            fs = fs * __expf(fm - nm) + ss[i] * __expf(sm[i] - nm);
            fm = nm;
        }
        M[row] = fm; Z[row] = fs;
    }
}

// ---------------------------------------------------------------- K6: normalize logits -> probs (in place)
__global__ __launch_bounds__(256) void k_norm(float* __restrict__ logits,
                                              const float* __restrict__ M,
                                              const float* __restrict__ Z) {
    long i4 = (long)blockIdx.x * blockDim.x + threadIdx.x;   // total 524,288 float4
    int row = (int)(i4 >> 12);
    float m = M[row], rz = 1.f / Z[row];
    float4 v = ((float4*)logits)[i4];
    v.x = __expf(v.x - m) * rz;
    v.y = __expf(v.y - m) * rz;
    v.z = __expf(v.z - m) * rz;
    v.w = __expf(v.w - m) * rz;
    ((float4*)logits)[i4] = v;
}

// ---------------------------------------------------------------- K7: protos = sum_n probs[b][p][n] * key[b][n][c]
// grid 256 (8 b x 32 chunks of 512 tokens), 256 threads
__global__ __launch_bounds__(256) void k_protos(const float* __restrict__ probs,
                                                const float* __restrict__ key,
                                                float* __restrict__ protos) {
    int b = blockIdx.x >> 5, ch = blockIdx.x & 31;
    int g = threadIdx.x >> 6, c = threadIdx.x & 63;
    __shared__ float4 pl4[2048];     // 16 rows x 512 probs
    float* pl = (float*)pl4;
    const float* P = probs + (long)b * 16 * N1 + ch * 512;
    for (int idx = threadIdx.x; idx < 8192; idx += 256) {
        int p = idx >> 9, n = idx & 511;
        pl[idx] = P[(long)p * N1 + n];
    }
    __syncthreads();
    const float* K = key + ((long)b * N1 + ch * 512) * 64;
    float acc[16];
    #pragma unroll
    for (int p = 0; p < 16; p++) acc[p] = 0.f;
    for (int n0 = g * 4; n0 < 512; n0 += 16) {
        float kv0 = K[(long)n0 * 64 + c];
        float kv1 = K[(long)(n0 + 1) * 64 + c];
        float kv2 = K[(long)(n0 + 2) * 64 + c];
        float kv3 = K[(long)(n0 + 3) * 64 + c];
        int q4 = n0 >> 2;
        #pragma unroll
        for (int p = 0; p < 16; p++) {
            float4 pv = pl4[p * 128 + q4];
            acc[p] += pv.x * kv0 + pv.y * kv1 + pv.z * kv2 + pv.w * kv3;
        }
    }
    __shared__ float red[4][64];
    #pragma unroll
    for (int p = 0; p < 16; p++) {
        __syncthreads();
        red[g][c] = acc[p];
        __syncthreads();
        if (g == 0) atomicAdd(&protos[(b * 16 + p) * 64 + c],
                              red[0][c] + red[1][c] + red[2][c] + red[3][c]);
    }
}

// ---------------------------------------------------------------- K8: MHA flash-decode, one block per (b,h,q)
__global__ __launch_bounds__(256) void k_mha(const float* __restrict__ qp,
                                             const float* __restrict__ kph,
                                             const float* __restrict__ vph,
                                             float* __restrict__ o) {
    int q = blockIdx.x & 15;
    int bh = blockIdx.x >> 4;
    int b = bh >> 3, h = bh & 7;
    const float4* K2 = (const float4*)(kph + (long)bh * N2 * 8);
    const float4* V2 = (const float4*)(vph + (long)bh * N2 * 8);
    const float* qv = qp + (long)(b * 16 + q) * 64 + h * 8;
    float4 q0 = ((const float4*)qv)[0];
    float4 q1 = ((const float4*)qv)[1];
    const float scale = 0.35355339059327373f;   // 1/sqrt(8)
    float m = -1e30f, l = 0.f;
    float acc[8];
    #pragma unroll
    for (int d = 0; d < 8; d++) acc[d] = 0.f;
    for (int n = threadIdx.x; n < N2; n += 256) {
        float4 k0 = K2[n * 2], k1 = K2[n * 2 + 1];
        float s = q0.x * k0.x + q0.y * k0.y + q0.z * k0.z + q0.w * k0.w
                + q1.x * k1.x + q1.y * k1.y + q1.z * k1.z + q1.w * k1.w;
        s *= scale;
        float nm = fmaxf(m, s);
        float corr = __expf(m - nm);
        float wgt = __expf(s - nm);
        l = l * corr + wgt;
        float4 v0 = V2[n * 2], v1 = V2[n * 2 + 1];
        acc[0] = acc[0] * corr + wgt * v0.x;
        acc[1] = acc[1] * corr + wgt * v0.y;
        acc[2] = acc[2] * corr + wgt * v0.z;
        acc[3] = acc[3] * corr + wgt * v0.w;
        acc[4] = acc[4] * corr + wgt * v1.x;
        acc[5] = acc[5] * corr + wgt * v1.y;
        acc[6] = acc[6] * corr + wgt * v1.z;
        acc[7] = acc[7] * corr + wgt * v1.w;
        m = nm;
    }
    for (int off = 32; off; off >>= 1) {
        float om = __shfl_down(m, off);
        float ol = __shfl_down(l, off);
        float oa[8];
        #pragma unroll
        for (int d = 0; d < 8; d++) oa[d] = __shfl_down(acc[d], off);
        float nm = fmaxf(m, om);
        float c1 = __expf(m - nm), c2 = __expf(om - nm);
        l = l * c1 + ol * c2;
        #pragma unroll
        for (int d = 0; d < 8; d++) acc[d] = acc[d] * c1 + oa[d] * c2;
        m = nm;
    }
    __shared__ float red[4][10];
    int wv = threadIdx.x >> 6;
    if ((threadIdx.x & 63) == 0) {
        red[wv][0] = m; red[wv][1] = l;
        #pragma unroll
        for (int d = 0; d < 8; d++) red[wv][2 + d] = acc[d];
    }
    __syncthreads();
    if (threadIdx.x == 0) {
        for (int i = 1; i < 4; i++) {
            float om = red[i][0], ol = red[i][1];
            float nm = fmaxf(m, om);
            float c1 = __expf(m - nm), c2 = __expf(om - nm);
            l = l * c1 + ol * c2;
            #pragma unroll
            for (int d = 0; d < 8; d++) acc[d] = acc[d] * c1 + red[i][2 + d] * c2;
            m = nm;
        }
        float inv = 1.f / l;
        float* op = o + (long)(b * 16 + q) * 64 + h * 8;
        #pragma unroll
        for (int d = 0; d < 8; d++) op[d] = acc[d] * inv;
    }
}

// ---------------------------------------------------------------- K9: epilogue — mscw2, out-proj, both LNs, output
__global__ __launch_bounds__(1024) void k_final(
        const float* __restrict__ queryb, const float* __restrict__ protos,
        const float* __restrict__ o,
        const float* __restrict__ w_out, const float* __restrict__ b_out,
        const float* __restrict__ ln1_g, const float* __restrict__ ln1_b,
        const float* __restrict__ ln2_g, const float* __restrict__ ln2_b,
        const float* __restrict__ lw1, const float* __restrict__ lb1,
        const float* __restrict__ lw2, const float* __restrict__ lb2,
        const float* __restrict__ gw1, const float* __restrict__ gb1,
        const float* __restrict__ gw2, const float* __restrict__ gb2,
        float* __restrict__ out) {
    int b = blockIdx.x;
    int t = threadIdx.x >> 6;   // token (== wave id)
    int c = threadIdx.x & 63;   // channel (== lane)
    __shared__ float xs[16][64], hid[16][64], os[16][64];
    __shared__ float pool[64], hidg[64], glo[64];
    float q = queryb[(long)(b * 16 + t) * 64 + c];
    float xin = protos[(long)(b * 16 + t) * 64 + c] + q;
    xs[t][c] = xin;
    os[t][c] = o[(long)(b * 16 + t) * 64 + c];
    __syncthreads();
    if (threadIdx.x < 64) {
        float s = 0.f;
        for (int tt = 0; tt < 16; tt++) s += xs[tt][threadIdx.x];
        pool[threadIdx.x] = s * (1.f / 16.f);
    }
    __syncthreads();
    if (threadIdx.x < 64) {
        int hh = threadIdx.x;
        float a = gb1[hh];
        for (int cc = 0; cc < 64; cc++) a += pool[cc] * gw1[hh * 64 + cc];
        hidg[hh] = fmaxf(a, 0.f);
    }
    __syncthreads();
    if (threadIdx.x < 64) {
        int ccc = threadIdx.x;
        float a = gb2[ccc];
        for (int hh = 0; hh < 64; hh++) a += hidg[hh] * gw2[ccc * 64 + hh];
        glo[ccc] = a;
    }
    // loc hidden (thread role h = c for token t); xs already synced
    float a = lb1[c];
    for (int cc = 0; cc < 64; cc++) a += xs[t][cc] * lw1[c * 64 + cc];
    hid[t][c] = fmaxf(a, 0.f);
    __syncthreads();   // covers hid and glo writes
    float loc = lb2[c];
    for (int hh = 0; hh < 64; hh++) loc += hid[t][hh] * lw2[c * 64 + hh];
    float attn2 = sigmoidf_(loc + glo[c]);
    float x2p = q * attn2 + q;
    // LN2 (wave == token; reduce over 64 lanes)
    float mu = x2p;
    for (int off = 32; off; off >>= 1) mu += __shfl_down(mu, off);
    mu = __shfl(mu, 0) * (1.f / 64.f);
    float d0 = x2p - mu;
    float vv = d0 * d0;
    for (int off = 32; off; off >>= 1) vv += __shfl_down(vv, off);
    vv = __shfl(vv, 0) * (1.f / 64.f);
    float x2 = d0 * rsqrtf(vv + 1e-5f) * ln2_g[c] + ln2_b[c];
    // x1 = LN1(o @ w_out^T + b_out + q)
    float x1p = b_out[c];
    for (int k = 0; k < 64; k++) x1p += os[t][k] * w_out[c * 64 + k];
    x1p += q;
    float mu1 = x1p;
    for (int off = 32; off; off >>= 1) mu1 += __shfl_down(mu1, off);
    mu1 = __shfl(mu1, 0) * (1.f / 64.f);
    float d1 = x1p - mu1;
    float v1 = d1 * d1;
    for (int off = 32; off; off >>= 1) v1 += __shfl_down(v1, off);
    v1 = __shfl(v1, 0) * (1.f / 64.f);
    float x1 = d1 * rsqrtf(v1 + 1e-5f) * ln1_g[c] + ln1_b[c];
    out[((long)t * 8 + b) * 64 + c] = x1 + x2;   // [NQ][B][C]
}

// ----------------------------------------------------------------
extern "C" void kernel_launch(void* const* d_in, const int* in_sizes, int n_in,
                              void* d_out, int out_size, void* d_ws, size_t ws_size,
                              hipStream_t stream) {
    const float* tgt       = (const float*)d_in[0];
    const float* memory    = (const float*)d_in[1];
    const float* pos       = (const float*)d_in[2];
    const float* query_pos = (const float*)d_in[3];
    const float* w_in      = (const float*)d_in[4];
    const float* b_in      = (const float*)d_in[5];
    const float* w_out     = (const float*)d_in[6];
    const float* b_out     = (const float*)d_in[7];
    const float* ln1_g     = (const float*)d_in[8];
    const float* ln1_b     = (const float*)d_in[9];
    const float* ln2_g     = (const float*)d_in[10];
    const float* ln2_b     = (const float*)d_in[11];
    const float* dw_w      = (const float*)d_in[12];
    const float* bn1_g     = (const float*)d_in[13];
    const float* bn1_b     = (const float*)d_in[14];
    const float* bn1_m     = (const float*)d_in[15];
    const float* bn1_v     = (const float*)d_in[16];
    const float* pw_w      = (const float*)d_in[17];
    const float* bn2_g     = (const float*)d_in[18];
    const float* bn2_b     = (const float*)d_in[19];
    const float* bn2_m     = (const float*)d_in[20];
    const float* bn2_v     = (const float*)d_in[21];
    const float* mheads    = (const float*)d_in[22];
    const float* m1_lw1 = (const float*)d_in[23];
    const float* m1_lb1 = (const float*)d_in[24];
    const float* m1_lw2 = (const float*)d_in[25];
    const float* m1_lb2 = (const float*)d_in[26];
    const float* m1_gw1 = (const float*)d_in[27];
    const float* m1_gb1 = (const float*)d_in[28];
    const float* m1_gw2 = (const float*)d_in[29];
    const float* m1_gb2 = (const float*)d_in[30];
    const float* m2_lw1 = (const float*)d_in[31];
    const float* m2_lb1 = (const float*)d_in[32];
    const float* m2_lw2 = (const float*)d_in[33];
    const float* m2_lb2 = (const float*)d_in[34];
    const float* m2_gw1 = (const float*)d_in[35];
    const float* m2_gb1 = (const float*)d_in[36];
    const float* m2_gw2 = (const float*)d_in[37];
    const float* m2_gb2 = (const float*)d_in[38];

    float* ws = (float*)d_ws;
    float* out = (float*)d_out;

    // zero the atomic accumulation regions (pool1raw + protos, contiguous)
    hipMemsetAsync(ws + OFF_POOL, 0, (512 + 8192) * sizeof(float), stream);

    k_key<<<8192, 256, 0, stream>>>(memory, pos, ws + OFF_KEY);
    k_pool1<<<512, 256, 0, stream>>>(ws + OFF_KEY, ws + OFF_POOL);
    k_glo1<<<8, 64, 0, stream>>>(ws + OFF_POOL, m1_gw1, m1_gb1, m1_gw2, m1_gb2, ws + OFF_GLO);
    k_qp<<<128, 64, 0, stream>>>(tgt, query_pos, w_in, b_in, ws + OFF_QP, ws + OFF_QB);
    k_mscw1<<<512, 256, 0, stream>>>(ws + OFF_KEY, ws + OFF_GLO,
                                     m1_lw1, m1_lb1, m1_lw2, m1_lb2,
                                     w_in, b_in, ws + OFF_KPH, ws + OFF_VPH);
    k_dsconv<<<1024, 256, 0, stream>>>(ws + OFF_KEY, dw_w,
                                       bn1_g, bn1_b, bn1_m, bn1_v, pw_w,
                                       bn2_g, bn2_b, bn2_m, bn2_v,
                                       mheads, ws + OFF_LOG);
    k_stats<<<128, 1024, 0, stream>>>(ws + OFF_LOG, ws + OFF_M, ws + OFF_Z);
    k_norm<<<2048, 256, 0, stream>>>(ws + OFF_LOG, ws + OFF_M, ws + OFF_Z);
    k_protos<<<256, 256, 0, stream>>>(ws + OFF_LOG, ws + OFF_KEY, ws + OFF_PROT);
    k_mha<<<1024, 256, 0, stream>>>(ws + OFF_QP, ws + OFF_KPH, ws + OFF_VPH, ws + OFF_O);
    k_final<<<8, 1024, 0, stream>>>(ws + OFF_QB, ws + OFF_PROT, ws + OFF_O,
                                    w_out, b_out, ln1_g, ln1_b, ln2_g, ln2_b,
                                    m2_lw1, m2_lb1, m2_lw2, m2_lb2,
                                    m2_gw1, m2_gb1, m2_gw2, m2_gb2,
                                    out);
}

// Round 2
// 319.582 us; speedup vs baseline: 1.1748x; 1.1748x over previous
//
#include <hip/hip_runtime.h>
#include <math.h>

// Problem constants
#define N1 16384
#define N2 4096

// Workspace layout (float offsets)
#define OFF_KEYB 0L            // key bf16 [B][N1][64] : 8,388,608 shorts = 4,194,304 floats
#define OFF_KPH  4194304L      // kp fp32 [B][H][N2][8]
#define OFF_VPH  6291456L
#define OFF_LOG  8388608L      // logits fp32 [B][P][N1]
#define OFF_WB   10485760L     // bf16 weights, 21504 shorts
#define OFF_POOL 10502144L     // 512  (zeroed)
#define OFF_PROT 10502656L     // 8192 (zeroed)
#define OFF_ZZ   10510848L     // 128  (zeroed)
#define OFF_GLO  10510976L
#define OFF_QP   10511488L
#define OFF_QB   10519680L
#define OFF_OO   10527872L

typedef __attribute__((ext_vector_type(8))) short bf16x8;
typedef __attribute__((ext_vector_type(4))) float floatx4;

#define MFMA16(a, b, c) __builtin_amdgcn_mfma_f32_16x16x32_bf16(a, b, c, 0, 0, 0)

__device__ __forceinline__ unsigned short f2bf(float f) {
    union { float f; unsigned u; } v; v.f = f;
    unsigned r = v.u + 0x7fffu + ((v.u >> 16) & 1u);
    return (unsigned short)(r >> 16);
}
__device__ __forceinline__ float bf2f(unsigned short s) {
    union { unsigned u; float f; } v; v.u = ((unsigned)s) << 16;
    return v.f;
}
__device__ __forceinline__ float sigmoidf_(float x) { return 1.f / (1.f + __expf(-x)); }
__device__ __forceinline__ bf16x8 ldg8(const unsigned short* p) { return *(const bf16x8*)p; }

// ---------------------------------------------------------------- prep: weights -> bf16
// wb shorts: [0]=lw1(4096) [4096]=lw2 [8192]=wk [12288]=wv [16384]=pw [20480]=mheads(1024)
__global__ __launch_bounds__(256) void k_prep(const float* __restrict__ lw1,
                                              const float* __restrict__ lw2,
                                              const float* __restrict__ w_in,
                                              const float* __restrict__ pw,
                                              const float* __restrict__ mh,
                                              unsigned short* __restrict__ wb) {
    int i = blockIdx.x * 256 + threadIdx.x;   // 21504 total
    float v;
    if (i < 4096) v = lw1[i];
    else if (i < 8192) v = lw2[i - 4096];
    else if (i < 16384) v = w_in[4096 + (i - 8192)];   // rows 64..191 (k then v)
    else if (i < 20480) v = pw[i - 16384];
    else v = mh[i - 20480];
    wb[i] = f2bf(v);
}

// ---------------------------------------------------------------- K1: key = bf16(memory + pos), [b][n][c]
__global__ __launch_bounds__(256) void k_key(const float* __restrict__ mem,
                                             const float* __restrict__ pos,
                                             unsigned short* __restrict__ keyb) {
    long i = (long)blockIdx.x * 256 + threadIdx.x;   // 1,048,576: 8 channels each
    int c8 = (int)(i & 7);
    long nb = i >> 3;                // b*16384 + n
    int b = (int)(nb >> 14);
    long n = nb & 16383;
    long s4 = (n * 8 + b) * 16 + c8 * 2;
    float4 m0 = ((const float4*)mem)[s4], m1 = ((const float4*)mem)[s4 + 1];
    float4 p0 = ((const float4*)pos)[s4], p1 = ((const float4*)pos)[s4 + 1];
    uint4 o;
    o.x = (unsigned)f2bf(m0.x + p0.x) | ((unsigned)f2bf(m0.y + p0.y) << 16);
    o.y = (unsigned)f2bf(m0.z + p0.z) | ((unsigned)f2bf(m0.w + p0.w) << 16);
    o.z = (unsigned)f2bf(m1.x + p1.x) | ((unsigned)f2bf(m1.y + p1.y) << 16);
    o.w = (unsigned)f2bf(m1.z + p1.z) | ((unsigned)f2bf(m1.w + p1.w) << 16);
    ((uint4*)keyb)[i] = o;
}

// ---------------------------------------------------------------- K2: pool1 raw sum of d-pixels
__global__ __launch_bounds__(256) void k_pool1(const unsigned short* __restrict__ keyb,
                                               float* __restrict__ pool1raw) {
    int b = blockIdx.x >> 6;
    int i = blockIdx.x & 63;
    int g = threadIdx.x >> 6;
    int c = threadIdx.x & 63;
    float s = 0.f;
    for (int j = g; j < 64; j += 4) {
        int n = (2 * i + 1) * 128 + 2 * j + 1;
        s += bf2f(keyb[((long)b * N1 + n) * 64 + c]);
    }
    __shared__ float red[4][64];
    red[g][c] = s;
    __syncthreads();
    if (g == 0)
        atomicAdd(&pool1raw[b * 64 + c], red[0][c] + red[1][c] + red[2][c] + red[3][c]);
}

// ---------------------------------------------------------------- K2b: glo1 = MLP(pool1)
__global__ __launch_bounds__(64) void k_glo1(const float* __restrict__ pool1raw,
                                             const float* __restrict__ gw1, const float* __restrict__ gb1,
                                             const float* __restrict__ gw2, const float* __restrict__ gb2,
                                             float* __restrict__ glo1) {
    int b = blockIdx.x;
    int t = threadIdx.x;
    __shared__ float pl[64], hid[64];
    pl[t] = pool1raw[b * 64 + t] * (2.0f / 4096.0f);
    __syncthreads();
    float h = gb1[t];
    for (int c = 0; c < 64; c++) h += pl[c] * gw1[t * 64 + c];
    hid[t] = fmaxf(h, 0.f);
    __syncthreads();
    float gl = gb2[t];
    for (int hh = 0; hh < 64; hh++) gl += hid[hh] * gw2[t * 64 + hh];
    glo1[b * 64 + t] = gl;
}

// ---------------------------------------------------------------- K2c: qp; queryb
__global__ __launch_bounds__(64) void k_qp(const float* __restrict__ tgt,
                                           const float* __restrict__ qpos,
                                           const float* __restrict__ w_in,
                                           const float* __restrict__ b_in,
                                           float* __restrict__ qp,
                                           float* __restrict__ queryb) {
    int b = blockIdx.x >> 4;
    int q = blockIdx.x & 15;
    int k = threadIdx.x;
    __shared__ float qv[64];
    long src = ((long)q * 8 + b) * 64 + k;
    float v = tgt[src] + qpos[src];
    qv[k] = v;
    queryb[(b * 16 + q) * 64 + k] = v;
    __syncthreads();
    float acc = b_in[k];
    for (int c = 0; c < 64; c++) acc += qv[c] * w_in[k * 64 + c];
    qp[(b * 16 + q) * 64 + k] = acc;
}

// ---------------------------------------------------------------- K3: mscw1 + fre + K/V projection (MFMA)
// grid 512 (8 b x 64 tiles of 64 tokens), 256 threads; each wave owns 16 tokens, fully independent.
__global__ __launch_bounds__(256) void k_mscw1(
        const unsigned short* __restrict__ keyb, const float* __restrict__ glo1,
        const float* __restrict__ lb1, const float* __restrict__ lb2,
        const float* __restrict__ b_in, const unsigned short* __restrict__ wb,
        float* __restrict__ kph, float* __restrict__ vph) {
    __shared__ __align__(16) short xbuf[64 * 72];   // x=2d, later fre
    __shared__ __align__(16) short sbuf[64 * 72];   // low
    __shared__ __align__(16) short hbuf[64 * 72];   // hidden
    int tid = threadIdx.x;
    int w = tid >> 6, lane = tid & 63;
    int b = blockIdx.x >> 6, tile = blockIdx.x & 63;
    int m0 = w * 16, n2_0 = tile * 64;
    const unsigned short* kb = keyb + (long)b * N1 * 64;
    // phase 1: build x, S for own 16 rows
    {
        int c = lane;
        #pragma unroll
        for (int it = 0; it < 16; it++) {
            int tok = m0 + it;
            int n2 = n2_0 + tok;
            int i = n2 >> 6, j = n2 & 63;
            long base = ((long)(2 * i) * 128 + 2 * j) * 64 + c;
            float fa = bf2f(kb[base]);
            float fb = bf2f(kb[base + 64]);
            float fc = bf2f(kb[base + 128 * 64]);
            float fd = bf2f(kb[base + 129 * 64]);
            xbuf[tok * 72 + c] = f2bf(2.f * fd);
            sbuf[tok * 72 + c] = f2bf(0.5f * (fa + fb + fc + fd));
        }
    }
    int col = lane & 15, q = lane >> 4;
    const unsigned short* w1b = wb;
    const unsigned short* w2b = wb + 4096;
    const unsigned short* wkb = wb + 8192;
    const unsigned short* wvb = wb + 12288;
    // G1: hid = relu(x @ w1^T + b1)
    {
        bf16x8 a0 = *(const bf16x8*)(xbuf + (m0 + col) * 72 + q * 8);
        bf16x8 a1 = *(const bf16x8*)(xbuf + (m0 + col) * 72 + 32 + q * 8);
        #pragma unroll
        for (int t = 0; t < 4; t++) {
            int n = t * 16 + col;
            float bias = lb1[n];
            floatx4 acc = {bias, bias, bias, bias};
            acc = MFMA16(a0, ldg8(w1b + n * 64 + q * 8), acc);
            acc = MFMA16(a1, ldg8(w1b + n * 64 + 32 + q * 8), acc);
            #pragma unroll
            for (int r = 0; r < 4; r++)
                hbuf[(m0 + q * 4 + r) * 72 + n] = f2bf(fmaxf(acc[r], 0.f));
        }
    }
    // G2: loc = hid @ w2^T + b2 ; fre = wei*x + (1-wei)*S  (high = x - S)
    {
        bf16x8 a0 = *(const bf16x8*)(hbuf + (m0 + col) * 72 + q * 8);
        bf16x8 a1 = *(const bf16x8*)(hbuf + (m0 + col) * 72 + 32 + q * 8);
        #pragma unroll
        for (int t = 0; t < 4; t++) {
            int n = t * 16 + col;
            float bias = lb2[n];
            floatx4 acc = {bias, bias, bias, bias};
            acc = MFMA16(a0, ldg8(w2b + n * 64 + q * 8), acc);
            acc = MFMA16(a1, ldg8(w2b + n * 64 + 32 + q * 8), acc);
            float g = glo1[b * 64 + n];
            #pragma unroll
            for (int r = 0; r < 4; r++) {
                int tok = m0 + q * 4 + r;
                float wei = sigmoidf_(acc[r] + g);
                float xv = bf2f(xbuf[tok * 72 + n]);
                float sv = bf2f(sbuf[tok * 72 + n]);
                xbuf[tok * 72 + n] = f2bf(wei * xv + (1.f - wei) * sv);
            }
        }
    }
    // G3/G4: kp = fre @ wk^T + bk ; vp = fre @ wv^T + bv  -> [b][h][n2][8]
    {
        bf16x8 a0 = *(const bf16x8*)(xbuf + (m0 + col) * 72 + q * 8);
        bf16x8 a1 = *(const bf16x8*)(xbuf + (m0 + col) * 72 + 32 + q * 8);
        #pragma unroll
        for (int t = 0; t < 4; t++) {
            int ko = t * 16 + col;
            float bk = b_in[64 + ko], bv = b_in[128 + ko];
            floatx4 ak = {bk, bk, bk, bk};
            floatx4 av = {bv, bv, bv, bv};
            ak = MFMA16(a0, ldg8(wkb + ko * 64 + q * 8), ak);
            ak = MFMA16(a1, ldg8(wkb + ko * 64 + 32 + q * 8), ak);
            av = MFMA16(a0, ldg8(wvb + ko * 64 + q * 8), av);
            av = MFMA16(a1, ldg8(wvb + ko * 64 + 32 + q * 8), av);
            int hh = ko >> 3, d = ko & 7;
            long basep = ((long)(b * 8 + hh) * 4096) * 8 + d;
            #pragma unroll
            for (int r = 0; r < 4; r++) {
                long n2 = n2_0 + m0 + q * 4 + r;
                kph[basep + n2 * 8] = ak[r];
                vph[basep + n2 * 8] = av[r];
            }
        }
    }
}

// ---------------------------------------------------------------- K4: dsconv (dw3x3+bn+relu, pw MFMA, mhead MFMA) + exp-sum
// grid 1024 (8 b x 128 rows), 512 threads (8 waves); wave owns 16 positions.
__global__ __launch_bounds__(512) void k_dsconv(
        const unsigned short* __restrict__ keyb, const float* __restrict__ dw_w,
        const float* __restrict__ bn1_g, const float* __restrict__ bn1_b,
        const float* __restrict__ bn1_m, const float* __restrict__ bn1_v,
        const float* __restrict__ bn2_g, const float* __restrict__ bn2_b,
        const float* __restrict__ bn2_m, const float* __restrict__ bn2_v,
        const unsigned short* __restrict__ wb,
        float* __restrict__ logits, float* __restrict__ Z) {
    __shared__ __align__(16) short y1buf[128 * 72];
    __shared__ __align__(16) short y2buf[128 * 72];
    __shared__ float lgbuf[128 * 17];
    __shared__ float zred[8][16];
    int tid = threadIdx.x;
    int w = tid >> 6, lane = tid & 63;
    int b = blockIdx.x >> 7, h = blockIdx.x & 127;
    int p0 = w * 16;
    const unsigned short* kb = keyb + (long)b * N1 * 64;
    // dw 3x3 + bn1 + relu
    {
        int c = lane;
        float wt[9];
        #pragma unroll
        for (int k = 0; k < 9; k++) wt[k] = dw_w[c * 9 + k];
        float s1 = bn1_g[c] * rsqrtf(bn1_v[c] + 1e-5f);
        float o1 = bn1_b[c] - bn1_m[c] * s1;
        float v0[18], v1[18], v2[18];
        bool okt = (h > 0), okb = (h < 127);
        #pragma unroll
        for (int t = 0; t < 18; t++) {
            int wc = p0 - 1 + t;
            bool okw = (wc >= 0) && (wc < 128);
            v0[t] = (okt && okw) ? bf2f(kb[((long)(h - 1) * 128 + wc) * 64 + c]) : 0.f;
            v1[t] = (okw)        ? bf2f(kb[((long)h * 128 + wc) * 64 + c]) : 0.f;
            v2[t] = (okb && okw) ? bf2f(kb[((long)(h + 1) * 128 + wc) * 64 + c]) : 0.f;
        }
        #pragma unroll
        for (int p = 0; p < 16; p++) {
            float a = v0[p] * wt[0] + v0[p + 1] * wt[1] + v0[p + 2] * wt[2]
                    + v1[p] * wt[3] + v1[p + 1] * wt[4] + v1[p + 2] * wt[5]
                    + v2[p] * wt[6] + v2[p + 1] * wt[7] + v2[p + 2] * wt[8];
            y1buf[(p0 + p) * 72 + c] = f2bf(fmaxf(a * s1 + o1, 0.f));
        }
    }
    int col = lane & 15, q = lane >> 4;
    // pw GEMM + bn2 + relu
    {
        const unsigned short* pwb = wb + 16384;
        bf16x8 a0 = *(const bf16x8*)(y1buf + (p0 + col) * 72 + q * 8);
        bf16x8 a1 = *(const bf16x8*)(y1buf + (p0 + col) * 72 + 32 + q * 8);
        #pragma unroll
        for (int t = 0; t < 4; t++) {
            int n = t * 16 + col;
            float s2 = bn2_g[n] * rsqrtf(bn2_v[n] + 1e-5f);
            float o2 = bn2_b[n] - bn2_m[n] * s2;
            floatx4 acc = {0.f, 0.f, 0.f, 0.f};
            acc = MFMA16(a0, ldg8(pwb + n * 64 + q * 8), acc);
            acc = MFMA16(a1, ldg8(pwb + n * 64 + 32 + q * 8), acc);
            #pragma unroll
            for (int r = 0; r < 4; r++)
                y2buf[(p0 + q * 4 + r) * 72 + n] = f2bf(fmaxf(acc[r] * s2 + o2, 0.f));
        }
    }
    // mhead GEMM (N=16) + exp partial sums
    {
        const unsigned short* mhb = wb + 20480;
        bf16x8 a0 = *(const bf16x8*)(y2buf + (p0 + col) * 72 + q * 8);
        bf16x8 a1 = *(const bf16x8*)(y2buf + (p0 + col) * 72 + 32 + q * 8);
        floatx4 acc = {0.f, 0.f, 0.f, 0.f};
        acc = MFMA16(a0, ldg8(mhb + col * 64 + q * 8), acc);
        acc = MFMA16(a1, ldg8(mhb + col * 64 + 32 + q * 8), acc);
        float s = 0.f;
        #pragma unroll
        for (int r = 0; r < 4; r++) {
            lgbuf[(p0 + q * 4 + r) * 17 + col] = acc[r];
            s += __expf(acc[r]);
        }
        s += __shfl_xor(s, 16);
        s += __shfl_xor(s, 32);
        if (lane < 16) zred[w][lane] = s;
    }
    __syncthreads();
    // coalesced writeout + Z atomics
    {
        int p = tid >> 5, x4 = tid & 31;
        float4 o;
        o.x = lgbuf[(x4 * 4 + 0) * 17 + p];
        o.y = lgbuf[(x4 * 4 + 1) * 17 + p];
        o.z = lgbuf[(x4 * 4 + 2) * 17 + p];
        o.w = lgbuf[(x4 * 4 + 3) * 17 + p];
        ((float4*)(logits + ((long)(b * 16 + p)) * N1 + h * 128))[x4] = o;
        if (tid < 16) {
            float zt = 0.f;
            #pragma unroll
            for (int ww = 0; ww < 8; ww++) zt += zred[ww][tid];
            atomicAdd(Z + b * 16 + tid, zt);
        }
    }
}

// ---------------------------------------------------------------- K7: protos = sum_n exp(logit)/Z * key
__global__ __launch_bounds__(256) void k_protos(const float* __restrict__ logits,
                                                const float* __restrict__ Z,
                                                const unsigned short* __restrict__ keyb,
                                                float* __restrict__ protos) {
    int b = blockIdx.x >> 5, ch = blockIdx.x & 31;
    int g = threadIdx.x >> 6, c = threadIdx.x & 63;
    __shared__ float4 pl4[2048];     // 16 p x 512 probs
    float* pl = (float*)pl4;
    __shared__ float rzs[16];
    if (threadIdx.x < 16) rzs[threadIdx.x] = 1.f / Z[b * 16 + threadIdx.x];
    __syncthreads();
    const float* L = logits + (long)b * 16 * N1 + ch * 512;
    for (int idx = threadIdx.x; idx < 8192; idx += 256) {
        int p = idx >> 9, n = idx & 511;
        pl[idx] = __expf(L[(long)p * N1 + n]) * rzs[p];
    }
    __syncthreads();
    const unsigned short* K = keyb + ((long)b * N1 + ch * 512) * 64;
    float acc[16];
    #pragma unroll
    for (int p = 0; p < 16; p++) acc[p] = 0.f;
    for (int n0 = g * 4; n0 < 512; n0 += 16) {
        float kv0 = bf2f(K[(long)n0 * 64 + c]);
        float kv1 = bf2f(K[(long)(n0 + 1) * 64 + c]);
        float kv2 = bf2f(K[(long)(n0 + 2) * 64 + c]);
        float kv3 = bf2f(K[(long)(n0 + 3) * 64 + c]);
        int q4 = n0 >> 2;
        #pragma unroll
        for (int p = 0; p < 16; p++) {
            float4 pv = pl4[p * 128 + q4];
            acc[p] += pv.x * kv0 + pv.y * kv1 + pv.z * kv2 + pv.w * kv3;
        }
    }
    __shared__ float red[4][64];
    #pragma unroll
    for (int p = 0; p < 16; p++) {
        __syncthreads();
        red[g][c] = acc[p];
        __syncthreads();
        if (g == 0) atomicAdd(&protos[(b * 16 + p) * 64 + c],
                              red[0][c] + red[1][c] + red[2][c] + red[3][c]);
    }
}

// ---------------------------------------------------------------- K8: MHA flash-decode
__global__ __launch_bounds__(256) void k_mha(const float* __restrict__ qp,
                                             const float* __restrict__ kph,
                                             const float* __restrict__ vph,
                                             float* __restrict__ o) {
    int q = blockIdx.x & 15;
    int bh = blockIdx.x >> 4;
    int b = bh >> 3, h = bh & 7;
    const float4* K2 = (const float4*)(kph + (long)bh * N2 * 8);
    const float4* V2 = (const float4*)(vph + (long)bh * N2 * 8);
    const float* qv = qp + (long)(b * 16 + q) * 64 + h * 8;
    float4 q0 = ((const float4*)qv)[0];
    float4 q1 = ((const float4*)qv)[1];
    const float scale = 0.35355339059327373f;
    float m = -1e30f, l = 0.f;
    float acc[8];
    #pragma unroll
    for (int d = 0; d < 8; d++) acc[d] = 0.f;
    for (int n = threadIdx.x; n < N2; n += 256) {
        float4 k0 = K2[n * 2], k1 = K2[n * 2 + 1];
        float s = q0.x * k0.x + q0.y * k0.y + q0.z * k0.z + q0.w * k0.w
                + q1.x * k1.x + q1.y * k1.y + q1.z * k1.z + q1.w * k1.w;
        s *= scale;
        float nm = fmaxf(m, s);
        float corr = __expf(m - nm);
        float wgt = __expf(s - nm);
        l = l * corr + wgt;
        float4 v0 = V2[n * 2], v1 = V2[n * 2 + 1];
        acc[0] = acc[0] * corr + wgt * v0.x;
        acc[1] = acc[1] * corr + wgt * v0.y;
        acc[2] = acc[2] * corr + wgt * v0.z;
        acc[3] = acc[3] * corr + wgt * v0.w;
        acc[4] = acc[4] * corr + wgt * v1.x;
        acc[5] = acc[5] * corr + wgt * v1.y;
        acc[6] = acc[6] * corr + wgt * v1.z;
        acc[7] = acc[7] * corr + wgt * v1.w;
        m = nm;
    }
    for (int off = 32; off; off >>= 1) {
        float om = __shfl_down(m, off);
        float ol = __shfl_down(l, off);
        float oa[8];
        #pragma unroll
        for (int d = 0; d < 8; d++) oa[d] = __shfl_down(acc[d], off);
        float nm = fmaxf(m, om);
        float c1 = __expf(m - nm), c2 = __expf(om - nm);
        l = l * c1 + ol * c2;
        #pragma unroll
        for (int d = 0; d < 8; d++) acc[d] = acc[d] * c1 + oa[d] * c2;
        m = nm;
    }
    __shared__ float red[4][10];
    int wv = threadIdx.x >> 6;
    if ((threadIdx.x & 63) == 0) {
        red[wv][0] = m; red[wv][1] = l;
        #pragma unroll
        for (int d = 0; d < 8; d++) red[wv][2 + d] = acc[d];
    }
    __syncthreads();
    if (threadIdx.x == 0) {
        for (int i = 1; i < 4; i++) {
            float om = red[i][0], ol = red[i][1];
            float nm = fmaxf(m, om);
            float c1 = __expf(m - nm), c2 = __expf(om - nm);
            l = l * c1 + ol * c2;
            #pragma unroll
            for (int d = 0; d < 8; d++) acc[d] = acc[d] * c1 + red[i][2 + d] * c2;
            m = nm;
        }
        float inv = 1.f / l;
        float* op = o + (long)(b * 16 + q) * 64 + h * 8;
        #pragma unroll
        for (int d = 0; d < 8; d++) op[d] = acc[d] * inv;
    }
}

// ---------------------------------------------------------------- K9: epilogue
__global__ __launch_bounds__(1024) void k_final(
        const float* __restrict__ queryb, const float* __restrict__ protos,
        const float* __restrict__ o,
        const float* __restrict__ w_out, const float* __restrict__ b_out,
        const float* __restrict__ ln1_g, const float* __restrict__ ln1_b,
        const float* __restrict__ ln2_g, const float* __restrict__ ln2_b,
        const float* __restrict__ lw1, const float* __restrict__ lb1,
        const float* __restrict__ lw2, const float* __restrict__ lb2,
        const float* __restrict__ gw1, const float* __restrict__ gb1,
        const float* __restrict__ gw2, const float* __restrict__ gb2,
        float* __restrict__ out) {
    int b = blockIdx.x;
    int t = threadIdx.x >> 6;
    int c = threadIdx.x & 63;
    __shared__ float xs[16][64], hid[16][64], os[16][64];
    __shared__ float pool[64], hidg[64], glo[64];
    float q = queryb[(long)(b * 16 + t) * 64 + c];
    float xin = protos[(long)(b * 16 + t) * 64 + c] + q;
    xs[t][c] = xin;
    os[t][c] = o[(long)(b * 16 + t) * 64 + c];
    __syncthreads();
    if (threadIdx.x < 64) {
        float s = 0.f;
        for (int tt = 0; tt < 16; tt++) s += xs[tt][threadIdx.x];
        pool[threadIdx.x] = s * (1.f / 16.f);
    }
    __syncthreads();
    if (threadIdx.x < 64) {
        int hh = threadIdx.x;
        float a = gb1[hh];
        for (int cc = 0; cc < 64; cc++) a += pool[cc] * gw1[hh * 64 + cc];
        hidg[hh] = fmaxf(a, 0.f);
    }
    __syncthreads();
    if (threadIdx.x < 64) {
        int ccc = threadIdx.x;
        float a = gb2[ccc];
        for (int hh = 0; hh < 64; hh++) a += hidg[hh] * gw2[ccc * 64 + hh];
        glo[ccc] = a;
    }
    float a = lb1[c];
    for (int cc = 0; cc < 64; cc++) a += xs[t][cc] * lw1[c * 64 + cc];
    hid[t][c] = fmaxf(a, 0.f);
    __syncthreads();
    float loc = lb2[c];
    for (int hh = 0; hh < 64; hh++) loc += hid[t][hh] * lw2[c * 64 + hh];
    float attn2 = sigmoidf_(loc + glo[c]);
    float x2p = q * attn2 + q;
    float mu = x2p;
    for (int off = 32; off; off >>= 1) mu += __shfl_down(mu, off);
    mu = __shfl(mu, 0) * (1.f / 64.f);
    float d0 = x2p - mu;
    float vv = d0 * d0;
    for (int off = 32; off; off >>= 1) vv += __shfl_down(vv, off);
    vv = __shfl(vv, 0) * (1.f / 64.f);
    float x2 = d0 * rsqrtf(vv + 1e-5f) * ln2_g[c] + ln2_b[c];
    float x1p = b_out[c];
    for (int k = 0; k < 64; k++) x1p += os[t][k] * w_out[c * 64 + k];
    x1p += q;
    float mu1 = x1p;
    for (int off = 32; off; off >>= 1) mu1 += __shfl_down(mu1, off);
    mu1 = __shfl(mu1, 0) * (1.f / 64.f);
    float d1 = x1p - mu1;
    float v1 = d1 * d1;
    for (int off = 32; off; off >>= 1) v1 += __shfl_down(v1, off);
    v1 = __shfl(v1, 0) * (1.f / 64.f);
    float x1 = d1 * rsqrtf(v1 + 1e-5f) * ln1_g[c] + ln1_b[c];
    out[((long)t * 8 + b) * 64 + c] = x1 + x2;
}

// ----------------------------------------------------------------
extern "C" void kernel_launch(void* const* d_in, const int* in_sizes, int n_in,
                              void* d_out, int out_size, void* d_ws, size_t ws_size,
                              hipStream_t stream) {
    const float* tgt       = (const float*)d_in[0];
    const float* memory    = (const float*)d_in[1];
    const float* pos       = (const float*)d_in[2];
    const float* query_pos = (const float*)d_in[3];
    const float* w_in      = (const float*)d_in[4];
    const float* b_in      = (const float*)d_in[5];
    const float* w_out     = (const float*)d_in[6];
    const float* b_out     = (const float*)d_in[7];
    const float* ln1_g     = (const float*)d_in[8];
    const float* ln1_b     = (const float*)d_in[9];
    const float* ln2_g     = (const float*)d_in[10];
    const float* ln2_b     = (const float*)d_in[11];
    const float* dw_w      = (const float*)d_in[12];
    const float* bn1_g     = (const float*)d_in[13];
    const float* bn1_b     = (const float*)d_in[14];
    const float* bn1_m     = (const float*)d_in[15];
    const float* bn1_v     = (const float*)d_in[16];
    const float* pw_w      = (const float*)d_in[17];
    const float* bn2_g     = (const float*)d_in[18];
    const float* bn2_b     = (const float*)d_in[19];
    const float* bn2_m     = (const float*)d_in[20];
    const float* bn2_v     = (const float*)d_in[21];
    const float* mheads    = (const float*)d_in[22];
    const float* m1_lw1 = (const float*)d_in[23];
    const float* m1_lb1 = (const float*)d_in[24];
    const float* m1_lw2 = (const float*)d_in[25];
    const float* m1_lb2 = (const float*)d_in[26];
    const float* m1_gw1 = (const float*)d_in[27];
    const float* m1_gb1 = (const float*)d_in[28];
    const float* m1_gw2 = (const float*)d_in[29];
    const float* m1_gb2 = (const float*)d_in[30];
    const float* m2_lw1 = (const float*)d_in[31];
    const float* m2_lb1 = (const float*)d_in[32];
    const float* m2_lw2 = (const float*)d_in[33];
    const float* m2_lb2 = (const float*)d_in[34];
    const float* m2_gw1 = (const float*)d_in[35];
    const float* m2_gb1 = (const float*)d_in[36];
    const float* m2_gw2 = (const float*)d_in[37];
    const float* m2_gb2 = (const float*)d_in[38];

    float* ws = (float*)d_ws;
    float* out = (float*)d_out;
    unsigned short* keyb = (unsigned short*)(ws + OFF_KEYB);
    unsigned short* wb   = (unsigned short*)(ws + OFF_WB);

    // zero atomic regions (pool + protos + Z, contiguous)
    hipMemsetAsync(ws + OFF_POOL, 0, 8832 * sizeof(float), stream);

    k_prep<<<84, 256, 0, stream>>>(m1_lw1, m1_lw2, w_in, pw_w, mheads, wb);
    k_key<<<4096, 256, 0, stream>>>(memory, pos, keyb);
    k_pool1<<<512, 256, 0, stream>>>(keyb, ws + OFF_POOL);
    k_glo1<<<8, 64, 0, stream>>>(ws + OFF_POOL, m1_gw1, m1_gb1, m1_gw2, m1_gb2, ws + OFF_GLO);
    k_qp<<<128, 64, 0, stream>>>(tgt, query_pos, w_in, b_in, ws + OFF_QP, ws + OFF_QB);
    k_mscw1<<<512, 256, 0, stream>>>(keyb, ws + OFF_GLO, m1_lb1, m1_lb2, b_in, wb,
                                     ws + OFF_KPH, ws + OFF_VPH);
    k_dsconv<<<1024, 512, 0, stream>>>(keyb, dw_w,
                                       bn1_g, bn1_b, bn1_m, bn1_v,
                                       bn2_g, bn2_b, bn2_m, bn2_v,
                                       wb, ws + OFF_LOG, ws + OFF_ZZ);
    k_protos<<<256, 256, 0, stream>>>(ws + OFF_LOG, ws + OFF_ZZ, keyb, ws + OFF_PROT);
    k_mha<<<1024, 256, 0, stream>>>(ws + OFF_QP, ws + OFF_KPH, ws + OFF_VPH, ws + OFF_OO);
    k_final<<<8, 1024, 0, stream>>>(ws + OFF_QB, ws + OFF_PROT, ws + OFF_OO,
                                    w_out, b_out, ln1_g, ln1_b, ln2_g, ln2_b,
                                    m2_lw1, m2_lb1, m2_lw2, m2_lb2,
                                    m2_gw1, m2_gb1, m2_gw2, m2_gb2,
                                    out);
}

// Round 3
// 318.088 us; speedup vs baseline: 1.1803x; 1.0047x over previous
//
#include <hip/hip_runtime.h>
#include <math.h>

#define N1 16384
#define N2 4096

// Workspace layout (float offsets)
#define OFF_KEY   0L            // key  bf16 [B][N1][64]
#define OFF_KEYT  4194304L      // keyT bf16 [B][64][N1]
#define OFF_KPH   8388608L      // kp bf16 [B*H][4096][8]
#define OFF_VPH   9437184L
#define OFF_PEXP  10485760L     // exp(logits) bf16 [B][16][N1]
#define OFF_WB    11534336L     // bf16 weights (21504 shorts)
#define OFF_CST   11545088L     // fp32 consts: dwTf[576], o1[64], s2[64], o2[64]
#define OFF_POOL  11545856L     // 512  (zeroed)
#define OFF_PROT  11546368L     // 8192 (zeroed)
#define OFF_ZZ    11554560L     // 128  (zeroed)
#define OFF_GLO   11554688L
#define OFF_QP    11555200L
#define OFF_QB    11563392L
#define OFF_PART  11571584L     // [B*H][16 q][4 qtr][12]

typedef __attribute__((ext_vector_type(8))) short bf16x8;
typedef __attribute__((ext_vector_type(4))) float floatx4;

#define MFMA16(a, b, c) __builtin_amdgcn_mfma_f32_16x16x32_bf16(a, b, c, 0, 0, 0)

__device__ __forceinline__ unsigned short f2bf(float f) {
    union { float f; unsigned u; } v; v.f = f;
    unsigned r = v.u + 0x7fffu + ((v.u >> 16) & 1u);
    return (unsigned short)(r >> 16);
}
__device__ __forceinline__ float bf2f(unsigned short s) {
    union { unsigned u; float f; } v; v.u = ((unsigned)s) << 16;
    return v.f;
}
__device__ __forceinline__ float sigmoidf_(float x) { return 1.f / (1.f + __expf(-x)); }
__device__ __forceinline__ bf16x8 ldg8b(const unsigned short* p) { return *(const bf16x8*)p; }
__device__ __forceinline__ void unpack8(uint4 v, float* f) {
    f[0] = bf2f((unsigned short)(v.x & 0xffff)); f[1] = bf2f((unsigned short)(v.x >> 16));
    f[2] = bf2f((unsigned short)(v.y & 0xffff)); f[3] = bf2f((unsigned short)(v.y >> 16));
    f[4] = bf2f((unsigned short)(v.z & 0xffff)); f[5] = bf2f((unsigned short)(v.z >> 16));
    f[6] = bf2f((unsigned short)(v.w & 0xffff)); f[7] = bf2f((unsigned short)(v.w >> 16));
}

// ---------------------------------------------------------------- prep: weights bf16 + folded consts
__global__ __launch_bounds__(256) void k_prep(const float* __restrict__ lw1,
                                              const float* __restrict__ lw2,
                                              const float* __restrict__ w_in,
                                              const float* __restrict__ pw,
                                              const float* __restrict__ mh,
                                              const float* __restrict__ dw_w,
                                              const float* __restrict__ bn1_g, const float* __restrict__ bn1_b,
                                              const float* __restrict__ bn1_m, const float* __restrict__ bn1_v,
                                              const float* __restrict__ bn2_g, const float* __restrict__ bn2_b,
                                              const float* __restrict__ bn2_m, const float* __restrict__ bn2_v,
                                              unsigned short* __restrict__ wb,
                                              float* __restrict__ cst) {
    int i = blockIdx.x * 256 + threadIdx.x;
    if (i < 21504) {
        float v;
        if (i < 4096) v = lw1[i];
        else if (i < 8192) v = lw2[i - 4096];
        else if (i < 16384) v = w_in[4096 + (i - 8192)];
        else if (i < 20480) v = pw[i - 16384];
        else v = mh[i - 20480];
        wb[i] = f2bf(v);
    } else if (i < 22272) {
        int j = i - 21504;
        if (j < 576) {            // dwTf[k][c] = dw[c][k]*s1[c]
            int k = j >> 6, c = j & 63;
            float s1 = bn1_g[c] * rsqrtf(bn1_v[c] + 1e-5f);
            cst[j] = dw_w[c * 9 + k] * s1;
        } else if (j < 640) {     // o1
            int c = j - 576;
            float s1 = bn1_g[c] * rsqrtf(bn1_v[c] + 1e-5f);
            cst[j] = bn1_b[c] - bn1_m[c] * s1;
        } else if (j < 704) {     // s2
            int c = j - 640;
            cst[j] = bn2_g[c] * rsqrtf(bn2_v[c] + 1e-5f);
        } else {                  // o2
            int c = j - 704;
            float s2 = bn2_g[c] * rsqrtf(bn2_v[c] + 1e-5f);
            cst[j] = bn2_b[c] - bn2_m[c] * s2;
        }
    }
}

// ---------------------------------------------------------------- K1: key & keyT (bf16)
__global__ __launch_bounds__(256) void k_key(const float* __restrict__ mem,
                                             const float* __restrict__ pos,
                                             unsigned short* __restrict__ key,
                                             unsigned short* __restrict__ keyT) {
    __shared__ short kt[32 * 512];   // [nl 32][b 8][c 64]
    int t = threadIdx.x;
    long nb0 = (long)blockIdx.x * 64;
    for (int pass = 0; pass < 2; pass++) {
        int nbase = pass * 32;
        for (int k = 0; k < 16; k++) {
            int u = k * 256 + t;
            int f = u * 4;
            int nl = f >> 9, b = (f >> 6) & 7, c = f & 63;
            long src = ((nb0 + nbase + nl) * 8 + b) * 16 + (c >> 2);
            float4 mm = ((const float4*)mem)[src];
            float4 pp = ((const float4*)pos)[src];
            unsigned s0 = f2bf(mm.x + pp.x), s1 = f2bf(mm.y + pp.y);
            unsigned s2 = f2bf(mm.z + pp.z), s3 = f2bf(mm.w + pp.w);
            uint2 o; o.x = s0 | (s1 << 16); o.y = s2 | (s3 << 16);
            ((uint2*)key)[((long)b * 1048576 + (nb0 + nbase + nl) * 64 + c) >> 2] = o;
            *(uint2*)(kt + nl * 512 + b * 64 + c) = o;
        }
        __syncthreads();
        for (int rr = 0; rr < 2; rr++) {
            int row = t * 2 + rr;            // b*64 + c
            long dstu4 = ((long)row * 16384 + nb0 + nbase) >> 3;
            #pragma unroll
            for (int g = 0; g < 4; g++) {
                unsigned a0 = (unsigned short)kt[(g * 8 + 0) * 512 + row];
                unsigned a1 = (unsigned short)kt[(g * 8 + 1) * 512 + row];
                unsigned a2 = (unsigned short)kt[(g * 8 + 2) * 512 + row];
                unsigned a3 = (unsigned short)kt[(g * 8 + 3) * 512 + row];
                unsigned a4 = (unsigned short)kt[(g * 8 + 4) * 512 + row];
                unsigned a5 = (unsigned short)kt[(g * 8 + 5) * 512 + row];
                unsigned a6 = (unsigned short)kt[(g * 8 + 6) * 512 + row];
                unsigned a7 = (unsigned short)kt[(g * 8 + 7) * 512 + row];
                uint4 o;
                o.x = a0 | (a1 << 16); o.y = a2 | (a3 << 16);
                o.z = a4 | (a5 << 16); o.w = a6 | (a7 << 16);
                ((uint4*)keyT)[dstu4 + g] = o;
            }
        }
        __syncthreads();
    }
}

// ---------------------------------------------------------------- K2: pool1 + glo1 MLP (one block per b)
__global__ __launch_bounds__(256) void k_pool_glo(const unsigned short* __restrict__ key,
                                                  const float* __restrict__ gw1, const float* __restrict__ gb1,
                                                  const float* __restrict__ gw2, const float* __restrict__ gb2,
                                                  float* __restrict__ glo1) {
    __shared__ float red[32][64];
    __shared__ float pl[64], hid[64];
    int b = blockIdx.x, t = threadIdx.x;
    int o = t & 7, s = t >> 3;
    float acc[8];
    #pragma unroll
    for (int j = 0; j < 8; j++) acc[j] = 0.f;
    for (int it = 0; it < 128; it++) {
        int p = it * 32 + s;
        int n = (2 * (p >> 6) + 1) * 128 + 2 * (p & 63) + 1;
        uint4 k4 = ((const uint4*)key)[(long)b * 131072 + n * 8 + o];
        float f[8]; unpack8(k4, f);
        #pragma unroll
        for (int j = 0; j < 8; j++) acc[j] += f[j];
    }
    #pragma unroll
    for (int j = 0; j < 8; j++) red[s][o * 8 + j] = acc[j];
    __syncthreads();
    if (t < 64) {
        float ssum = 0.f;
        for (int i = 0; i < 32; i++) ssum += red[i][t];
        pl[t] = ssum * (2.f / 4096.f);
    }
    __syncthreads();
    if (t < 64) {
        float a = gb1[t];
        for (int c = 0; c < 64; c++) a += pl[c] * gw1[t * 64 + c];
        hid[t] = fmaxf(a, 0.f);
    }
    __syncthreads();
    if (t < 64) {
        float g = gb2[t];
        for (int h = 0; h < 64; h++) g += hid[h] * gw2[t * 64 + h];
        glo1[b * 64 + t] = g;
    }
}

// ---------------------------------------------------------------- K2c: qp; queryb
__global__ __launch_bounds__(64) void k_qp(const float* __restrict__ tgt,
                                           const float* __restrict__ qpos,
                                           const float* __restrict__ w_in,
                                           const float* __restrict__ b_in,
                                           float* __restrict__ qp,
                                           float* __restrict__ queryb) {
    int b = blockIdx.x >> 4;
    int q = blockIdx.x & 15;
    int k = threadIdx.x;
    __shared__ float qv[64];
    long src = ((long)q * 8 + b) * 64 + k;
    float v = tgt[src] + qpos[src];
    qv[k] = v;
    queryb[(b * 16 + q) * 64 + k] = v;
    __syncthreads();
    float acc = b_in[k];
    for (int c = 0; c < 64; c++) acc += qv[c] * w_in[k * 64 + c];
    qp[(b * 16 + q) * 64 + k] = acc;
}

// ---------------------------------------------------------------- K3: mscw1 + fre + K/V projection (MFMA, reg A-frags)
__global__ __launch_bounds__(256) void k_mscw1(
        const unsigned short* __restrict__ keyb, const float* __restrict__ glo1,
        const float* __restrict__ lb1, const float* __restrict__ lb2,
        const float* __restrict__ b_in, const unsigned short* __restrict__ wb,
        unsigned short* __restrict__ kph, unsigned short* __restrict__ vph) {
    __shared__ __align__(16) short hbuf[64 * 72];
    __shared__ __align__(16) short wbuf[64 * 72];
    int tid = threadIdx.x;
    int w = tid >> 6, l = tid & 63;
    int b = blockIdx.x >> 6, tile = blockIdx.x & 63;
    int m0 = w * 16;
    int trow = l & 15, oct = l >> 4;
    int n2 = tile * 64 + m0 + trow;
    int i = n2 >> 6, j = n2 & 63;
    const unsigned short* kb = keyb + (long)b * 1048576;
    long base = ((long)(2 * i) * 128 + 2 * j) * 64;
    float x[16], S[16];
    bf16x8 ax[2];
    #pragma unroll
    for (int half = 0; half < 2; half++) {
        int o = oct + half * 4;
        uint4 fa = *(const uint4*)(kb + base + o * 8);
        uint4 fb = *(const uint4*)(kb + base + 64 + o * 8);
        uint4 fc = *(const uint4*)(kb + base + 8192 + o * 8);
        uint4 fd = *(const uint4*)(kb + base + 8256 + o * 8);
        float A[8], B[8], C[8], D[8];
        unpack8(fa, A); unpack8(fb, B); unpack8(fc, C); unpack8(fd, D);
        #pragma unroll
        for (int jj = 0; jj < 8; jj++) {
            float xd = 2.f * D[jj];
            x[half * 8 + jj] = xd;
            S[half * 8 + jj] = 0.5f * (A[jj] + B[jj] + C[jj] + D[jj]);
            ax[half][jj] = (short)f2bf(xd);
        }
    }
    const unsigned short* w1b = wb;
    const unsigned short* w2b = wb + 4096;
    const unsigned short* wkb = wb + 8192;
    const unsigned short* wvb = wb + 12288;
    // G1: hid = relu(x @ w1^T + b1)
    #pragma unroll
    for (int t4 = 0; t4 < 4; t4++) {
        int n = t4 * 16 + trow;
        float bias = lb1[n];
        floatx4 acc = {bias, bias, bias, bias};
        acc = MFMA16(ax[0], ldg8b(w1b + n * 64 + oct * 8), acc);
        acc = MFMA16(ax[1], ldg8b(w1b + n * 64 + 32 + oct * 8), acc);
        #pragma unroll
        for (int r = 0; r < 4; r++)
            hbuf[(m0 + oct * 4 + r) * 72 + n] = (short)f2bf(fmaxf(acc[r], 0.f));
    }
    __syncthreads();
    // G2: wei = sigmoid(hid @ w2^T + b2 + glo)
    {
        bf16x8 ah0 = *(const bf16x8*)(hbuf + (m0 + trow) * 72 + oct * 8);
        bf16x8 ah1 = *(const bf16x8*)(hbuf + (m0 + trow) * 72 + 32 + oct * 8);
        const float* gl = glo1 + b * 64;
        #pragma unroll
        for (int t4 = 0; t4 < 4; t4++) {
            int n = t4 * 16 + trow;
            float bias = lb2[n];
            floatx4 acc = {bias, bias, bias, bias};
            acc = MFMA16(ah0, ldg8b(w2b + n * 64 + oct * 8), acc);
            acc = MFMA16(ah1, ldg8b(w2b + n * 64 + 32 + oct * 8), acc);
            float g = gl[n];
            #pragma unroll
            for (int r = 0; r < 4; r++)
                wbuf[(m0 + oct * 4 + r) * 72 + n] = (short)f2bf(sigmoidf_(acc[r] + g));
        }
    }
    __syncthreads();
    // fre = wei*x + (1-wei)*S, straight into A-frags
    bf16x8 af0, af1;
    {
        bf16x8 w0 = *(const bf16x8*)(wbuf + (m0 + trow) * 72 + oct * 8);
        bf16x8 w1v = *(const bf16x8*)(wbuf + (m0 + trow) * 72 + 32 + oct * 8);
        #pragma unroll
        for (int jj = 0; jj < 8; jj++) {
            float we0 = bf2f((unsigned short)w0[jj]);
            float we1 = bf2f((unsigned short)w1v[jj]);
            af0[jj] = (short)f2bf(we0 * x[jj] + (1.f - we0) * S[jj]);
            af1[jj] = (short)f2bf(we1 * x[8 + jj] + (1.f - we1) * S[8 + jj]);
        }
    }
    __syncthreads();   // before reusing hbuf/wbuf as kbuf/vbuf
    short* kbuf = hbuf; short* vbuf = wbuf;
    #pragma unroll
    for (int t4 = 0; t4 < 4; t4++) {
        int ko = t4 * 16 + trow;
        float bk = b_in[64 + ko], bv = b_in[128 + ko];
        floatx4 ak = {bk, bk, bk, bk};
        floatx4 av = {bv, bv, bv, bv};
        ak = MFMA16(af0, ldg8b(wkb + ko * 64 + oct * 8), ak);
        ak = MFMA16(af1, ldg8b(wkb + ko * 64 + 32 + oct * 8), ak);
        av = MFMA16(af0, ldg8b(wvb + ko * 64 + oct * 8), av);
        av = MFMA16(af1, ldg8b(wvb + ko * 64 + 32 + oct * 8), av);
        #pragma unroll
        for (int r = 0; r < 4; r++) {
            int row = m0 + oct * 4 + r;
            kbuf[row * 72 + ko] = (short)f2bf(ak[r]);
            vbuf[row * 72 + ko] = (short)f2bf(av[r]);
        }
    }
    __syncthreads();
    for (int u = tid; u < 512; u += 256) {
        int h = u >> 6, tok = u & 63;
        uint4 kk = *(const uint4*)(kbuf + tok * 72 + h * 8);
        uint4 vv = *(const uint4*)(vbuf + tok * 72 + h * 8);
        long du = (long)(b * 8 + h) * 4096 + tile * 64 + tok;
        ((uint4*)kph)[du] = kk;
        ((uint4*)vph)[du] = vv;
    }
}

// ---------------------------------------------------------------- K4: dsconv + mask head -> pexp bf16 + Z
__global__ __launch_bounds__(512) void k_dsconv(
        const unsigned short* __restrict__ keyb,
        const unsigned short* __restrict__ wb,
        const float* __restrict__ cst,
        unsigned short* __restrict__ pexp, float* __restrict__ Z) {
    __shared__ __align__(16) short y2buf[128 * 72];
    __shared__ __align__(16) short pbuf[16 * 136];
    __shared__ float zred[8][16];
    int tid = threadIdx.x;
    int w = tid >> 6, l = tid & 63;
    int b = blockIdx.x >> 7, h = blockIdx.x & 127;
    int p0 = w * 16, pr = l & 15, oct = l >> 4;
    int pos = p0 + pr;
    const unsigned short* kb = keyb + (long)b * 1048576;
    const float* dwt = cst;
    const float* o1c = cst + 576;
    const float* s2c = cst + 640;
    const float* o2c = cst + 704;
    bf16x8 af[2];
    #pragma unroll
    for (int half = 0; half < 2; half++) {
        int o = oct + half * 4;
        float acc[8];
        #pragma unroll
        for (int jj = 0; jj < 8; jj++) acc[jj] = 0.f;
        #pragma unroll
        for (int r = 0; r < 3; r++) {
            int row = h - 1 + r;
            bool rok = (row >= 0) && (row < 128);
            #pragma unroll
            for (int kk = 0; kk < 3; kk++) {
                int col = pos - 1 + kk;
                bool ok = rok && (col >= 0) && (col < 128);
                uint4 px = {0u, 0u, 0u, 0u};
                if (ok) px = *(const uint4*)(kb + ((long)row * 128 + col) * 64 + o * 8);
                float4 wa = *(const float4*)(dwt + (r * 3 + kk) * 64 + o * 8);
                float4 wc = *(const float4*)(dwt + (r * 3 + kk) * 64 + o * 8 + 4);
                float f[8]; unpack8(px, f);
                acc[0] += f[0] * wa.x; acc[1] += f[1] * wa.y;
                acc[2] += f[2] * wa.z; acc[3] += f[3] * wa.w;
                acc[4] += f[4] * wc.x; acc[5] += f[5] * wc.y;
                acc[6] += f[6] * wc.z; acc[7] += f[7] * wc.w;
            }
        }
        float4 oa = *(const float4*)(o1c + o * 8);
        float4 ob = *(const float4*)(o1c + o * 8 + 4);
        acc[0] = fmaxf(acc[0] + oa.x, 0.f); acc[1] = fmaxf(acc[1] + oa.y, 0.f);
        acc[2] = fmaxf(acc[2] + oa.z, 0.f); acc[3] = fmaxf(acc[3] + oa.w, 0.f);
        acc[4] = fmaxf(acc[4] + ob.x, 0.f); acc[5] = fmaxf(acc[5] + ob.y, 0.f);
        acc[6] = fmaxf(acc[6] + ob.z, 0.f); acc[7] = fmaxf(acc[7] + ob.w, 0.f);
        #pragma unroll
        for (int jj = 0; jj < 8; jj++) af[half][jj] = (short)f2bf(acc[jj]);
    }
    // pw GEMM + bn2 + relu
    const unsigned short* pwb = wb + 16384;
    #pragma unroll
    for (int t4 = 0; t4 < 4; t4++) {
        int n = t4 * 16 + pr;
        floatx4 acc = {0.f, 0.f, 0.f, 0.f};
        acc = MFMA16(af[0], ldg8b(pwb + n * 64 + oct * 8), acc);
        acc = MFMA16(af[1], ldg8b(pwb + n * 64 + 32 + oct * 8), acc);
        float s2 = s2c[n], o2 = o2c[n];
        #pragma unroll
        for (int r = 0; r < 4; r++)
            y2buf[(p0 + oct * 4 + r) * 72 + n] = (short)f2bf(fmaxf(acc[r] * s2 + o2, 0.f));
    }
    __syncthreads();
    // mask head + exp
    {
        const unsigned short* mhb = wb + 20480;
        bf16x8 a0 = *(const bf16x8*)(y2buf + (p0 + pr) * 72 + oct * 8);
        bf16x8 a1 = *(const bf16x8*)(y2buf + (p0 + pr) * 72 + 32 + oct * 8);
        floatx4 lg = {0.f, 0.f, 0.f, 0.f};
        lg = MFMA16(a0, ldg8b(mhb + pr * 64 + oct * 8), lg);
        lg = MFMA16(a1, ldg8b(mhb + pr * 64 + 32 + oct * 8), lg);
        float zs = 0.f;
        #pragma unroll
        for (int r = 0; r < 4; r++) {
            float e = __expf(lg[r]);
            zs += e;
            pbuf[pr * 136 + p0 + oct * 4 + r] = (short)f2bf(e);
        }
        zs += __shfl_xor(zs, 16);
        zs += __shfl_xor(zs, 32);
        if (l < 16) zred[w][l] = zs;
    }
    __syncthreads();
    if (tid < 256) {
        int p = tid >> 4, ch = tid & 15;
        uint4 o = *(const uint4*)(pbuf + p * 136 + ch * 8);
        ((uint4*)pexp)[((long)(b * 16 + p) * 16384 + h * 128 + ch * 8) >> 3] = o;
    }
    if (tid < 16) {
        float zt = 0.f;
        #pragma unroll
        for (int ww = 0; ww < 8; ww++) zt += zred[ww][tid];
        atomicAdd(Z + b * 16 + tid, zt);
    }
}

// ---------------------------------------------------------------- K5: protos = pexp @ key (MFMA over keyT)
__global__ __launch_bounds__(256) void k_protos(const unsigned short* __restrict__ pexp,
                                                const unsigned short* __restrict__ keyT,
                                                float* __restrict__ protos) {
    int b = blockIdx.x >> 4, ch = blockIdx.x & 15;
    int tid = threadIdx.x;
    int w = tid >> 6, l = tid & 63;
    int col = l & 15, oct = l >> 4;
    long abase = (long)b * 262144 + (long)col * 16384 + ch * 1024 + oct * 8;
    long bbase = (long)b * 1048576 + (long)(w * 16 + col) * 16384 + ch * 1024 + oct * 8;
    floatx4 acc = {0.f, 0.f, 0.f, 0.f};
    for (int it = 0; it < 32; it++) {
        bf16x8 A = *(const bf16x8*)(pexp + abase + it * 32);
        bf16x8 B = *(const bf16x8*)(keyT + bbase + it * 32);
        acc = MFMA16(A, B, acc);
    }
    int c = w * 16 + col;
    #pragma unroll
    for (int r = 0; r < 4; r++)
        atomicAdd(protos + (b * 16 + oct * 4 + r) * 64 + c, acc[r]);
}

// ---------------------------------------------------------------- K6: MHA flash-decode partials (b,h,quarter)
__global__ __launch_bounds__(256) void k_mha(const float* __restrict__ qp,
                                             const unsigned short* __restrict__ kph,
                                             const unsigned short* __restrict__ vph,
                                             float* __restrict__ part) {
    int bh = blockIdx.x >> 2, qtr = blockIdx.x & 3;
    int b = bh >> 3, hh = bh & 7;
    int tid = threadIdx.x;
    int q = tid >> 4, sub = tid & 15;
    const float* qv = qp + (long)(b * 16 + q) * 64 + hh * 8;
    float4 q0 = ((const float4*)qv)[0];
    float4 q1 = ((const float4*)qv)[1];
    const uint4* K4 = (const uint4*)kph + (long)bh * 4096;
    const uint4* V4 = (const uint4*)vph + (long)bh * 4096;
    const float scale = 0.35355339059327373f;
    float m = -1e30f, lsum = 0.f;
    float acc[8];
    #pragma unroll
    for (int d = 0; d < 8; d++) acc[d] = 0.f;
    for (int i = 0; i < 64; i++) {
        int n = qtr * 1024 + i * 16 + sub;
        float k8[8]; unpack8(K4[n], k8);
        float s = q0.x * k8[0] + q0.y * k8[1] + q0.z * k8[2] + q0.w * k8[3]
                + q1.x * k8[4] + q1.y * k8[5] + q1.z * k8[6] + q1.w * k8[7];
        s *= scale;
        float nm = fmaxf(m, s);
        float corr = __expf(m - nm);
        float wgt = __expf(s - nm);
        lsum = lsum * corr + wgt;
        float v8[8]; unpack8(V4[n], v8);
        #pragma unroll
        for (int d = 0; d < 8; d++) acc[d] = acc[d] * corr + wgt * v8[d];
        m = nm;
    }
    #pragma unroll
    for (int off = 1; off < 16; off <<= 1) {
        float om = __shfl_xor(m, off);
        float ol = __shfl_xor(lsum, off);
        float oa[8];
        #pragma unroll
        for (int d = 0; d < 8; d++) oa[d] = __shfl_xor(acc[d], off);
        float nm = fmaxf(m, om);
        float c1 = __expf(m - nm), c2 = __expf(om - nm);
        lsum = lsum * c1 + ol * c2;
        #pragma unroll
        for (int d = 0; d < 8; d++) acc[d] = acc[d] * c1 + oa[d] * c2;
        m = nm;
    }
    if (sub == 0) {
        float* P = part + ((long)(bh * 16 + q) * 4 + qtr) * 12;
        P[0] = m; P[1] = lsum;
        #pragma unroll
        for (int d = 0; d < 8; d++) P[2 + d] = acc[d];
    }
}

// ---------------------------------------------------------------- K7: epilogue — merge MHA, mscw2, LNs
__global__ __launch_bounds__(1024) void k_final(
        const float* __restrict__ queryb, const float* __restrict__ protos,
        const float* __restrict__ Z, const float* __restrict__ part,
        const float* __restrict__ w_out, const float* __restrict__ b_out,
        const float* __restrict__ ln1_g, const float* __restrict__ ln1_b,
        const float* __restrict__ ln2_g, const float* __restrict__ ln2_b,
        const float* __restrict__ lw1, const float* __restrict__ lb1,
        const float* __restrict__ lw2, const float* __restrict__ lb2,
        const float* __restrict__ gw1, const float* __restrict__ gb1,
        const float* __restrict__ gw2, const float* __restrict__ gb2,
        float* __restrict__ out) {
    int b = blockIdx.x;
    int t = threadIdx.x >> 6;
    int c = threadIdx.x & 63;
    __shared__ float xs[16][64], hid[16][64], os[16][64];
    __shared__ float pool[64], hidg[64], glo[64];
    float q = queryb[(long)(b * 16 + t) * 64 + c];
    float rz = 1.f / Z[b * 16 + t];
    float xin = protos[(long)(b * 16 + t) * 64 + c] * rz + q;
    xs[t][c] = xin;
    // merge MHA partials
    {
        int hh = c >> 3, d = c & 7;
        const float* P = part + ((long)((b * 8 + hh) * 16 + t) * 4) * 12;
        float mm = -1e30f, ll = 0.f, aa = 0.f;
        #pragma unroll
        for (int qtr = 0; qtr < 4; qtr++) {
            float pm = P[qtr * 12], pl2 = P[qtr * 12 + 1], pa = P[qtr * 12 + 2 + d];
            float nm = fmaxf(mm, pm);
            float c1 = __expf(mm - nm), c2 = __expf(pm - nm);
            aa = aa * c1 + pa * c2;
            ll = ll * c1 + pl2 * c2;
            mm = nm;
        }
        os[t][c] = aa / ll;
    }
    __syncthreads();
    if (threadIdx.x < 64) {
        float s = 0.f;
        for (int tt = 0; tt < 16; tt++) s += xs[tt][threadIdx.x];
        pool[threadIdx.x] = s * (1.f / 16.f);
    }
    __syncthreads();
    if (threadIdx.x < 64) {
        int hh = threadIdx.x;
        float a = gb1[hh];
        for (int cc = 0; cc < 64; cc++) a += pool[cc] * gw1[hh * 64 + cc];
        hidg[hh] = fmaxf(a, 0.f);
    }
    __syncthreads();
    if (threadIdx.x < 64) {
        int ccc = threadIdx.x;
        float a = gb2[ccc];
        for (int hh = 0; hh < 64; hh++) a += hidg[hh] * gw2[ccc * 64 + hh];
        glo[ccc] = a;
    }
    float a = lb1[c];
    for (int cc = 0; cc < 64; cc++) a += xs[t][cc] * lw1[c * 64 + cc];
    hid[t][c] = fmaxf(a, 0.f);
    __syncthreads();
    float loc = lb2[c];
    for (int hh = 0; hh < 64; hh++) loc += hid[t][hh] * lw2[c * 64 + hh];
    float attn2 = sigmoidf_(loc + glo[c]);
    float x2p = q * attn2 + q;
    float mu = x2p;
    for (int off = 32; off; off >>= 1) mu += __shfl_down(mu, off);
    mu = __shfl(mu, 0) * (1.f / 64.f);
    float d0 = x2p - mu;
    float vv = d0 * d0;
    for (int off = 32; off; off >>= 1) vv += __shfl_down(vv, off);
    vv = __shfl(vv, 0) * (1.f / 64.f);
    float x2 = d0 * rsqrtf(vv + 1e-5f) * ln2_g[c] + ln2_b[c];
    float x1p = b_out[c];
    for (int k = 0; k < 64; k++) x1p += os[t][k] * w_out[c * 64 + k];
    x1p += q;
    float mu1 = x1p;
    for (int off = 32; off; off >>= 1) mu1 += __shfl_down(mu1, off);
    mu1 = __shfl(mu1, 0) * (1.f / 64.f);
    float d1 = x1p - mu1;
    float v1 = d1 * d1;
    for (int off = 32; off; off >>= 1) v1 += __shfl_down(v1, off);
    v1 = __shfl(v1, 0) * (1.f / 64.f);
    float x1 = d1 * rsqrtf(v1 + 1e-5f) * ln1_g[c] + ln1_b[c];
    out[((long)t * 8 + b) * 64 + c] = x1 + x2;
}

// ----------------------------------------------------------------
extern "C" void kernel_launch(void* const* d_in, const int* in_sizes, int n_in,
                              void* d_out, int out_size, void* d_ws, size_t ws_size,
                              hipStream_t stream) {
    const float* tgt       = (const float*)d_in[0];
    const float* memory    = (const float*)d_in[1];
    const float* pos       = (const float*)d_in[2];
    const float* query_pos = (const float*)d_in[3];
    const float* w_in      = (const float*)d_in[4];
    const float* b_in      = (const float*)d_in[5];
    const float* w_out     = (const float*)d_in[6];
    const float* b_out     = (const float*)d_in[7];
    const float* ln1_g     = (const float*)d_in[8];
    const float* ln1_b     = (const float*)d_in[9];
    const float* ln2_g     = (const float*)d_in[10];
    const float* ln2_b     = (const float*)d_in[11];
    const float* dw_w      = (const float*)d_in[12];
    const float* bn1_g     = (const float*)d_in[13];
    const float* bn1_b     = (const float*)d_in[14];
    const float* bn1_m     = (const float*)d_in[15];
    const float* bn1_v     = (const float*)d_in[16];
    const float* pw_w      = (const float*)d_in[17];
    const float* bn2_g     = (const float*)d_in[18];
    const float* bn2_b     = (const float*)d_in[19];
    const float* bn2_m     = (const float*)d_in[20];
    const float* bn2_v     = (const float*)d_in[21];
    const float* mheads    = (const float*)d_in[22];
    const float* m1_lw1 = (const float*)d_in[23];
    const float* m1_lb1 = (const float*)d_in[24];
    const float* m1_lw2 = (const float*)d_in[25];
    const float* m1_lb2 = (const float*)d_in[26];
    const float* m1_gw1 = (const float*)d_in[27];
    const float* m1_gb1 = (const float*)d_in[28];
    const float* m1_gw2 = (const float*)d_in[29];
    const float* m1_gb2 = (const float*)d_in[30];
    const float* m2_lw1 = (const float*)d_in[31];
    const float* m2_lb1 = (const float*)d_in[32];
    const float* m2_lw2 = (const float*)d_in[33];
    const float* m2_lb2 = (const float*)d_in[34];
    const float* m2_gw1 = (const float*)d_in[35];
    const float* m2_gb1 = (const float*)d_in[36];
    const float* m2_gw2 = (const float*)d_in[37];
    const float* m2_gb2 = (const float*)d_in[38];

    float* ws = (float*)d_ws;
    float* out = (float*)d_out;
    unsigned short* keyb = (unsigned short*)(ws + OFF_KEY);
    unsigned short* keyT = (unsigned short*)(ws + OFF_KEYT);
    unsigned short* kph  = (unsigned short*)(ws + OFF_KPH);
    unsigned short* vph  = (unsigned short*)(ws + OFF_VPH);
    unsigned short* pexp = (unsigned short*)(ws + OFF_PEXP);
    unsigned short* wb   = (unsigned short*)(ws + OFF_WB);

    // zero atomic regions (pool + protos + Z, contiguous)
    hipMemsetAsync(ws + OFF_POOL, 0, 8832 * sizeof(float), stream);

    k_prep<<<88, 256, 0, stream>>>(m1_lw1, m1_lw2, w_in, pw_w, mheads, dw_w,
                                   bn1_g, bn1_b, bn1_m, bn1_v,
                                   bn2_g, bn2_b, bn2_m, bn2_v,
                                   wb, ws + OFF_CST);
    k_key<<<256, 256, 0, stream>>>(memory, pos, keyb, keyT);
    k_qp<<<128, 64, 0, stream>>>(tgt, query_pos, w_in, b_in, ws + OFF_QP, ws + OFF_QB);
    k_pool_glo<<<8, 256, 0, stream>>>(keyb, m1_gw1, m1_gb1, m1_gw2, m1_gb2, ws + OFF_GLO);
    k_mscw1<<<512, 256, 0, stream>>>(keyb, ws + OFF_GLO, m1_lb1, m1_lb2, b_in, wb, kph, vph);
    k_dsconv<<<1024, 512, 0, stream>>>(keyb, wb, ws + OFF_CST, pexp, ws + OFF_ZZ);
    k_protos<<<128, 256, 0, stream>>>(pexp, keyT, ws + OFF_PROT);
    k_mha<<<256, 256, 0, stream>>>(ws + OFF_QP, kph, vph, ws + OFF_PART);
    k_final<<<8, 1024, 0, stream>>>(ws + OFF_QB, ws + OFF_PROT, ws + OFF_ZZ, ws + OFF_PART,
                                    w_out, b_out, ln1_g, ln1_b, ln2_g, ln2_b,
                                    m2_lw1, m2_lb1, m2_lw2, m2_lb2,
                                    m2_gw1, m2_gb1, m2_gw2, m2_gb2,
                                    out);
}

// Round 4
// 267.351 us; speedup vs baseline: 1.4043x; 1.1898x over previous
//
#include <hip/hip_runtime.h>
#include <math.h>

#define N1 16384
#define N2 4096

// Workspace layout (float offsets)
#define OFF_KEY   0L            // key bf16 [B][N1][64] = 8,388,608 shorts
#define OFF_KPH   4194304L      // kp bf16 [B*H][4096][8]
#define OFF_VPH   5242880L
#define OFF_PEXP  6291456L      // exp(logits) bf16 [B][16][N1]
#define OFF_WB    7340032L      // bf16 weights (21504 shorts)
#define OFF_CST   7350784L      // fp32 consts: dwTf[576], o1[64], s2[64], o2[64]
#define OFF_POOL  7351552L      // 512  (zeroed)
#define OFF_PROT  7352064L      // 8192 (zeroed)
#define OFF_ZZ    7360256L      // 128  (zeroed)
#define OFF_GLO   7360384L
#define OFF_QP    7360896L
#define OFF_QB    7369088L
#define OFF_PART  7377280L      // [B*H][16 q][8 seg][12]

typedef __attribute__((ext_vector_type(8))) short bf16x8;
typedef __attribute__((ext_vector_type(4))) float floatx4;

#define MFMA16(a, b, c) __builtin_amdgcn_mfma_f32_16x16x32_bf16(a, b, c, 0, 0, 0)

__device__ __forceinline__ unsigned short f2bf(float f) {
    union { float f; unsigned u; } v; v.f = f;
    unsigned r = v.u + 0x7fffu + ((v.u >> 16) & 1u);
    return (unsigned short)(r >> 16);
}
__device__ __forceinline__ float bf2f(unsigned short s) {
    union { unsigned u; float f; } v; v.u = ((unsigned)s) << 16;
    return v.f;
}
__device__ __forceinline__ float sigmoidf_(float x) { return 1.f / (1.f + __expf(-x)); }
__device__ __forceinline__ bf16x8 ldg8b(const unsigned short* p) { return *(const bf16x8*)p; }
__device__ __forceinline__ void unpack8(uint4 v, float* f) {
    f[0] = bf2f((unsigned short)(v.x & 0xffff)); f[1] = bf2f((unsigned short)(v.x >> 16));
    f[2] = bf2f((unsigned short)(v.y & 0xffff)); f[3] = bf2f((unsigned short)(v.y >> 16));
    f[4] = bf2f((unsigned short)(v.z & 0xffff)); f[5] = bf2f((unsigned short)(v.z >> 16));
    f[6] = bf2f((unsigned short)(v.w & 0xffff)); f[7] = bf2f((unsigned short)(v.w >> 16));
}

// ---------------------------------------------------------------- prep: weights bf16 + folded consts
__global__ __launch_bounds__(256) void k_prep(const float* __restrict__ lw1,
                                              const float* __restrict__ lw2,
                                              const float* __restrict__ w_in,
                                              const float* __restrict__ pw,
                                              const float* __restrict__ mh,
                                              const float* __restrict__ dw_w,
                                              const float* __restrict__ bn1_g, const float* __restrict__ bn1_b,
                                              const float* __restrict__ bn1_m, const float* __restrict__ bn1_v,
                                              const float* __restrict__ bn2_g, const float* __restrict__ bn2_b,
                                              const float* __restrict__ bn2_m, const float* __restrict__ bn2_v,
                                              unsigned short* __restrict__ wb,
                                              float* __restrict__ cst) {
    int i = blockIdx.x * 256 + threadIdx.x;
    if (i < 21504) {
        float v;
        if (i < 4096) v = lw1[i];
        else if (i < 8192) v = lw2[i - 4096];
        else if (i < 16384) v = w_in[4096 + (i - 8192)];
        else if (i < 20480) v = pw[i - 16384];
        else v = mh[i - 20480];
        wb[i] = f2bf(v);
    } else if (i < 22272) {
        int j = i - 21504;
        if (j < 576) {            // dwTf[k][c] = dw[c][k]*s1[c]
            int k = j >> 6, c = j & 63;
            float s1 = bn1_g[c] * rsqrtf(bn1_v[c] + 1e-5f);
            cst[j] = dw_w[c * 9 + k] * s1;
        } else if (j < 640) {     // o1
            int c = j - 576;
            float s1 = bn1_g[c] * rsqrtf(bn1_v[c] + 1e-5f);
            cst[j] = bn1_b[c] - bn1_m[c] * s1;
        } else if (j < 704) {     // s2
            int c = j - 640;
            cst[j] = bn2_g[c] * rsqrtf(bn2_v[c] + 1e-5f);
        } else {                  // o2
            int c = j - 704;
            float s2 = bn2_g[c] * rsqrtf(bn2_v[c] + 1e-5f);
            cst[j] = bn2_b[c] - bn2_m[c] * s2;
        }
    }
}

// ---------------------------------------------------------------- K1: key = bf16(memory+pos) + pool1 fold
// 4096 blocks x 256; block = 32 consecutive n of one b (one row parity).
__global__ __launch_bounds__(256) void k_key(const float* __restrict__ mem,
                                             const float* __restrict__ pos,
                                             unsigned short* __restrict__ key,
                                             float* __restrict__ pool1raw) {
    __shared__ float sh[16][64];
    int tid = threadIdx.x;
    int b = blockIdx.x >> 9;
    int n_base = (blockIdx.x & 511) * 32;
    int c8 = tid & 7, local_n = tid >> 3;
    int n = n_base + local_n;
    long s4 = ((long)n * 8 + b) * 16 + c8 * 2;
    float4 m0 = ((const float4*)mem)[s4], m1 = ((const float4*)mem)[s4 + 1];
    float4 p0 = ((const float4*)pos)[s4], p1 = ((const float4*)pos)[s4 + 1];
    float f[8];
    f[0] = m0.x + p0.x; f[1] = m0.y + p0.y; f[2] = m0.z + p0.z; f[3] = m0.w + p0.w;
    f[4] = m1.x + p1.x; f[5] = m1.y + p1.y; f[6] = m1.z + p1.z; f[7] = m1.w + p1.w;
    uint4 o;
    o.x = (unsigned)f2bf(f[0]) | ((unsigned)f2bf(f[1]) << 16);
    o.y = (unsigned)f2bf(f[2]) | ((unsigned)f2bf(f[3]) << 16);
    o.z = (unsigned)f2bf(f[4]) | ((unsigned)f2bf(f[5]) << 16);
    o.w = (unsigned)f2bf(f[6]) | ((unsigned)f2bf(f[7]) << 16);
    ((uint4*)key)[(long)(b * 16384 + n) * 8 + c8] = o;
    // pool of d-pixels (odd row, odd col)
    int parity = (n_base >> 7) & 1;
    if (parity) {
        if (local_n & 1) {
            #pragma unroll
            for (int j = 0; j < 8; j++) sh[local_n >> 1][c8 * 8 + j] = f[j];
        }
        __syncthreads();
        if (tid < 64) {
            float s = 0.f;
            #pragma unroll
            for (int k = 0; k < 16; k++) s += sh[k][tid];
            atomicAdd(pool1raw + b * 64 + tid, s);
        }
    }
}

// ---------------------------------------------------------------- K2: qp + glo merged (136 blocks of 64)
__global__ __launch_bounds__(64) void k_qp_glo(const float* __restrict__ tgt,
                                               const float* __restrict__ qpos,
                                               const float* __restrict__ w_in,
                                               const float* __restrict__ b_in,
                                               const float* __restrict__ pool1raw,
                                               const float* __restrict__ gw1, const float* __restrict__ gb1,
                                               const float* __restrict__ gw2, const float* __restrict__ gb2,
                                               float* __restrict__ qp,
                                               float* __restrict__ queryb,
                                               float* __restrict__ glo1) {
    __shared__ float s0[64], s1v[64];
    int t = threadIdx.x;
    if (blockIdx.x < 128) {
        int b = blockIdx.x >> 4;
        int q = blockIdx.x & 15;
        long src = ((long)q * 8 + b) * 64 + t;
        float v = tgt[src] + qpos[src];
        s0[t] = v;
        queryb[(b * 16 + q) * 64 + t] = v;
        __syncthreads();
        float acc = b_in[t];
        for (int c = 0; c < 64; c++) acc += s0[c] * w_in[t * 64 + c];
        qp[(b * 16 + q) * 64 + t] = acc;
    } else {
        int b = blockIdx.x - 128;
        s0[t] = pool1raw[b * 64 + t] * (2.0f / 4096.0f);
        __syncthreads();
        float h = gb1[t];
        for (int c = 0; c < 64; c++) h += s0[c] * gw1[t * 64 + c];
        s1v[t] = fmaxf(h, 0.f);
        __syncthreads();
        float gl = gb2[t];
        for (int hh = 0; hh < 64; hh++) gl += s1v[hh] * gw2[t * 64 + hh];
        glo1[b * 64 + t] = gl;
    }
}

// ---------------------------------------------------------------- K3: mscw1 + fre + K/V proj (LDS-staged + MFMA)
// grid 512 (8 b x 64 row-pairs), 256 threads.
__global__ __launch_bounds__(256) void k_mscw1(
        const unsigned short* __restrict__ keyb, const float* __restrict__ glo1,
        const float* __restrict__ lb1, const float* __restrict__ lb2,
        const float* __restrict__ b_in, const unsigned short* __restrict__ wb,
        unsigned short* __restrict__ kph, unsigned short* __restrict__ vph) {
    __shared__ __align__(16) short stage[256 * 72];   // rows 2i,2i+1 padded
    __shared__ __align__(16) short hbuf[64 * 72];
    __shared__ __align__(16) short wbuf[64 * 72];
    int tid = threadIdx.x;
    int w = tid >> 6, l = tid & 63;
    int b = blockIdx.x >> 6, tile = blockIdx.x & 63;
    int m0 = w * 16, trow = l & 15, oct = l >> 4;
    // stage 256 positions (32 KB contiguous) coalesced
    const unsigned short* src = keyb + ((long)b * 16384 + tile * 256) * 64;
    #pragma unroll
    for (int k = 0; k < 8; k++) {
        int u = k * 256 + tid;          // 2048 uint4
        int p = u >> 3, o = u & 7;
        uint4 v = *(const uint4*)(src + (long)u * 8);
        *(uint4*)(stage + p * 72 + o * 8) = v;
    }
    __syncthreads();
    int j = m0 + trow;
    float x[16], S[16];
    bf16x8 ax[2];
    #pragma unroll
    for (int half = 0; half < 2; half++) {
        int o = oct + half * 4;
        uint4 fa4 = *(const uint4*)(stage + (2 * j) * 72 + o * 8);
        uint4 fb4 = *(const uint4*)(stage + (2 * j + 1) * 72 + o * 8);
        uint4 fc4 = *(const uint4*)(stage + (128 + 2 * j) * 72 + o * 8);
        uint4 fd4 = *(const uint4*)(stage + (129 + 2 * j) * 72 + o * 8);
        float A[8], B[8], C[8], D[8];
        unpack8(fa4, A); unpack8(fb4, B); unpack8(fc4, C); unpack8(fd4, D);
        #pragma unroll
        for (int jj = 0; jj < 8; jj++) {
            float xd = 2.f * D[jj];
            x[half * 8 + jj] = xd;
            S[half * 8 + jj] = 0.5f * (A[jj] + B[jj] + C[jj] + D[jj]);
            ax[half][jj] = (short)f2bf(xd);
        }
    }
    const unsigned short* w1b = wb;
    const unsigned short* w2b = wb + 4096;
    const unsigned short* wkb = wb + 8192;
    const unsigned short* wvb = wb + 12288;
    // G1: hid = relu(x @ w1^T + b1)
    #pragma unroll
    for (int t4 = 0; t4 < 4; t4++) {
        int n = t4 * 16 + trow;
        float bias = lb1[n];
        floatx4 acc = {bias, bias, bias, bias};
        acc = MFMA16(ax[0], ldg8b(w1b + n * 64 + oct * 8), acc);
        acc = MFMA16(ax[1], ldg8b(w1b + n * 64 + 32 + oct * 8), acc);
        #pragma unroll
        for (int r = 0; r < 4; r++)
            hbuf[(m0 + oct * 4 + r) * 72 + n] = (short)f2bf(fmaxf(acc[r], 0.f));
    }
    __syncthreads();
    // G2: wei = sigmoid(hid @ w2^T + b2 + glo)
    {
        bf16x8 ah0 = *(const bf16x8*)(hbuf + (m0 + trow) * 72 + oct * 8);
        bf16x8 ah1 = *(const bf16x8*)(hbuf + (m0 + trow) * 72 + 32 + oct * 8);
        const float* gl = glo1 + b * 64;
        #pragma unroll
        for (int t4 = 0; t4 < 4; t4++) {
            int n = t4 * 16 + trow;
            float bias = lb2[n];
            floatx4 acc = {bias, bias, bias, bias};
            acc = MFMA16(ah0, ldg8b(w2b + n * 64 + oct * 8), acc);
            acc = MFMA16(ah1, ldg8b(w2b + n * 64 + 32 + oct * 8), acc);
            float g = gl[n];
            #pragma unroll
            for (int r = 0; r < 4; r++)
                wbuf[(m0 + oct * 4 + r) * 72 + n] = (short)f2bf(sigmoidf_(acc[r] + g));
        }
    }
    __syncthreads();
    // fre = wei*x + (1-wei)*S -> A-frags
    bf16x8 af0, af1;
    {
        bf16x8 w0 = *(const bf16x8*)(wbuf + (m0 + trow) * 72 + oct * 8);
        bf16x8 w1v = *(const bf16x8*)(wbuf + (m0 + trow) * 72 + 32 + oct * 8);
        #pragma unroll
        for (int jj = 0; jj < 8; jj++) {
            float we0 = bf2f((unsigned short)w0[jj]);
            float we1 = bf2f((unsigned short)w1v[jj]);
            af0[jj] = (short)f2bf(we0 * x[jj] + (1.f - we0) * S[jj]);
            af1[jj] = (short)f2bf(we1 * x[8 + jj] + (1.f - we1) * S[8 + jj]);
        }
    }
    __syncthreads();   // reuse hbuf/wbuf as kbuf/vbuf
    short* kbuf = hbuf; short* vbuf = wbuf;
    #pragma unroll
    for (int t4 = 0; t4 < 4; t4++) {
        int ko = t4 * 16 + trow;
        float bk = b_in[64 + ko], bv = b_in[128 + ko];
        floatx4 ak = {bk, bk, bk, bk};
        floatx4 av = {bv, bv, bv, bv};
        ak = MFMA16(af0, ldg8b(wkb + ko * 64 + oct * 8), ak);
        ak = MFMA16(af1, ldg8b(wkb + ko * 64 + 32 + oct * 8), ak);
        av = MFMA16(af0, ldg8b(wvb + ko * 64 + oct * 8), av);
        av = MFMA16(af1, ldg8b(wvb + ko * 64 + 32 + oct * 8), av);
        #pragma unroll
        for (int r = 0; r < 4; r++) {
            int row = m0 + oct * 4 + r;
            kbuf[row * 72 + ko] = (short)f2bf(ak[r]);
            vbuf[row * 72 + ko] = (short)f2bf(av[r]);
        }
    }
    __syncthreads();
    for (int u = tid; u < 512; u += 256) {
        int h = u >> 6, tok = u & 63;
        uint4 kk = *(const uint4*)(kbuf + tok * 72 + h * 8);
        uint4 vv = *(const uint4*)(vbuf + tok * 72 + h * 8);
        long du = (long)(b * 8 + h) * 4096 + tile * 64 + tok;
        ((uint4*)kph)[du] = kk;
        ((uint4*)vph)[du] = vv;
    }
}

// ---------------------------------------------------------------- K4: dsconv (LDS-staged) + mask head -> pexp + Z
// grid 1024 (8 b x 128 rows), 512 threads.
__global__ __launch_bounds__(512) void k_dsconv(
        const unsigned short* __restrict__ keyb,
        const unsigned short* __restrict__ wb,
        const float* __restrict__ cst,
        unsigned short* __restrict__ pexp, float* __restrict__ Z) {
    __shared__ __align__(16) short stage[3 * 128 * 72];   // 55296 B; aliased as y2buf after conv
    __shared__ __align__(16) short pbuf[16 * 136];
    __shared__ float cbuf[768];
    __shared__ float zred[8][16];
    int tid = threadIdx.x;
    int w = tid >> 6, l = tid & 63;
    int b = blockIdx.x >> 7, h = blockIdx.x & 127;
    int p0 = w * 16, pr = l & 15, oct = l >> 4;
    for (int k = tid; k < 768; k += 512) cbuf[k] = cst[k];
    // stage rows h-1..h+1 (dense coalesced copies; zero-fill boundaries)
    const unsigned short* kb = keyb + (long)b * 1048576;
    #pragma unroll
    for (int r = 0; r < 3; r++) {
        int row = h - 1 + r;
        if ((unsigned)row < 128u) {
            const unsigned short* src = kb + (long)row * 8192;
            #pragma unroll
            for (int k = 0; k < 4; k++) {
                int u = k * 512 + tid;      // 2048 uint4 per row
                int p = u >> 3, o = u & 7;
                uint4 v = *(const uint4*)(src + (long)u * 8);
                *(uint4*)(stage + (r * 128 + p) * 72 + o * 8) = v;
            }
        } else {
            uint4 zz = {0u, 0u, 0u, 0u};
            #pragma unroll
            for (int k = 0; k < 4; k++) {
                int u = k * 512 + tid;
                int p = u >> 3, o = u & 7;
                *(uint4*)(stage + (r * 128 + p) * 72 + o * 8) = zz;
            }
        }
    }
    __syncthreads();
    // dw conv 3x3 from LDS
    float accf[2][8];
    #pragma unroll
    for (int half = 0; half < 2; half++)
        #pragma unroll
        for (int jj = 0; jj < 8; jj++) accf[half][jj] = 0.f;
    #pragma unroll
    for (int r = 0; r < 3; r++) {
        #pragma unroll
        for (int kk = 0; kk < 3; kk++) {
            int col = p0 + pr - 1 + kk;
            if ((unsigned)col < 128u) {
                #pragma unroll
                for (int half = 0; half < 2; half++) {
                    int o = oct + half * 4;
                    uint4 d4 = *(const uint4*)(stage + (r * 128 + col) * 72 + o * 8);
                    float f[8]; unpack8(d4, f);
                    float4 wa = *(const float4*)(cbuf + (r * 3 + kk) * 64 + o * 8);
                    float4 wc = *(const float4*)(cbuf + (r * 3 + kk) * 64 + o * 8 + 4);
                    accf[half][0] += f[0] * wa.x; accf[half][1] += f[1] * wa.y;
                    accf[half][2] += f[2] * wa.z; accf[half][3] += f[3] * wa.w;
                    accf[half][4] += f[4] * wc.x; accf[half][5] += f[5] * wc.y;
                    accf[half][6] += f[6] * wc.z; accf[half][7] += f[7] * wc.w;
                }
            }
        }
    }
    bf16x8 af[2];
    #pragma unroll
    for (int half = 0; half < 2; half++) {
        int o = oct + half * 4;
        float4 oa = *(const float4*)(cbuf + 576 + o * 8);
        float4 ob = *(const float4*)(cbuf + 576 + o * 8 + 4);
        af[half][0] = (short)f2bf(fmaxf(accf[half][0] + oa.x, 0.f));
        af[half][1] = (short)f2bf(fmaxf(accf[half][1] + oa.y, 0.f));
        af[half][2] = (short)f2bf(fmaxf(accf[half][2] + oa.z, 0.f));
        af[half][3] = (short)f2bf(fmaxf(accf[half][3] + oa.w, 0.f));
        af[half][4] = (short)f2bf(fmaxf(accf[half][4] + ob.x, 0.f));
        af[half][5] = (short)f2bf(fmaxf(accf[half][5] + ob.y, 0.f));
        af[half][6] = (short)f2bf(fmaxf(accf[half][6] + ob.z, 0.f));
        af[half][7] = (short)f2bf(fmaxf(accf[half][7] + ob.w, 0.f));
    }
    __syncthreads();        // conv reads done; stage becomes y2buf
    short* y2buf = stage;
    const unsigned short* pwb = wb + 16384;
    #pragma unroll
    for (int t4 = 0; t4 < 4; t4++) {
        int n = t4 * 16 + pr;
        floatx4 acc = {0.f, 0.f, 0.f, 0.f};
        acc = MFMA16(af[0], ldg8b(pwb + n * 64 + oct * 8), acc);
        acc = MFMA16(af[1], ldg8b(pwb + n * 64 + 32 + oct * 8), acc);
        float s2 = cbuf[640 + n], o2 = cbuf[704 + n];
        #pragma unroll
        for (int r = 0; r < 4; r++)
            y2buf[(p0 + oct * 4 + r) * 72 + n] = (short)f2bf(fmaxf(acc[r] * s2 + o2, 0.f));
    }
    __syncthreads();
    // mask head + exp
    {
        const unsigned short* mhb = wb + 20480;
        bf16x8 a0 = *(const bf16x8*)(y2buf + (p0 + pr) * 72 + oct * 8);
        bf16x8 a1 = *(const bf16x8*)(y2buf + (p0 + pr) * 72 + 32 + oct * 8);
        floatx4 lg = {0.f, 0.f, 0.f, 0.f};
        lg = MFMA16(a0, ldg8b(mhb + pr * 64 + oct * 8), lg);
        lg = MFMA16(a1, ldg8b(mhb + pr * 64 + 32 + oct * 8), lg);
        float zs = 0.f;
        #pragma unroll
        for (int r = 0; r < 4; r++) {
            float e = __expf(lg[r]);
            zs += e;
            pbuf[pr * 136 + p0 + oct * 4 + r] = (short)f2bf(e);
        }
        zs += __shfl_xor(zs, 16);
        zs += __shfl_xor(zs, 32);
        if (l < 16) zred[w][l] = zs;
    }
    __syncthreads();
    if (tid < 256) {
        int p = tid >> 4, ch = tid & 15;
        uint4 o = *(const uint4*)(pbuf + p * 136 + ch * 8);
        ((uint4*)pexp)[((long)(b * 16 + p) * 16384 + h * 128 + ch * 8) >> 3] = o;
    }
    if (tid < 16) {
        float zt = 0.f;
        #pragma unroll
        for (int ww = 0; ww < 8; ww++) zt += zred[ww][tid];
        atomicAdd(Z + b * 16 + tid, zt);
    }
}

// ---------------------------------------------------------------- K5: protos = pexp @ key (MFMA, in-kernel transpose)
// grid 512 (8 b x 64 chunks of 256 n), 256 threads (4 waves = 4 c-tiles).
__global__ __launch_bounds__(256) void k_protos(const unsigned short* __restrict__ pexp,
                                                const unsigned short* __restrict__ keyb,
                                                float* __restrict__ protos) {
    __shared__ __align__(16) short ldsT[64 * 264];   // [c][n], padded
    int tid = threadIdx.x;
    int b = blockIdx.x >> 6, ch = blockIdx.x & 63;
    long nbase = (long)b * 16384 + ch * 256;
    #pragma unroll
    for (int k = 0; k < 8; k++) {
        int u = k * 256 + tid;       // 2048 uint4
        int n = u >> 3, o = u & 7;
        uint4 v = *(const uint4*)(keyb + (nbase + n) * 64 + o * 8);
        ldsT[(o * 8 + 0) * 264 + n] = (short)(v.x & 0xffff);
        ldsT[(o * 8 + 1) * 264 + n] = (short)(v.x >> 16);
        ldsT[(o * 8 + 2) * 264 + n] = (short)(v.y & 0xffff);
        ldsT[(o * 8 + 3) * 264 + n] = (short)(v.y >> 16);
        ldsT[(o * 8 + 4) * 264 + n] = (short)(v.z & 0xffff);
        ldsT[(o * 8 + 5) * 264 + n] = (short)(v.z >> 16);
        ldsT[(o * 8 + 6) * 264 + n] = (short)(v.w & 0xffff);
        ldsT[(o * 8 + 7) * 264 + n] = (short)(v.w >> 16);
    }
    __syncthreads();
    int w = tid >> 6, l = tid & 63;
    int col = l & 15, oct = l >> 4;
    const unsigned short* pb = pexp + ((long)b * 16 + col) * 16384 + ch * 256;
    floatx4 acc = {0.f, 0.f, 0.f, 0.f};
    #pragma unroll
    for (int s = 0; s < 8; s++) {
        bf16x8 A = *(const bf16x8*)(pb + s * 32 + oct * 8);
        bf16x8 B = *(const bf16x8*)(ldsT + (w * 16 + col) * 264 + s * 32 + oct * 8);
        acc = MFMA16(A, B, acc);
    }
    #pragma unroll
    for (int r = 0; r < 4; r++)
        atomicAdd(protos + (b * 16 + oct * 4 + r) * 64 + w * 16 + col, acc[r]);
}

// ---------------------------------------------------------------- K6: MHA flash-decode partials (b,h,eighth)
__global__ __launch_bounds__(256) void k_mha(const float* __restrict__ qp,
                                             const unsigned short* __restrict__ kph,
                                             const unsigned short* __restrict__ vph,
                                             float* __restrict__ part) {
    int bh = blockIdx.x >> 3, seg = blockIdx.x & 7;
    int b = bh >> 3, hh = bh & 7;
    int tid = threadIdx.x;
    int q = tid >> 4, sub = tid & 15;
    const float* qv = qp + (long)(b * 16 + q) * 64 + hh * 8;
    float4 q0 = ((const float4*)qv)[0];
    float4 q1 = ((const float4*)qv)[1];
    const uint4* K4 = (const uint4*)kph + (long)bh * 4096;
    const uint4* V4 = (const uint4*)vph + (long)bh * 4096;
    const float scale = 0.35355339059327373f;
    float m = -1e30f, lsum = 0.f;
    float acc[8];
    #pragma unroll
    for (int d = 0; d < 8; d++) acc[d] = 0.f;
    for (int i = 0; i < 32; i++) {
        int n = seg * 512 + i * 16 + sub;
        float k8[8]; unpack8(K4[n], k8);
        float s = q0.x * k8[0] + q0.y * k8[1] + q0.z * k8[2] + q0.w * k8[3]
                + q1.x * k8[4] + q1.y * k8[5] + q1.z * k8[6] + q1.w * k8[7];
        s *= scale;
        float nm = fmaxf(m, s);
        float corr = __expf(m - nm);
        float wgt = __expf(s - nm);
        lsum = lsum * corr + wgt;
        float v8[8]; unpack8(V4[n], v8);
        #pragma unroll
        for (int d = 0; d < 8; d++) acc[d] = acc[d] * corr + wgt * v8[d];
        m = nm;
    }
    #pragma unroll
    for (int off = 1; off < 16; off <<= 1) {
        float om = __shfl_xor(m, off);
        float ol = __shfl_xor(lsum, off);
        float oa[8];
        #pragma unroll
        for (int d = 0; d < 8; d++) oa[d] = __shfl_xor(acc[d], off);
        float nm = fmaxf(m, om);
        float c1 = __expf(m - nm), c2 = __expf(om - nm);
        lsum = lsum * c1 + ol * c2;
        #pragma unroll
        for (int d = 0; d < 8; d++) acc[d] = acc[d] * c1 + oa[d] * c2;
        m = nm;
    }
    if (sub == 0) {
        float* P = part + ((long)(bh * 16 + q) * 8 + seg) * 12;
        P[0] = m; P[1] = lsum;
        #pragma unroll
        for (int d = 0; d < 8; d++) P[2 + d] = acc[d];
    }
}

// ---------------------------------------------------------------- K7: epilogue — merge MHA, mscw2, LNs
__global__ __launch_bounds__(1024) void k_final(
        const float* __restrict__ queryb, const float* __restrict__ protos,
        const float* __restrict__ Z, const float* __restrict__ part,
        const float* __restrict__ w_out, const float* __restrict__ b_out,
        const float* __restrict__ ln1_g, const float* __restrict__ ln1_b,
        const float* __restrict__ ln2_g, const float* __restrict__ ln2_b,
        const float* __restrict__ lw1, const float* __restrict__ lb1,
        const float* __restrict__ lw2, const float* __restrict__ lb2,
        const float* __restrict__ gw1, const float* __restrict__ gb1,
        const float* __restrict__ gw2, const float* __restrict__ gb2,
        float* __restrict__ out) {
    int b = blockIdx.x;
    int t = threadIdx.x >> 6;
    int c = threadIdx.x & 63;
    __shared__ float xs[16][64], hid[16][64], os[16][64];
    __shared__ float pool[64], hidg[64], glo[64];
    float q = queryb[(long)(b * 16 + t) * 64 + c];
    float rz = 1.f / Z[b * 16 + t];
    float xin = protos[(long)(b * 16 + t) * 64 + c] * rz + q;
    xs[t][c] = xin;
    {
        int hh = c >> 3, d = c & 7;
        const float* P = part + ((long)((b * 8 + hh) * 16 + t) * 8) * 12;
        float mm = -1e30f, ll = 0.f, aa = 0.f;
        #pragma unroll
        for (int s = 0; s < 8; s++) {
            float pm = P[s * 12], pl2 = P[s * 12 + 1], pa = P[s * 12 + 2 + d];
            float nm = fmaxf(mm, pm);
            float c1 = __expf(mm - nm), c2 = __expf(pm - nm);
            aa = aa * c1 + pa * c2;
            ll = ll * c1 + pl2 * c2;
            mm = nm;
        }
        os[t][c] = aa / ll;
    }
    __syncthreads();
    if (threadIdx.x < 64) {
        float s = 0.f;
        for (int tt = 0; tt < 16; tt++) s += xs[tt][threadIdx.x];
        pool[threadIdx.x] = s * (1.f / 16.f);
    }
    __syncthreads();
    if (threadIdx.x < 64) {
        int hh = threadIdx.x;
        float a = gb1[hh];
        for (int cc = 0; cc < 64; cc++) a += pool[cc] * gw1[hh * 64 + cc];
        hidg[hh] = fmaxf(a, 0.f);
    }
    __syncthreads();
    if (threadIdx.x < 64) {
        int ccc = threadIdx.x;
        float a = gb2[ccc];
        for (int hh = 0; hh < 64; hh++) a += hidg[hh] * gw2[ccc * 64 + hh];
        glo[ccc] = a;
    }
    float a = lb1[c];
    for (int cc = 0; cc < 64; cc++) a += xs[t][cc] * lw1[c * 64 + cc];
    hid[t][c] = fmaxf(a, 0.f);
    __syncthreads();
    float loc = lb2[c];
    for (int hh = 0; hh < 64; hh++) loc += hid[t][hh] * lw2[c * 64 + hh];
    float attn2 = sigmoidf_(loc + glo[c]);
    float x2p = q * attn2 + q;
    float mu = x2p;
    for (int off = 32; off; off >>= 1) mu += __shfl_down(mu, off);
    mu = __shfl(mu, 0) * (1.f / 64.f);
    float d0 = x2p - mu;
    float vv = d0 * d0;
    for (int off = 32; off; off >>= 1) vv += __shfl_down(vv, off);
    vv = __shfl(vv, 0) * (1.f / 64.f);
    float x2 = d0 * rsqrtf(vv + 1e-5f) * ln2_g[c] + ln2_b[c];
    float x1p = b_out[c];
    for (int k = 0; k < 64; k++) x1p += os[t][k] * w_out[c * 64 + k];
    x1p += q;
    float mu1 = x1p;
    for (int off = 32; off; off >>= 1) mu1 += __shfl_down(mu1, off);
    mu1 = __shfl(mu1, 0) * (1.f / 64.f);
    float d1 = x1p - mu1;
    float v1 = d1 * d1;
    for (int off = 32; off; off >>= 1) v1 += __shfl_down(v1, off);
    v1 = __shfl(v1, 0) * (1.f / 64.f);
    float x1 = d1 * rsqrtf(v1 + 1e-5f) * ln1_g[c] + ln1_b[c];
    out[((long)t * 8 + b) * 64 + c] = x1 + x2;
}

// ----------------------------------------------------------------
extern "C" void kernel_launch(void* const* d_in, const int* in_sizes, int n_in,
                              void* d_out, int out_size, void* d_ws, size_t ws_size,
                              hipStream_t stream) {
    const float* tgt       = (const float*)d_in[0];
    const float* memory    = (const float*)d_in[1];
    const float* pos       = (const float*)d_in[2];
    const float* query_pos = (const float*)d_in[3];
    const float* w_in      = (const float*)d_in[4];
    const float* b_in      = (const float*)d_in[5];
    const float* w_out     = (const float*)d_in[6];
    const float* b_out     = (const float*)d_in[7];
    const float* ln1_g     = (const float*)d_in[8];
    const float* ln1_b     = (const float*)d_in[9];
    const float* ln2_g     = (const float*)d_in[10];
    const float* ln2_b     = (const float*)d_in[11];
    const float* dw_w      = (const float*)d_in[12];
    const float* bn1_g     = (const float*)d_in[13];
    const float* bn1_b     = (const float*)d_in[14];
    const float* bn1_m     = (const float*)d_in[15];
    const float* bn1_v     = (const float*)d_in[16];
    const float* pw_w      = (const float*)d_in[17];
    const float* bn2_g     = (const float*)d_in[18];
    const float* bn2_b     = (const float*)d_in[19];
    const float* bn2_m     = (const float*)d_in[20];
    const float* bn2_v     = (const float*)d_in[21];
    const float* mheads    = (const float*)d_in[22];
    const float* m1_lw1 = (const float*)d_in[23];
    const float* m1_lb1 = (const float*)d_in[24];
    const float* m1_lw2 = (const float*)d_in[25];
    const float* m1_lb2 = (const float*)d_in[26];
    const float* m1_gw1 = (const float*)d_in[27];
    const float* m1_gb1 = (const float*)d_in[28];
    const float* m1_gw2 = (const float*)d_in[29];
    const float* m1_gb2 = (const float*)d_in[30];
    const float* m2_lw1 = (const float*)d_in[31];
    const float* m2_lb1 = (const float*)d_in[32];
    const float* m2_lw2 = (const float*)d_in[33];
    const float* m2_lb2 = (const float*)d_in[34];
    const float* m2_gw1 = (const float*)d_in[35];
    const float* m2_gb1 = (const float*)d_in[36];
    const float* m2_gw2 = (const float*)d_in[37];
    const float* m2_gb2 = (const float*)d_in[38];

    float* ws = (float*)d_ws;
    float* out = (float*)d_out;
    unsigned short* keyb = (unsigned short*)(ws + OFF_KEY);
    unsigned short* kph  = (unsigned short*)(ws + OFF_KPH);
    unsigned short* vph  = (unsigned short*)(ws + OFF_VPH);
    unsigned short* pexp = (unsigned short*)(ws + OFF_PEXP);
    unsigned short* wb   = (unsigned short*)(ws + OFF_WB);

    // zero atomic regions (pool + protos + Z, contiguous)
    hipMemsetAsync(ws + OFF_POOL, 0, 8832 * sizeof(float), stream);

    k_prep<<<88, 256, 0, stream>>>(m1_lw1, m1_lw2, w_in, pw_w, mheads, dw_w,
                                   bn1_g, bn1_b, bn1_m, bn1_v,
                                   bn2_g, bn2_b, bn2_m, bn2_v,
                                   wb, ws + OFF_CST);
    k_key<<<4096, 256, 0, stream>>>(memory, pos, keyb, ws + OFF_POOL);
    k_qp_glo<<<136, 64, 0, stream>>>(tgt, query_pos, w_in, b_in, ws + OFF_POOL,
                                     m1_gw1, m1_gb1, m1_gw2, m1_gb2,
                                     ws + OFF_QP, ws + OFF_QB, ws + OFF_GLO);
    k_mscw1<<<512, 256, 0, stream>>>(keyb, ws + OFF_GLO, m1_lb1, m1_lb2, b_in, wb, kph, vph);
    k_dsconv<<<1024, 512, 0, stream>>>(keyb, wb, ws + OFF_CST, pexp, ws + OFF_ZZ);
    k_protos<<<512, 256, 0, stream>>>(pexp, keyb, ws + OFF_PROT);
    k_mha<<<512, 256, 0, stream>>>(ws + OFF_QP, kph, vph, ws + OFF_PART);
    k_final<<<8, 1024, 0, stream>>>(ws + OFF_QB, ws + OFF_PROT, ws + OFF_ZZ, ws + OFF_PART,
                                    w_out, b_out, ln1_g, ln1_b, ln2_g, ln2_b,
                                    m2_lw1, m2_lb1, m2_lw2, m2_lb2,
                                    m2_gw1, m2_gb1, m2_gw2, m2_gb2,
                                    out);
}

// Round 5
// 247.743 us; speedup vs baseline: 1.5154x; 1.0791x over previous
//
#include <hip/hip_runtime.h>
#include <math.h>

#define N1 16384
#define N2 4096

// Workspace layout (float offsets)
#define OFF_KEY   0L            // key bf16 [B][N1][64] = 8,388,608 shorts
#define OFF_KPH   4194304L      // kp bf16 [B*H][4096][8]
#define OFF_VPH   5242880L
#define OFF_WB    6291456L      // bf16 weights (21504 shorts)
#define OFF_CST   6302208L      // fp32: dwTf[576],o1[64],s2[64],o2[64], then 7x4096 transposed mats
#define OFF_POOL  6331648L      // 512  (zeroed)
#define OFF_PROT  6332160L      // 8192 (zeroed)
#define OFF_ZZ    6340352L      // 128  (zeroed)
#define OFF_QP    6340480L
#define OFF_QB    6348672L
#define OFF_PART  6356864L      // [B*H][16 q][8 seg][12]

typedef __attribute__((ext_vector_type(8))) short bf16x8;
typedef __attribute__((ext_vector_type(4))) float floatx4;

#define MFMA16(a, b, c) __builtin_amdgcn_mfma_f32_16x16x32_bf16(a, b, c, 0, 0, 0)

__device__ __forceinline__ unsigned short f2bf(float f) {
    union { float f; unsigned u; } v; v.f = f;
    unsigned r = v.u + 0x7fffu + ((v.u >> 16) & 1u);
    return (unsigned short)(r >> 16);
}
__device__ __forceinline__ float bf2f(unsigned short s) {
    union { unsigned u; float f; } v; v.u = ((unsigned)s) << 16;
    return v.f;
}
__device__ __forceinline__ float sigmoidf_(float x) { return 1.f / (1.f + __expf(-x)); }
__device__ __forceinline__ bf16x8 ldg8b(const unsigned short* p) { return *(const bf16x8*)p; }
__device__ __forceinline__ void unpack8(uint4 v, float* f) {
    f[0] = bf2f((unsigned short)(v.x & 0xffff)); f[1] = bf2f((unsigned short)(v.x >> 16));
    f[2] = bf2f((unsigned short)(v.y & 0xffff)); f[3] = bf2f((unsigned short)(v.y >> 16));
    f[4] = bf2f((unsigned short)(v.z & 0xffff)); f[5] = bf2f((unsigned short)(v.z >> 16));
    f[6] = bf2f((unsigned short)(v.w & 0xffff)); f[7] = bf2f((unsigned short)(v.w >> 16));
}

// ---------------------------------------------------------------- prep: weights bf16 + folded consts + transposed fp32 + qp
// blocks 0..83: wb (21504 bf16); 84..198: cst fp32 (29440); 199..230: qp (32 blocks x 4 (b,q))
__global__ __launch_bounds__(256) void k_prep(const float* __restrict__ m1lw1,
                                              const float* __restrict__ m1lw2,
                                              const float* __restrict__ w_in,
                                              const float* __restrict__ pw,
                                              const float* __restrict__ mh,
                                              const float* __restrict__ dw_w,
                                              const float* __restrict__ bn1_g, const float* __restrict__ bn1_b,
                                              const float* __restrict__ bn1_m, const float* __restrict__ bn1_v,
                                              const float* __restrict__ bn2_g, const float* __restrict__ bn2_b,
                                              const float* __restrict__ bn2_m, const float* __restrict__ bn2_v,
                                              const float* __restrict__ m1gw1, const float* __restrict__ m1gw2,
                                              const float* __restrict__ m2gw1, const float* __restrict__ m2gw2,
                                              const float* __restrict__ m2lw1, const float* __restrict__ m2lw2,
                                              const float* __restrict__ w_out,
                                              const float* __restrict__ tgt, const float* __restrict__ qpos,
                                              const float* __restrict__ b_in,
                                              unsigned short* __restrict__ wb,
                                              float* __restrict__ cst,
                                              float* __restrict__ qp, float* __restrict__ queryb) {
    int blk = blockIdx.x, tid = threadIdx.x;
    if (blk < 84) {
        int i = blk * 256 + tid;
        float v;
        if (i < 4096) v = m1lw1[i];
        else if (i < 8192) v = m1lw2[i - 4096];
        else if (i < 16384) v = w_in[4096 + (i - 8192)];
        else if (i < 20480) v = pw[i - 16384];
        else v = mh[i - 20480];
        wb[i] = f2bf(v);
    } else if (blk < 199) {
        int j = (blk - 84) * 256 + tid;   // < 29440
        float v;
        if (j < 576) {
            int k = j >> 6, c = j & 63;
            float s1 = bn1_g[c] * rsqrtf(bn1_v[c] + 1e-5f);
            v = dw_w[c * 9 + k] * s1;
        } else if (j < 640) {
            int c = j - 576;
            float s1 = bn1_g[c] * rsqrtf(bn1_v[c] + 1e-5f);
            v = bn1_b[c] - bn1_m[c] * s1;
        } else if (j < 704) {
            int c = j - 640;
            v = bn2_g[c] * rsqrtf(bn2_v[c] + 1e-5f);
        } else if (j < 768) {
            int c = j - 704;
            float s2 = bn2_g[c] * rsqrtf(bn2_v[c] + 1e-5f);
            v = bn2_b[c] - bn2_m[c] * s2;
        } else {
            int jj = j - 768;
            int m = jj >> 12, idx = jj & 4095;
            int sidx = (idx & 63) * 64 + (idx >> 6);   // transpose
            const float* src;
            switch (m) {
                case 0: src = m1gw1; break;
                case 1: src = m1gw2; break;
                case 2: src = m2gw1; break;
                case 3: src = m2gw2; break;
                case 4: src = m2lw1; break;
                case 5: src = m2lw2; break;
                default: src = w_out; break;
            }
            v = src[sidx];
        }
        cst[j] = v;
    } else {
        __shared__ float qv[4][64];
        int g = tid >> 6, lane = tid & 63;
        int u = (blk - 199) * 4 + g;
        int b = u >> 4, q = u & 15;
        long src = ((long)q * 8 + b) * 64 + lane;
        float v = tgt[src] + qpos[src];
        qv[g][lane] = v;
        queryb[(b * 16 + q) * 64 + lane] = v;
        __syncthreads();
        float acc = b_in[lane];
        for (int cc = 0; cc < 64; cc++) acc += qv[g][cc] * w_in[lane * 64 + cc];
        qp[(b * 16 + q) * 64 + lane] = acc;
    }
}

// ---------------------------------------------------------------- K1: key = bf16(memory+pos) + pool1 fold
__global__ __launch_bounds__(256) void k_key(const float* __restrict__ mem,
                                             const float* __restrict__ pos,
                                             unsigned short* __restrict__ key,
                                             float* __restrict__ pool1raw) {
    __shared__ float sh[16][64];
    int tid = threadIdx.x;
    int b = blockIdx.x >> 9;
    int n_base = (blockIdx.x & 511) * 32;
    int c8 = tid & 7, local_n = tid >> 3;
    int n = n_base + local_n;
    long s4 = ((long)n * 8 + b) * 16 + c8 * 2;
    float4 m0 = ((const float4*)mem)[s4], m1 = ((const float4*)mem)[s4 + 1];
    float4 p0 = ((const float4*)pos)[s4], p1 = ((const float4*)pos)[s4 + 1];
    float f[8];
    f[0] = m0.x + p0.x; f[1] = m0.y + p0.y; f[2] = m0.z + p0.z; f[3] = m0.w + p0.w;
    f[4] = m1.x + p1.x; f[5] = m1.y + p1.y; f[6] = m1.z + p1.z; f[7] = m1.w + p1.w;
    uint4 o;
    o.x = (unsigned)f2bf(f[0]) | ((unsigned)f2bf(f[1]) << 16);
    o.y = (unsigned)f2bf(f[2]) | ((unsigned)f2bf(f[3]) << 16);
    o.z = (unsigned)f2bf(f[4]) | ((unsigned)f2bf(f[5]) << 16);
    o.w = (unsigned)f2bf(f[6]) | ((unsigned)f2bf(f[7]) << 16);
    ((uint4*)key)[(long)(b * 16384 + n) * 8 + c8] = o;
    int parity = (n_base >> 7) & 1;
    if (parity) {
        if (local_n & 1) {
            #pragma unroll
            for (int j = 0; j < 8; j++) sh[local_n >> 1][c8 * 8 + j] = f[j];
        }
        __syncthreads();
        if (tid < 64) {
            float s = 0.f;
            #pragma unroll
            for (int k = 0; k < 16; k++) s += sh[k][tid];
            atomicAdd(pool1raw + b * 64 + tid, s);
        }
    }
}

// ---------------------------------------------------------------- K3: mscw1 + inline glo + fre + K/V proj
// grid 512 (8 b x 64 tiles), 256 threads.
__global__ __launch_bounds__(256) void k_mscw1(
        const unsigned short* __restrict__ keyb, const float* __restrict__ pool1raw,
        const float* __restrict__ lb1, const float* __restrict__ lb2,
        const float* __restrict__ gb1, const float* __restrict__ gb2,
        const float* __restrict__ b_in, const unsigned short* __restrict__ wb,
        const float* __restrict__ cst,
        unsigned short* __restrict__ kph, unsigned short* __restrict__ vph) {
    __shared__ __align__(16) short stage[256 * 72];
    __shared__ __align__(16) short hbuf[64 * 72];
    __shared__ __align__(16) short wbuf[64 * 72];
    __shared__ float parr[64], gtmp[64], gbuf[64];
    int tid = threadIdx.x;
    int w = tid >> 6, l = tid & 63;
    int b = blockIdx.x >> 6, tile = blockIdx.x & 63;
    int m0 = w * 16, trow = l & 15, oct = l >> 4;
    const float* gw1T = cst + 768;      // m1_gw1T
    const float* gw2T = cst + 4864;     // m1_gw2T
    if (tid < 64) parr[tid] = pool1raw[b * 64 + tid] * (2.0f / 4096.0f);
    const unsigned short* src = keyb + ((long)b * 16384 + tile * 256) * 64;
    #pragma unroll
    for (int k = 0; k < 8; k++) {
        int u = k * 256 + tid;
        int p = u >> 3, o = u & 7;
        uint4 v = *(const uint4*)(src + (long)u * 8);
        *(uint4*)(stage + p * 72 + o * 8) = v;
    }
    __syncthreads();   // sync1: stage + parr
    // glo layer1 (threads 0..63, transposed coalesced weights)
    if (tid < 64) {
        float a = gb1[tid];
        for (int cc = 0; cc < 64; cc++) a += parr[cc] * gw1T[cc * 64 + tid];
        gtmp[tid] = fmaxf(a, 0.f);
    }
    int j = m0 + trow;
    float x[16], S[16];
    bf16x8 ax[2];
    #pragma unroll
    for (int half = 0; half < 2; half++) {
        int o = oct + half * 4;
        uint4 fa4 = *(const uint4*)(stage + (2 * j) * 72 + o * 8);
        uint4 fb4 = *(const uint4*)(stage + (2 * j + 1) * 72 + o * 8);
        uint4 fc4 = *(const uint4*)(stage + (128 + 2 * j) * 72 + o * 8);
        uint4 fd4 = *(const uint4*)(stage + (129 + 2 * j) * 72 + o * 8);
        float A[8], B[8], C[8], D[8];
        unpack8(fa4, A); unpack8(fb4, B); unpack8(fc4, C); unpack8(fd4, D);
        #pragma unroll
        for (int jj = 0; jj < 8; jj++) {
            float xd = 2.f * D[jj];
            x[half * 8 + jj] = xd;
            S[half * 8 + jj] = 0.5f * (A[jj] + B[jj] + C[jj] + D[jj]);
            ax[half][jj] = (short)f2bf(xd);
        }
    }
    const unsigned short* w1b = wb;
    const unsigned short* w2b = wb + 4096;
    const unsigned short* wkb = wb + 8192;
    const unsigned short* wvb = wb + 12288;
    // G1: hid = relu(x @ w1^T + b1)
    #pragma unroll
    for (int t4 = 0; t4 < 4; t4++) {
        int n = t4 * 16 + trow;
        float bias = lb1[n];
        floatx4 acc = {bias, bias, bias, bias};
        acc = MFMA16(ax[0], ldg8b(w1b + n * 64 + oct * 8), acc);
        acc = MFMA16(ax[1], ldg8b(w1b + n * 64 + 32 + oct * 8), acc);
        #pragma unroll
        for (int r = 0; r < 4; r++)
            hbuf[(m0 + oct * 4 + r) * 72 + n] = (short)f2bf(fmaxf(acc[r], 0.f));
    }
    __syncthreads();   // sync2: hbuf + gtmp
    if (tid < 64) {
        float g = gb2[tid];
        for (int hh = 0; hh < 64; hh++) g += gtmp[hh] * gw2T[hh * 64 + tid];
        gbuf[tid] = g;
    }
    __syncthreads();   // sync2b: gbuf ready
    // G2: wei = sigmoid(hid @ w2^T + b2 + glo)
    {
        bf16x8 ah0 = *(const bf16x8*)(hbuf + (m0 + trow) * 72 + oct * 8);
        bf16x8 ah1 = *(const bf16x8*)(hbuf + (m0 + trow) * 72 + 32 + oct * 8);
        #pragma unroll
        for (int t4 = 0; t4 < 4; t4++) {
            int n = t4 * 16 + trow;
            float bias = lb2[n];
            floatx4 acc = {bias, bias, bias, bias};
            acc = MFMA16(ah0, ldg8b(w2b + n * 64 + oct * 8), acc);
            acc = MFMA16(ah1, ldg8b(w2b + n * 64 + 32 + oct * 8), acc);
            float g = gbuf[n];
            #pragma unroll
            for (int r = 0; r < 4; r++)
                wbuf[(m0 + oct * 4 + r) * 72 + n] = (short)f2bf(sigmoidf_(acc[r] + g));
        }
    }
    __syncthreads();   // sync3
    bf16x8 af0, af1;
    {
        bf16x8 w0 = *(const bf16x8*)(wbuf + (m0 + trow) * 72 + oct * 8);
        bf16x8 w1v = *(const bf16x8*)(wbuf + (m0 + trow) * 72 + 32 + oct * 8);
        #pragma unroll
        for (int jj = 0; jj < 8; jj++) {
            float we0 = bf2f((unsigned short)w0[jj]);
            float we1 = bf2f((unsigned short)w1v[jj]);
            af0[jj] = (short)f2bf(we0 * x[jj] + (1.f - we0) * S[jj]);
            af1[jj] = (short)f2bf(we1 * x[8 + jj] + (1.f - we1) * S[8 + jj]);
        }
    }
    __syncthreads();   // sync4: reuse hbuf/wbuf
    short* kbuf = hbuf; short* vbuf = wbuf;
    #pragma unroll
    for (int t4 = 0; t4 < 4; t4++) {
        int ko = t4 * 16 + trow;
        float bk = b_in[64 + ko], bv = b_in[128 + ko];
        floatx4 ak = {bk, bk, bk, bk};
        floatx4 av = {bv, bv, bv, bv};
        ak = MFMA16(af0, ldg8b(wkb + ko * 64 + oct * 8), ak);
        ak = MFMA16(af1, ldg8b(wkb + ko * 64 + 32 + oct * 8), ak);
        av = MFMA16(af0, ldg8b(wvb + ko * 64 + oct * 8), av);
        av = MFMA16(af1, ldg8b(wvb + ko * 64 + 32 + oct * 8), av);
        #pragma unroll
        for (int r = 0; r < 4; r++) {
            int row = m0 + oct * 4 + r;
            kbuf[row * 72 + ko] = (short)f2bf(ak[r]);
            vbuf[row * 72 + ko] = (short)f2bf(av[r]);
        }
    }
    __syncthreads();   // sync5
    for (int u = tid; u < 512; u += 256) {
        int h = u >> 6, tok = u & 63;
        uint4 kk = *(const uint4*)(kbuf + tok * 72 + h * 8);
        uint4 vv = *(const uint4*)(vbuf + tok * 72 + h * 8);
        long du = (long)(b * 8 + h) * 4096 + tile * 64 + tok;
        ((uint4*)kph)[du] = kk;
        ((uint4*)vph)[du] = vv;
    }
}

// ---------------------------------------------------------------- K4: dsconv + mask head + fused protos partial + Z
// grid 1024 (8 b x 128 rows), 512 threads.
__global__ __launch_bounds__(512) void k_dsconv(
        const unsigned short* __restrict__ keyb,
        const unsigned short* __restrict__ wb,
        const float* __restrict__ cst,
        float* __restrict__ protos, float* __restrict__ Z) {
    __shared__ __align__(16) short stage[3 * 128 * 72];   // r0 later = y2buf; r2 later = KT
    __shared__ __align__(16) short pbuf[16 * 136];
    __shared__ float cbuf[768];
    __shared__ float zred[8][16];
    int tid = threadIdx.x;
    int w = tid >> 6, l = tid & 63;
    int b = blockIdx.x >> 7, h = blockIdx.x & 127;
    int p0 = w * 16, pr = l & 15, oct = l >> 4;
    for (int k = tid; k < 768; k += 512) cbuf[k] = cst[k];
    const unsigned short* kb = keyb + (long)b * 1048576;
    #pragma unroll
    for (int r = 0; r < 3; r++) {
        int row = h - 1 + r;
        if ((unsigned)row < 128u) {
            const unsigned short* src = kb + (long)row * 8192;
            #pragma unroll
            for (int k = 0; k < 4; k++) {
                int u = k * 512 + tid;
                int p = u >> 3, o = u & 7;
                uint4 v = *(const uint4*)(src + (long)u * 8);
                *(uint4*)(stage + (r * 128 + p) * 72 + o * 8) = v;
            }
        } else {
            uint4 zz = {0u, 0u, 0u, 0u};
            #pragma unroll
            for (int k = 0; k < 4; k++) {
                int u = k * 512 + tid;
                int p = u >> 3, o = u & 7;
                *(uint4*)(stage + (r * 128 + p) * 72 + o * 8) = zz;
            }
        }
    }
    __syncthreads();   // stage ready
    // dw conv 3x3 from LDS
    float accf[2][8];
    #pragma unroll
    for (int half = 0; half < 2; half++)
        #pragma unroll
        for (int jj = 0; jj < 8; jj++) accf[half][jj] = 0.f;
    #pragma unroll
    for (int r = 0; r < 3; r++) {
        #pragma unroll
        for (int kk = 0; kk < 3; kk++) {
            int col = p0 + pr - 1 + kk;
            if ((unsigned)col < 128u) {
                #pragma unroll
                for (int half = 0; half < 2; half++) {
                    int o = oct + half * 4;
                    uint4 d4 = *(const uint4*)(stage + (r * 128 + col) * 72 + o * 8);
                    float f[8]; unpack8(d4, f);
                    float4 wa = *(const float4*)(cbuf + (r * 3 + kk) * 64 + o * 8);
                    float4 wc = *(const float4*)(cbuf + (r * 3 + kk) * 64 + o * 8 + 4);
                    accf[half][0] += f[0] * wa.x; accf[half][1] += f[1] * wa.y;
                    accf[half][2] += f[2] * wa.z; accf[half][3] += f[3] * wa.w;
                    accf[half][4] += f[4] * wc.x; accf[half][5] += f[5] * wc.y;
                    accf[half][6] += f[6] * wc.z; accf[half][7] += f[7] * wc.w;
                }
            }
        }
    }
    bf16x8 af[2];
    #pragma unroll
    for (int half = 0; half < 2; half++) {
        int o = oct + half * 4;
        float4 oa = *(const float4*)(cbuf + 576 + o * 8);
        float4 ob = *(const float4*)(cbuf + 576 + o * 8 + 4);
        af[half][0] = (short)f2bf(fmaxf(accf[half][0] + oa.x, 0.f));
        af[half][1] = (short)f2bf(fmaxf(accf[half][1] + oa.y, 0.f));
        af[half][2] = (short)f2bf(fmaxf(accf[half][2] + oa.z, 0.f));
        af[half][3] = (short)f2bf(fmaxf(accf[half][3] + oa.w, 0.f));
        af[half][4] = (short)f2bf(fmaxf(accf[half][4] + ob.x, 0.f));
        af[half][5] = (short)f2bf(fmaxf(accf[half][5] + ob.y, 0.f));
        af[half][6] = (short)f2bf(fmaxf(accf[half][6] + ob.z, 0.f));
        af[half][7] = (short)f2bf(fmaxf(accf[half][7] + ob.w, 0.f));
    }
    __syncthreads();   // conv reads done
    // phase 3: pw GEMM -> y2buf (r0 region); transpose center row -> KT (r2 region, XOR-swizzled)
    short* y2buf = stage;
    short* KT = stage + 18432;
    {
        const unsigned short* pwb = wb + 16384;
        #pragma unroll
        for (int t4 = 0; t4 < 4; t4++) {
            int n = t4 * 16 + pr;
            floatx4 acc = {0.f, 0.f, 0.f, 0.f};
            acc = MFMA16(af[0], ldg8b(pwb + n * 64 + oct * 8), acc);
            acc = MFMA16(af[1], ldg8b(pwb + n * 64 + 32 + oct * 8), acc);
            float s2 = cbuf[640 + n], o2 = cbuf[704 + n];
            #pragma unroll
            for (int r = 0; r < 4; r++)
                y2buf[(p0 + oct * 4 + r) * 72 + n] = (short)f2bf(fmaxf(acc[r] * s2 + o2, 0.f));
        }
        // transpose: KT[c][n ^ (o<<3)] = key[h][n][c], c = o*8+j
        #pragma unroll
        for (int k = 0; k < 2; k++) {
            int u = k * 512 + tid;          // 1024 uint4
            int n = u >> 3, o = u & 7;
            uint4 v = *(const uint4*)(stage + (128 + n) * 72 + o * 8);
            int nx = n ^ (o << 3);
            KT[(o * 8 + 0) * 136 + nx] = (short)(v.x & 0xffff);
            KT[(o * 8 + 1) * 136 + nx] = (short)(v.x >> 16);
            KT[(o * 8 + 2) * 136 + nx] = (short)(v.y & 0xffff);
            KT[(o * 8 + 3) * 136 + nx] = (short)(v.y >> 16);
            KT[(o * 8 + 4) * 136 + nx] = (short)(v.z & 0xffff);
            KT[(o * 8 + 5) * 136 + nx] = (short)(v.z >> 16);
            KT[(o * 8 + 6) * 136 + nx] = (short)(v.w & 0xffff);
            KT[(o * 8 + 7) * 136 + nx] = (short)(v.w >> 16);
        }
    }
    __syncthreads();
    // phase 4: mask head + exp -> pbuf + zred
    {
        const unsigned short* mhb = wb + 20480;
        bf16x8 a0 = *(const bf16x8*)(y2buf + (p0 + pr) * 72 + oct * 8);
        bf16x8 a1 = *(const bf16x8*)(y2buf + (p0 + pr) * 72 + 32 + oct * 8);
        floatx4 lg = {0.f, 0.f, 0.f, 0.f};
        lg = MFMA16(a0, ldg8b(mhb + pr * 64 + oct * 8), lg);
        lg = MFMA16(a1, ldg8b(mhb + pr * 64 + 32 + oct * 8), lg);
        float zs = 0.f;
        #pragma unroll
        for (int r = 0; r < 4; r++) {
            float e = __expf(lg[r]);
            zs += e;
            pbuf[pr * 136 + p0 + oct * 4 + r] = (short)f2bf(e);
        }
        zs += __shfl_xor(zs, 16);
        zs += __shfl_xor(zs, 32);
        if (l < 16) zred[w][l] = zs;
    }
    __syncthreads();
    // phase 5: protos partial = E[16x128] @ K[128x64] (waves 0-3, c-tile = w) + Z atomic
    if (w < 4) {
        int ct = w;
        int c = ct * 16 + pr;
        int xrc = ((c >> 3) & 7) << 3;
        floatx4 acc = {0.f, 0.f, 0.f, 0.f};
        #pragma unroll
        for (int s = 0; s < 4; s++) {
            bf16x8 A = *(const bf16x8*)(pbuf + pr * 136 + s * 32 + oct * 8);
            bf16x8 B = *(const bf16x8*)(KT + c * 136 + ((s * 32 + oct * 8) ^ xrc));
            acc = MFMA16(A, B, acc);
        }
        #pragma unroll
        for (int r = 0; r < 4; r++)
            atomicAdd(protos + (b * 16 + oct * 4 + r) * 64 + c, acc[r]);
    }
    if (tid < 16) {
        float zt = 0.f;
        #pragma unroll
        for (int ww = 0; ww < 8; ww++) zt += zred[ww][tid];
        atomicAdd(Z + b * 16 + tid, zt);
    }
}

// ---------------------------------------------------------------- K6: MHA flash-decode partials (b,h,eighth)
__global__ __launch_bounds__(256) void k_mha(const float* __restrict__ qp,
                                             const unsigned short* __restrict__ kph,
                                             const unsigned short* __restrict__ vph,
                                             float* __restrict__ part) {
    int bh = blockIdx.x >> 3, seg = blockIdx.x & 7;
    int b = bh >> 3, hh = bh & 7;
    int tid = threadIdx.x;
    int q = tid >> 4, sub = tid & 15;
    const float* qv = qp + (long)(b * 16 + q) * 64 + hh * 8;
    float4 q0 = ((const float4*)qv)[0];
    float4 q1 = ((const float4*)qv)[1];
    const uint4* K4 = (const uint4*)kph + (long)bh * 4096;
    const uint4* V4 = (const uint4*)vph + (long)bh * 4096;
    const float scale = 0.35355339059327373f;
    float m = -1e30f, lsum = 0.f;
    float acc[8];
    #pragma unroll
    for (int d = 0; d < 8; d++) acc[d] = 0.f;
    for (int i = 0; i < 32; i++) {
        int n = seg * 512 + i * 16 + sub;
        float k8[8]; unpack8(K4[n], k8);
        float s = q0.x * k8[0] + q0.y * k8[1] + q0.z * k8[2] + q0.w * k8[3]
                + q1.x * k8[4] + q1.y * k8[5] + q1.z * k8[6] + q1.w * k8[7];
        s *= scale;
        float nm = fmaxf(m, s);
        float corr = __expf(m - nm);
        float wgt = __expf(s - nm);
        lsum = lsum * corr + wgt;
        float v8[8]; unpack8(V4[n], v8);
        #pragma unroll
        for (int d = 0; d < 8; d++) acc[d] = acc[d] * corr + wgt * v8[d];
        m = nm;
    }
    #pragma unroll
    for (int off = 1; off < 16; off <<= 1) {
        float om = __shfl_xor(m, off);
        float ol = __shfl_xor(lsum, off);
        float oa[8];
        #pragma unroll
        for (int d = 0; d < 8; d++) oa[d] = __shfl_xor(acc[d], off);
        float nm = fmaxf(m, om);
        float c1 = __expf(m - nm), c2 = __expf(om - nm);
        lsum = lsum * c1 + ol * c2;
        #pragma unroll
        for (int d = 0; d < 8; d++) acc[d] = acc[d] * c1 + oa[d] * c2;
        m = nm;
    }
    if (sub == 0) {
        float* P = part + ((long)(bh * 16 + q) * 8 + seg) * 12;
        P[0] = m; P[1] = lsum;
        #pragma unroll
        for (int d = 0; d < 8; d++) P[2 + d] = acc[d];
    }
}

// ---------------------------------------------------------------- K7: epilogue — merge MHA, mscw2, LNs (transposed weights)
__global__ __launch_bounds__(1024) void k_final(
        const float* __restrict__ queryb, const float* __restrict__ protos,
        const float* __restrict__ Z, const float* __restrict__ part,
        const float* __restrict__ cst,
        const float* __restrict__ b_out,
        const float* __restrict__ ln1_g, const float* __restrict__ ln1_b,
        const float* __restrict__ ln2_g, const float* __restrict__ ln2_b,
        const float* __restrict__ lb1, const float* __restrict__ lb2,
        const float* __restrict__ gb1, const float* __restrict__ gb2,
        float* __restrict__ out) {
    const float* gw1T = cst + 8960;    // m2_gw1T
    const float* gw2T = cst + 13056;   // m2_gw2T
    const float* lw1T = cst + 17152;   // m2_lw1T
    const float* lw2T = cst + 21248;   // m2_lw2T
    const float* woT  = cst + 25344;   // w_outT
    int b = blockIdx.x;
    int t = threadIdx.x >> 6;
    int c = threadIdx.x & 63;
    __shared__ float xs[16][64], hid[16][64], os[16][64];
    __shared__ float pool[64], hidg[64], glo[64];
    float q = queryb[(long)(b * 16 + t) * 64 + c];
    float rz = 1.f / Z[b * 16 + t];
    float xin = protos[(long)(b * 16 + t) * 64 + c] * rz + q;
    xs[t][c] = xin;
    {
        int hh = c >> 3, d = c & 7;
        const float* P = part + ((long)((b * 8 + hh) * 16 + t) * 8) * 12;
        float mm = -1e30f, ll = 0.f, aa = 0.f;
        #pragma unroll
        for (int s = 0; s < 8; s++) {
            float pm = P[s * 12], pl2 = P[s * 12 + 1], pa = P[s * 12 + 2 + d];
            float nm = fmaxf(mm, pm);
            float c1 = __expf(mm - nm), c2 = __expf(pm - nm);
            aa = aa * c1 + pa * c2;
            ll = ll * c1 + pl2 * c2;
            mm = nm;
        }
        os[t][c] = aa / ll;
    }
    __syncthreads();
    if (threadIdx.x < 64) {
        float s = 0.f;
        for (int tt = 0; tt < 16; tt++) s += xs[tt][threadIdx.x];
        pool[threadIdx.x] = s * (1.f / 16.f);
    }
    __syncthreads();
    if (threadIdx.x < 64) {
        int hh = threadIdx.x;
        float a = gb1[hh];
        for (int cc = 0; cc < 64; cc++) a += pool[cc] * gw1T[cc * 64 + hh];
        hidg[hh] = fmaxf(a, 0.f);
    }
    __syncthreads();
    if (threadIdx.x < 64) {
        int ccc = threadIdx.x;
        float a = gb2[ccc];
        for (int hh = 0; hh < 64; hh++) a += hidg[hh] * gw2T[hh * 64 + ccc];
        glo[ccc] = a;
    }
    float a = lb1[c];
    for (int cc = 0; cc < 64; cc++) a += xs[t][cc] * lw1T[cc * 64 + c];
    hid[t][c] = fmaxf(a, 0.f);
    __syncthreads();
    float loc = lb2[c];
    for (int hh = 0; hh < 64; hh++) loc += hid[t][hh] * lw2T[hh * 64 + c];
    float attn2 = sigmoidf_(loc + glo[c]);
    float x2p = q * attn2 + q;
    float mu = x2p;
    for (int off = 32; off; off >>= 1) mu += __shfl_down(mu, off);
    mu = __shfl(mu, 0) * (1.f / 64.f);
    float d0 = x2p - mu;
    float vv = d0 * d0;
    for (int off = 32; off; off >>= 1) vv += __shfl_down(vv, off);
    vv = __shfl(vv, 0) * (1.f / 64.f);
    float x2 = d0 * rsqrtf(vv + 1e-5f) * ln2_g[c] + ln2_b[c];
    float x1p = b_out[c];
    for (int k = 0; k < 64; k++) x1p += os[t][k] * woT[k * 64 + c];
    x1p += q;
    float mu1 = x1p;
    for (int off = 32; off; off >>= 1) mu1 += __shfl_down(mu1, off);
    mu1 = __shfl(mu1, 0) * (1.f / 64.f);
    float d1 = x1p - mu1;
    float v1 = d1 * d1;
    for (int off = 32; off; off >>= 1) v1 += __shfl_down(v1, off);
    v1 = __shfl(v1, 0) * (1.f / 64.f);
    float x1 = d1 * rsqrtf(v1 + 1e-5f) * ln1_g[c] + ln1_b[c];
    out[((long)t * 8 + b) * 64 + c] = x1 + x2;
}

// ----------------------------------------------------------------
extern "C" void kernel_launch(void* const* d_in, const int* in_sizes, int n_in,
                              void* d_out, int out_size, void* d_ws, size_t ws_size,
                              hipStream_t stream) {
    const float* tgt       = (const float*)d_in[0];
    const float* memory    = (const float*)d_in[1];
    const float* pos       = (const float*)d_in[2];
    const float* query_pos = (const float*)d_in[3];
    const float* w_in      = (const float*)d_in[4];
    const float* b_in      = (const float*)d_in[5];
    const float* w_out     = (const float*)d_in[6];
    const float* b_out     = (const float*)d_in[7];
    const float* ln1_g     = (const float*)d_in[8];
    const float* ln1_b     = (const float*)d_in[9];
    const float* ln2_g     = (const float*)d_in[10];
    const float* ln2_b     = (const float*)d_in[11];
    const float* dw_w      = (const float*)d_in[12];
    const float* bn1_g     = (const float*)d_in[13];
    const float* bn1_b     = (const float*)d_in[14];
    const float* bn1_m     = (const float*)d_in[15];
    const float* bn1_v     = (const float*)d_in[16];
    const float* pw_w      = (const float*)d_in[17];
    const float* bn2_g     = (const float*)d_in[18];
    const float* bn2_b     = (const float*)d_in[19];
    const float* bn2_m     = (const float*)d_in[20];
    const float* bn2_v     = (const float*)d_in[21];
    const float* mheads    = (const float*)d_in[22];
    const float* m1_lw1 = (const float*)d_in[23];
    const float* m1_lb1 = (const float*)d_in[24];
    const float* m1_lw2 = (const float*)d_in[25];
    const float* m1_lb2 = (const float*)d_in[26];
    const float* m1_gw1 = (const float*)d_in[27];
    const float* m1_gb1 = (const float*)d_in[28];
    const float* m1_gw2 = (const float*)d_in[29];
    const float* m1_gb2 = (const float*)d_in[30];
    const float* m2_lw1 = (const float*)d_in[31];
    const float* m2_lb1 = (const float*)d_in[32];
    const float* m2_lw2 = (const float*)d_in[33];
    const float* m2_lb2 = (const float*)d_in[34];
    const float* m2_gw1 = (const float*)d_in[35];
    const float* m2_gb1 = (const float*)d_in[36];
    const float* m2_gw2 = (const float*)d_in[37];
    const float* m2_gb2 = (const float*)d_in[38];

    float* ws = (float*)d_ws;
    float* out = (float*)d_out;
    unsigned short* keyb = (unsigned short*)(ws + OFF_KEY);
    unsigned short* kph  = (unsigned short*)(ws + OFF_KPH);
    unsigned short* vph  = (unsigned short*)(ws + OFF_VPH);
    unsigned short* wb   = (unsigned short*)(ws + OFF_WB);

    // zero atomic regions (pool + protos + Z, contiguous)
    hipMemsetAsync(ws + OFF_POOL, 0, 8832 * sizeof(float), stream);

    k_prep<<<231, 256, 0, stream>>>(m1_lw1, m1_lw2, w_in, pw_w, mheads, dw_w,
                                    bn1_g, bn1_b, bn1_m, bn1_v,
                                    bn2_g, bn2_b, bn2_m, bn2_v,
                                    m1_gw1, m1_gw2, m2_gw1, m2_gw2,
                                    m2_lw1, m2_lw2, w_out,
                                    tgt, query_pos, b_in,
                                    wb, ws + OFF_CST, ws + OFF_QP, ws + OFF_QB);
    k_key<<<4096, 256, 0, stream>>>(memory, pos, keyb, ws + OFF_POOL);
    k_mscw1<<<512, 256, 0, stream>>>(keyb, ws + OFF_POOL, m1_lb1, m1_lb2,
                                     m1_gb1, m1_gb2, b_in, wb, ws + OFF_CST, kph, vph);
    k_dsconv<<<1024, 512, 0, stream>>>(keyb, wb, ws + OFF_CST,
                                       ws + OFF_PROT, ws + OFF_ZZ);
    k_mha<<<512, 256, 0, stream>>>(ws + OFF_QP, kph, vph, ws + OFF_PART);
    k_final<<<8, 1024, 0, stream>>>(ws + OFF_QB, ws + OFF_PROT, ws + OFF_ZZ, ws + OFF_PART,
                                    ws + OFF_CST, b_out,
                                    ln1_g, ln1_b, ln2_g, ln2_b,
                                    m2_lb1, m2_lb2, m2_gb1, m2_gb2,
                                    out);
}

// Round 6
// 243.401 us; speedup vs baseline: 1.5425x; 1.0178x over previous
//
#include <hip/hip_runtime.h>
#include <math.h>

#define N1 16384
#define N2 4096

// Workspace layout (float offsets)
#define OFF_KEY   0L            // key bf16 [B][N1][64] = 8,388,608 shorts
#define OFF_KPH   4194304L      // kp bf16 [B*H][4096][8]
#define OFF_VPH   5242880L
#define OFF_WB    6291456L      // bf16 weights (21504 shorts)
#define OFF_CST   6302208L      // fp32: dwTf[576],o1[64],s2[64],o2[64], then 7x4096 transposed mats
#define OFF_POOL  6331648L      // 512  (zeroed)
#define OFF_PROT  6332160L      // 8192 (zeroed)
#define OFF_ZZ    6340352L      // 128  (zeroed)
#define OFF_QP    6340480L
#define OFF_QB    6348672L
#define OFF_PART  6356864L      // [B*H][16 q][8 seg][12]

typedef __attribute__((ext_vector_type(8))) short bf16x8;
typedef __attribute__((ext_vector_type(4))) float floatx4;

#define MFMA16(a, b, c) __builtin_amdgcn_mfma_f32_16x16x32_bf16(a, b, c, 0, 0, 0)

__device__ __forceinline__ unsigned short f2bf(float f) {
    union { float f; unsigned u; } v; v.f = f;
    unsigned r = v.u + 0x7fffu + ((v.u >> 16) & 1u);
    return (unsigned short)(r >> 16);
}
__device__ __forceinline__ float bf2f(unsigned short s) {
    union { unsigned u; float f; } v; v.u = ((unsigned)s) << 16;
    return v.f;
}
__device__ __forceinline__ float sigmoidf_(float x) { return 1.f / (1.f + __expf(-x)); }
__device__ __forceinline__ bf16x8 ldg8b(const unsigned short* p) { return *(const bf16x8*)p; }
__device__ __forceinline__ void unpack8(uint4 v, float* f) {
    f[0] = bf2f((unsigned short)(v.x & 0xffff)); f[1] = bf2f((unsigned short)(v.x >> 16));
    f[2] = bf2f((unsigned short)(v.y & 0xffff)); f[3] = bf2f((unsigned short)(v.y >> 16));
    f[4] = bf2f((unsigned short)(v.z & 0xffff)); f[5] = bf2f((unsigned short)(v.z >> 16));
    f[6] = bf2f((unsigned short)(v.w & 0xffff)); f[7] = bf2f((unsigned short)(v.w >> 16));
}

// ---------------------------------------------------------------- stage1: key+pool (blocks 0..4095) | prep (4096..4326)
__global__ __launch_bounds__(256) void k_stage1(
        const float* __restrict__ mem, const float* __restrict__ pos,
        const float* __restrict__ m1lw1, const float* __restrict__ m1lw2,
        const float* __restrict__ w_in, const float* __restrict__ pw,
        const float* __restrict__ mh, const float* __restrict__ dw_w,
        const float* __restrict__ bn1_g, const float* __restrict__ bn1_b,
        const float* __restrict__ bn1_m, const float* __restrict__ bn1_v,
        const float* __restrict__ bn2_g, const float* __restrict__ bn2_b,
        const float* __restrict__ bn2_m, const float* __restrict__ bn2_v,
        const float* __restrict__ m1gw1, const float* __restrict__ m1gw2,
        const float* __restrict__ m2gw1, const float* __restrict__ m2gw2,
        const float* __restrict__ m2lw1, const float* __restrict__ m2lw2,
        const float* __restrict__ w_out,
        const float* __restrict__ tgt, const float* __restrict__ qpos,
        const float* __restrict__ b_in,
        unsigned short* __restrict__ key, float* __restrict__ pool1raw,
        unsigned short* __restrict__ wb, float* __restrict__ cst,
        float* __restrict__ qp, float* __restrict__ queryb) {
    int tid = threadIdx.x;
    if (blockIdx.x < 4096) {
        __shared__ float sh[16][64];
        int b = blockIdx.x >> 9;
        int n_base = (blockIdx.x & 511) * 32;
        int c8 = tid & 7, local_n = tid >> 3;
        int n = n_base + local_n;
        long s4 = ((long)n * 8 + b) * 16 + c8 * 2;
        float4 m0 = ((const float4*)mem)[s4], m1 = ((const float4*)mem)[s4 + 1];
        float4 p0 = ((const float4*)pos)[s4], p1 = ((const float4*)pos)[s4 + 1];
        float f[8];
        f[0] = m0.x + p0.x; f[1] = m0.y + p0.y; f[2] = m0.z + p0.z; f[3] = m0.w + p0.w;
        f[4] = m1.x + p1.x; f[5] = m1.y + p1.y; f[6] = m1.z + p1.z; f[7] = m1.w + p1.w;
        uint4 o;
        o.x = (unsigned)f2bf(f[0]) | ((unsigned)f2bf(f[1]) << 16);
        o.y = (unsigned)f2bf(f[2]) | ((unsigned)f2bf(f[3]) << 16);
        o.z = (unsigned)f2bf(f[4]) | ((unsigned)f2bf(f[5]) << 16);
        o.w = (unsigned)f2bf(f[6]) | ((unsigned)f2bf(f[7]) << 16);
        ((uint4*)key)[(long)(b * 16384 + n) * 8 + c8] = o;
        int parity = (n_base >> 7) & 1;
        if (parity) {
            if (local_n & 1) {
                #pragma unroll
                for (int j = 0; j < 8; j++) sh[local_n >> 1][c8 * 8 + j] = f[j];
            }
            __syncthreads();
            if (tid < 64) {
                float s = 0.f;
                #pragma unroll
                for (int k = 0; k < 16; k++) s += sh[k][tid];
                atomicAdd(pool1raw + b * 64 + tid, s);
            }
        }
        return;
    }
    int blk = blockIdx.x - 4096;
    if (blk < 84) {
        int i = blk * 256 + tid;
        float v;
        if (i < 4096) v = m1lw1[i];
        else if (i < 8192) v = m1lw2[i - 4096];
        else if (i < 16384) v = w_in[4096 + (i - 8192)];
        else if (i < 20480) v = pw[i - 16384];
        else v = mh[i - 20480];
        wb[i] = f2bf(v);
    } else if (blk < 199) {
        int j = (blk - 84) * 256 + tid;   // < 29440
        float v;
        if (j < 576) {
            int k = j >> 6, c = j & 63;
            float s1 = bn1_g[c] * rsqrtf(bn1_v[c] + 1e-5f);
            v = dw_w[c * 9 + k] * s1;
        } else if (j < 640) {
            int c = j - 576;
            float s1 = bn1_g[c] * rsqrtf(bn1_v[c] + 1e-5f);
            v = bn1_b[c] - bn1_m[c] * s1;
        } else if (j < 704) {
            int c = j - 640;
            v = bn2_g[c] * rsqrtf(bn2_v[c] + 1e-5f);
        } else if (j < 768) {
            int c = j - 704;
            float s2 = bn2_g[c] * rsqrtf(bn2_v[c] + 1e-5f);
            v = bn2_b[c] - bn2_m[c] * s2;
        } else {
            int jj = j - 768;
            int m = jj >> 12, idx = jj & 4095;
            int sidx = (idx & 63) * 64 + (idx >> 6);   // transpose
            const float* src;
            switch (m) {
                case 0: src = m1gw1; break;
                case 1: src = m1gw2; break;
                case 2: src = m2gw1; break;
                case 3: src = m2gw2; break;
                case 4: src = m2lw1; break;
                case 5: src = m2lw2; break;
                default: src = w_out; break;
            }
            v = src[sidx];
        }
        cst[j] = v;
    } else {
        __shared__ float qv[4][64];
        int g = tid >> 6, lane = tid & 63;
        int u = (blk - 199) * 4 + g;
        int b = u >> 4, q = u & 15;
        long src = ((long)q * 8 + b) * 64 + lane;
        float v = tgt[src] + qpos[src];
        qv[g][lane] = v;
        queryb[(b * 16 + q) * 64 + lane] = v;
        __syncthreads();
        float acc = b_in[lane];
        for (int cc = 0; cc < 64; cc++) acc += qv[g][cc] * w_in[lane * 64 + cc];
        qp[(b * 16 + q) * 64 + lane] = acc;
    }
}

// ---------------------------------------------------------------- stage2: mscw1 (blocks 0..511) | dsconv (512..1535)
__global__ __launch_bounds__(512) void k_stage2(
        const unsigned short* __restrict__ keyb,
        const float* __restrict__ pool1raw,
        const float* __restrict__ lb1, const float* __restrict__ lb2,
        const float* __restrict__ gb1, const float* __restrict__ gb2,
        const float* __restrict__ b_in,
        const unsigned short* __restrict__ wb,
        const float* __restrict__ cst,
        unsigned short* __restrict__ kph, unsigned short* __restrict__ vph,
        float* __restrict__ protos, float* __restrict__ Z) {
    __shared__ __align__(16) char smem[63488];
    int tid = threadIdx.x;
    int w = tid >> 6, l = tid & 63;
    if (blockIdx.x < 512) {
        // ---------------- mscw1: 8 waves, wave-pairs split column tiles
        short* stage = (short*)smem;               // 256*72 shorts
        short* hbuf  = (short*)(smem + 36864);     // 64*72
        short* wbuf  = (short*)(smem + 46080);     // 64*72
        float* parr  = (float*)(smem + 55296);
        float* gtmp  = parr + 64;
        float* gbuf  = parr + 128;
        int b = blockIdx.x >> 6, tile = blockIdx.x & 63;
        int pairw = w >> 1, ch2 = w & 1;
        int m0 = pairw * 16, trow = l & 15, oct = l >> 4;
        const float* gw1T = cst + 768;
        const float* gw2T = cst + 4864;
        if (tid < 64) parr[tid] = pool1raw[b * 64 + tid] * (2.0f / 4096.0f);
        const unsigned short* src = keyb + ((long)b * 16384 + tile * 256) * 64;
        #pragma unroll
        for (int k = 0; k < 4; k++) {
            int u = k * 512 + tid;          // 2048 uint4
            int p = u >> 3, o = u & 7;
            uint4 v = *(const uint4*)(src + (long)u * 8);
            *(uint4*)(stage + p * 72 + o * 8) = v;
        }
        __syncthreads();   // sync1
        if (tid < 64) {
            float a = gb1[tid];
            for (int cc = 0; cc < 64; cc++) a += parr[cc] * gw1T[cc * 64 + tid];
            gtmp[tid] = fmaxf(a, 0.f);
        }
        int j = m0 + trow;
        float x[16], S[16];
        bf16x8 ax[2];
        #pragma unroll
        for (int half = 0; half < 2; half++) {
            int o = oct + half * 4;
            uint4 fa4 = *(const uint4*)(stage + (2 * j) * 72 + o * 8);
            uint4 fb4 = *(const uint4*)(stage + (2 * j + 1) * 72 + o * 8);
            uint4 fc4 = *(const uint4*)(stage + (128 + 2 * j) * 72 + o * 8);
            uint4 fd4 = *(const uint4*)(stage + (129 + 2 * j) * 72 + o * 8);
            float A[8], B[8], C[8], D[8];
            unpack8(fa4, A); unpack8(fb4, B); unpack8(fc4, C); unpack8(fd4, D);
            #pragma unroll
            for (int jj = 0; jj < 8; jj++) {
                float xd = 2.f * D[jj];
                x[half * 8 + jj] = xd;
                S[half * 8 + jj] = 0.5f * (A[jj] + B[jj] + C[jj] + D[jj]);
                ax[half][jj] = (short)f2bf(xd);
            }
        }
        const unsigned short* w1b = wb;
        const unsigned short* w2b = wb + 4096;
        const unsigned short* wkb = wb + 8192;
        const unsigned short* wvb = wb + 12288;
        // G1: hid = relu(x @ w1^T + b1), col tiles split by ch2
        #pragma unroll
        for (int t4i = 0; t4i < 2; t4i++) {
            int n = (ch2 * 2 + t4i) * 16 + trow;
            float bias = lb1[n];
            floatx4 acc = {bias, bias, bias, bias};
            acc = MFMA16(ax[0], ldg8b(w1b + n * 64 + oct * 8), acc);
            acc = MFMA16(ax[1], ldg8b(w1b + n * 64 + 32 + oct * 8), acc);
            #pragma unroll
            for (int r = 0; r < 4; r++)
                hbuf[(m0 + oct * 4 + r) * 72 + n] = (short)f2bf(fmaxf(acc[r], 0.f));
        }
        __syncthreads();   // sync2
        if (tid < 64) {
            float g = gb2[tid];
            for (int hh = 0; hh < 64; hh++) g += gtmp[hh] * gw2T[hh * 64 + tid];
            gbuf[tid] = g;
        }
        __syncthreads();   // sync2b
        // G2: wei = sigmoid(hid @ w2^T + b2 + glo)
        {
            bf16x8 ah0 = *(const bf16x8*)(hbuf + (m0 + trow) * 72 + oct * 8);
            bf16x8 ah1 = *(const bf16x8*)(hbuf + (m0 + trow) * 72 + 32 + oct * 8);
            #pragma unroll
            for (int t4i = 0; t4i < 2; t4i++) {
                int n = (ch2 * 2 + t4i) * 16 + trow;
                float bias = lb2[n];
                floatx4 acc = {bias, bias, bias, bias};
                acc = MFMA16(ah0, ldg8b(w2b + n * 64 + oct * 8), acc);
                acc = MFMA16(ah1, ldg8b(w2b + n * 64 + 32 + oct * 8), acc);
                float g = gbuf[n];
                #pragma unroll
                for (int r = 0; r < 4; r++)
                    wbuf[(m0 + oct * 4 + r) * 72 + n] = (short)f2bf(sigmoidf_(acc[r] + g));
            }
        }
        __syncthreads();   // sync3
        bf16x8 af0, af1;
        {
            bf16x8 w0 = *(const bf16x8*)(wbuf + (m0 + trow) * 72 + oct * 8);
            bf16x8 w1v = *(const bf16x8*)(wbuf + (m0 + trow) * 72 + 32 + oct * 8);
            #pragma unroll
            for (int jj = 0; jj < 8; jj++) {
                float we0 = bf2f((unsigned short)w0[jj]);
                float we1 = bf2f((unsigned short)w1v[jj]);
                af0[jj] = (short)f2bf(we0 * x[jj] + (1.f - we0) * S[jj]);
                af1[jj] = (short)f2bf(we1 * x[8 + jj] + (1.f - we1) * S[8 + jj]);
            }
        }
        __syncthreads();   // sync4: reuse hbuf/wbuf as kbuf/vbuf
        short* kbuf = hbuf; short* vbuf = wbuf;
        #pragma unroll
        for (int t4i = 0; t4i < 2; t4i++) {
            int ko = (ch2 * 2 + t4i) * 16 + trow;
            float bk = b_in[64 + ko], bv = b_in[128 + ko];
            floatx4 ak = {bk, bk, bk, bk};
            floatx4 av = {bv, bv, bv, bv};
            ak = MFMA16(af0, ldg8b(wkb + ko * 64 + oct * 8), ak);
            ak = MFMA16(af1, ldg8b(wkb + ko * 64 + 32 + oct * 8), ak);
            av = MFMA16(af0, ldg8b(wvb + ko * 64 + oct * 8), av);
            av = MFMA16(af1, ldg8b(wvb + ko * 64 + 32 + oct * 8), av);
            #pragma unroll
            for (int r = 0; r < 4; r++) {
                int row = m0 + oct * 4 + r;
                kbuf[row * 72 + ko] = (short)f2bf(ak[r]);
                vbuf[row * 72 + ko] = (short)f2bf(av[r]);
            }
        }
        __syncthreads();   // sync5
        {
            int h = tid >> 6, tok = tid & 63;
            uint4 kk = *(const uint4*)(kbuf + tok * 72 + h * 8);
            uint4 vv = *(const uint4*)(vbuf + tok * 72 + h * 8);
            long du = (long)(b * 8 + h) * 4096 + tile * 64 + tok;
            ((uint4*)kph)[du] = kk;
            ((uint4*)vph)[du] = vv;
        }
        return;
    }
    // ---------------- dsconv: blocks 512..1535
    {
        short* stage = (short*)smem;                       // 3*128*72
        short* pbuf  = (short*)(smem + 55296);             // 16*136
        float* cbuf  = (float*)(smem + 55296 + 4352);      // 768
        float* zred  = (float*)(smem + 55296 + 4352 + 3072); // [8][16]
        int blk = blockIdx.x - 512;
        int b = blk >> 7, h = blk & 127;
        int p0 = w * 16, pr = l & 15, oct = l >> 4;
        for (int k = tid; k < 768; k += 512) cbuf[k] = cst[k];
        const unsigned short* kb = keyb + (long)b * 1048576;
        #pragma unroll
        for (int r = 0; r < 3; r++) {
            int row = h - 1 + r;
            if ((unsigned)row < 128u) {
                const unsigned short* src = kb + (long)row * 8192;
                #pragma unroll
                for (int k = 0; k < 2; k++) {       // FIXED: 1024 uint4 per row, not 2048
                    int u = k * 512 + tid;
                    int p = u >> 3, o = u & 7;
                    uint4 v = *(const uint4*)(src + (long)u * 8);
                    *(uint4*)(stage + (r * 128 + p) * 72 + o * 8) = v;
                }
            } else {
                uint4 zz = {0u, 0u, 0u, 0u};
                #pragma unroll
                for (int k = 0; k < 2; k++) {
                    int u = k * 512 + tid;
                    int p = u >> 3, o = u & 7;
                    *(uint4*)(stage + (r * 128 + p) * 72 + o * 8) = zz;
                }
            }
        }
        __syncthreads();
        // dw conv 3x3 from LDS
        float accf[2][8];
        #pragma unroll
        for (int half = 0; half < 2; half++)
            #pragma unroll
            for (int jj = 0; jj < 8; jj++) accf[half][jj] = 0.f;
        #pragma unroll
        for (int r = 0; r < 3; r++) {
            #pragma unroll
            for (int kk = 0; kk < 3; kk++) {
                int col = p0 + pr - 1 + kk;
                if ((unsigned)col < 128u) {
                    #pragma unroll
                    for (int half = 0; half < 2; half++) {
                        int o = oct + half * 4;
                        uint4 d4 = *(const uint4*)(stage + (r * 128 + col) * 72 + o * 8);
                        float f[8]; unpack8(d4, f);
                        float4 wa = *(const float4*)(cbuf + (r * 3 + kk) * 64 + o * 8);
                        float4 wc = *(const float4*)(cbuf + (r * 3 + kk) * 64 + o * 8 + 4);
                        accf[half][0] += f[0] * wa.x; accf[half][1] += f[1] * wa.y;
                        accf[half][2] += f[2] * wa.z; accf[half][3] += f[3] * wa.w;
                        accf[half][4] += f[4] * wc.x; accf[half][5] += f[5] * wc.y;
                        accf[half][6] += f[6] * wc.z; accf[half][7] += f[7] * wc.w;
                    }
                }
            }
        }
        bf16x8 af[2];
        #pragma unroll
        for (int half = 0; half < 2; half++) {
            int o = oct + half * 4;
            float4 oa = *(const float4*)(cbuf + 576 + o * 8);
            float4 ob = *(const float4*)(cbuf + 576 + o * 8 + 4);
            af[half][0] = (short)f2bf(fmaxf(accf[half][0] + oa.x, 0.f));
            af[half][1] = (short)f2bf(fmaxf(accf[half][1] + oa.y, 0.f));
            af[half][2] = (short)f2bf(fmaxf(accf[half][2] + oa.z, 0.f));
            af[half][3] = (short)f2bf(fmaxf(accf[half][3] + oa.w, 0.f));
            af[half][4] = (short)f2bf(fmaxf(accf[half][4] + ob.x, 0.f));
            af[half][5] = (short)f2bf(fmaxf(accf[half][5] + ob.y, 0.f));
            af[half][6] = (short)f2bf(fmaxf(accf[half][6] + ob.z, 0.f));
            af[half][7] = (short)f2bf(fmaxf(accf[half][7] + ob.w, 0.f));
        }
        __syncthreads();   // conv reads done
        short* y2buf = stage;
        short* KT = stage + 18432;
        {
            const unsigned short* pwb = wb + 16384;
            #pragma unroll
            for (int t4 = 0; t4 < 4; t4++) {
                int n = t4 * 16 + pr;
                floatx4 acc = {0.f, 0.f, 0.f, 0.f};
                acc = MFMA16(af[0], ldg8b(pwb + n * 64 + oct * 8), acc);
                acc = MFMA16(af[1], ldg8b(pwb + n * 64 + 32 + oct * 8), acc);
                float s2 = cbuf[640 + n], o2 = cbuf[704 + n];
                #pragma unroll
                for (int r = 0; r < 4; r++)
                    y2buf[(p0 + oct * 4 + r) * 72 + n] = (short)f2bf(fmaxf(acc[r] * s2 + o2, 0.f));
            }
            // transpose center row -> KT[c][n ^ (o<<3)]
            #pragma unroll
            for (int k = 0; k < 2; k++) {
                int u = k * 512 + tid;          // 1024 uint4
                int n = u >> 3, o = u & 7;
                uint4 v = *(const uint4*)(stage + (128 + n) * 72 + o * 8);
                int nx = n ^ (o << 3);
                KT[(o * 8 + 0) * 136 + nx] = (short)(v.x & 0xffff);
                KT[(o * 8 + 1) * 136 + nx] = (short)(v.x >> 16);
                KT[(o * 8 + 2) * 136 + nx] = (short)(v.y & 0xffff);
                KT[(o * 8 + 3) * 136 + nx] = (short)(v.y >> 16);
                KT[(o * 8 + 4) * 136 + nx] = (short)(v.z & 0xffff);
                KT[(o * 8 + 5) * 136 + nx] = (short)(v.z >> 16);
                KT[(o * 8 + 6) * 136 + nx] = (short)(v.w & 0xffff);
                KT[(o * 8 + 7) * 136 + nx] = (short)(v.w >> 16);
            }
        }
        __syncthreads();
        // mask head + exp
        {
            const unsigned short* mhb = wb + 20480;
            bf16x8 a0 = *(const bf16x8*)(y2buf + (p0 + pr) * 72 + oct * 8);
            bf16x8 a1 = *(const bf16x8*)(y2buf + (p0 + pr) * 72 + 32 + oct * 8);
            floatx4 lg = {0.f, 0.f, 0.f, 0.f};
            lg = MFMA16(a0, ldg8b(mhb + pr * 64 + oct * 8), lg);
            lg = MFMA16(a1, ldg8b(mhb + pr * 64 + 32 + oct * 8), lg);
            float zs = 0.f;
            #pragma unroll
            for (int r = 0; r < 4; r++) {
                float e = __expf(lg[r]);
                zs += e;
                pbuf[pr * 136 + p0 + oct * 4 + r] = (short)f2bf(e);
            }
            zs += __shfl_xor(zs, 16);
            zs += __shfl_xor(zs, 32);
            if (l < 16) zred[w * 16 + l] = zs;
        }
        __syncthreads();
        // protos partial (waves 0-3) + Z atomic
        if (w < 4) {
            int c = w * 16 + pr;
            int xrc = ((c >> 3) & 7) << 3;
            floatx4 acc = {0.f, 0.f, 0.f, 0.f};
            #pragma unroll
            for (int s = 0; s < 4; s++) {
                bf16x8 A = *(const bf16x8*)(pbuf + pr * 136 + s * 32 + oct * 8);
                bf16x8 B = *(const bf16x8*)(KT + c * 136 + ((s * 32 + oct * 8) ^ xrc));
                acc = MFMA16(A, B, acc);
            }
            #pragma unroll
            for (int r = 0; r < 4; r++)
                atomicAdd(protos + (b * 16 + oct * 4 + r) * 64 + c, acc[r]);
        }
        if (tid < 16) {
            float zt = 0.f;
            #pragma unroll
            for (int ww = 0; ww < 8; ww++) zt += zred[ww * 16 + tid];
            atomicAdd(Z + b * 16 + tid, zt);
        }
    }
}

// ---------------------------------------------------------------- K6: MHA flash-decode partials (b,h,eighth)
__global__ __launch_bounds__(256) void k_mha(const float* __restrict__ qp,
                                             const unsigned short* __restrict__ kph,
                                             const unsigned short* __restrict__ vph,
                                             float* __restrict__ part) {
    int bh = blockIdx.x >> 3, seg = blockIdx.x & 7;
    int b = bh >> 3, hh = bh & 7;
    int tid = threadIdx.x;
    int q = tid >> 4, sub = tid & 15;
    const float* qv = qp + (long)(b * 16 + q) * 64 + hh * 8;
    float4 q0 = ((const float4*)qv)[0];
    float4 q1 = ((const float4*)qv)[1];
    const uint4* K4 = (const uint4*)kph + (long)bh * 4096;
    const uint4* V4 = (const uint4*)vph + (long)bh * 4096;
    const float scale = 0.35355339059327373f;
    float m = -1e30f, lsum = 0.f;
    float acc[8];
    #pragma unroll
    for (int d = 0; d < 8; d++) acc[d] = 0.f;
    for (int i = 0; i < 32; i++) {
        int n = seg * 512 + i * 16 + sub;
        float k8[8]; unpack8(K4[n], k8);
        float s = q0.x * k8[0] + q0.y * k8[1] + q0.z * k8[2] + q0.w * k8[3]
                + q1.x * k8[4] + q1.y * k8[5] + q1.z * k8[6] + q1.w * k8[7];
        s *= scale;
        float nm = fmaxf(m, s);
        float corr = __expf(m - nm);
        float wgt = __expf(s - nm);
        lsum = lsum * corr + wgt;
        float v8[8]; unpack8(V4[n], v8);
        #pragma unroll
        for (int d = 0; d < 8; d++) acc[d] = acc[d] * corr + wgt * v8[d];
        m = nm;
    }
    #pragma unroll
    for (int off = 1; off < 16; off <<= 1) {
        float om = __shfl_xor(m, off);
        float ol = __shfl_xor(lsum, off);
        float oa[8];
        #pragma unroll
        for (int d = 0; d < 8; d++) oa[d] = __shfl_xor(acc[d], off);
        float nm = fmaxf(m, om);
        float c1 = __expf(m - nm), c2 = __expf(om - nm);
        lsum = lsum * c1 + ol * c2;
        #pragma unroll
        for (int d = 0; d < 8; d++) acc[d] = acc[d] * c1 + oa[d] * c2;
        m = nm;
    }
    if (sub == 0) {
        float* P = part + ((long)(bh * 16 + q) * 8 + seg) * 12;
        P[0] = m; P[1] = lsum;
        #pragma unroll
        for (int d = 0; d < 8; d++) P[2 + d] = acc[d];
    }
}

// ---------------------------------------------------------------- K7: epilogue — merge MHA, mscw2, LNs
__global__ __launch_bounds__(1024) void k_final(
        const float* __restrict__ queryb, const float* __restrict__ protos,
        const float* __restrict__ Z, const float* __restrict__ part,
        const float* __restrict__ cst,
        const float* __restrict__ b_out,
        const float* __restrict__ ln1_g, const float* __restrict__ ln1_b,
        const float* __restrict__ ln2_g, const float* __restrict__ ln2_b,
        const float* __restrict__ lb1, const float* __restrict__ lb2,
        const float* __restrict__ gb1, const float* __restrict__ gb2,
        float* __restrict__ out) {
    const float* gw1T = cst + 8960;
    const float* gw2T = cst + 13056;
    const float* lw1T = cst + 17152;
    const float* lw2T = cst + 21248;
    const float* woT  = cst + 25344;
    int b = blockIdx.x;
    int t = threadIdx.x >> 6;
    int c = threadIdx.x & 63;
    __shared__ float xs[16][64], hid[16][64], os[16][64];
    __shared__ float pool[64], hidg[64], glo[64];
    float q = queryb[(long)(b * 16 + t) * 64 + c];
    float rz = 1.f / Z[b * 16 + t];
    float xin = protos[(long)(b * 16 + t) * 64 + c] * rz + q;
    xs[t][c] = xin;
    {
        int hh = c >> 3, d = c & 7;
        const float* P = part + ((long)((b * 8 + hh) * 16 + t) * 8) * 12;
        float mm = -1e30f, ll = 0.f, aa = 0.f;
        #pragma unroll
        for (int s = 0; s < 8; s++) {
            float pm = P[s * 12], pl2 = P[s * 12 + 1], pa = P[s * 12 + 2 + d];
            float nm = fmaxf(mm, pm);
            float c1 = __expf(mm - nm), c2 = __expf(pm - nm);
            aa = aa * c1 + pa * c2;
            ll = ll * c1 + pl2 * c2;
            mm = nm;
        }
        os[t][c] = aa / ll;
    }
    __syncthreads();
    if (threadIdx.x < 64) {
        float s = 0.f;
        for (int tt = 0; tt < 16; tt++) s += xs[tt][threadIdx.x];
        pool[threadIdx.x] = s * (1.f / 16.f);
    }
    __syncthreads();
    if (threadIdx.x < 64) {
        int hh = threadIdx.x;
        float a = gb1[hh];
        for (int cc = 0; cc < 64; cc++) a += pool[cc] * gw1T[cc * 64 + hh];
        hidg[hh] = fmaxf(a, 0.f);
    }
    __syncthreads();
    if (threadIdx.x < 64) {
        int ccc = threadIdx.x;
        float a = gb2[ccc];
        for (int hh = 0; hh < 64; hh++) a += hidg[hh] * gw2T[hh * 64 + ccc];
        glo[ccc] = a;
    }
    float a = lb1[c];
    for (int cc = 0; cc < 64; cc++) a += xs[t][cc] * lw1T[cc * 64 + c];
    hid[t][c] = fmaxf(a, 0.f);
    __syncthreads();
    float loc = lb2[c];
    for (int hh = 0; hh < 64; hh++) loc += hid[t][hh] * lw2T[hh * 64 + c];
    float attn2 = sigmoidf_(loc + glo[c]);
    float x2p = q * attn2 + q;
    float mu = x2p;
    for (int off = 32; off; off >>= 1) mu += __shfl_down(mu, off);
    mu = __shfl(mu, 0) * (1.f / 64.f);
    float d0 = x2p - mu;
    float vv = d0 * d0;
    for (int off = 32; off; off >>= 1) vv += __shfl_down(vv, off);
    vv = __shfl(vv, 0) * (1.f / 64.f);
    float x2 = d0 * rsqrtf(vv + 1e-5f) * ln2_g[c] + ln2_b[c];
    float x1p = b_out[c];
    for (int k = 0; k < 64; k++) x1p += os[t][k] * woT[k * 64 + c];
    x1p += q;
    float mu1 = x1p;
    for (int off = 32; off; off >>= 1) mu1 += __shfl_down(mu1, off);
    mu1 = __shfl(mu1, 0) * (1.f / 64.f);
    float d1 = x1p - mu1;
    float v1 = d1 * d1;
    for (int off = 32; off; off >>= 1) v1 += __shfl_down(v1, off);
    v1 = __shfl(v1, 0) * (1.f / 64.f);
    float x1 = d1 * rsqrtf(v1 + 1e-5f) * ln1_g[c] + ln1_b[c];
    out[((long)t * 8 + b) * 64 + c] = x1 + x2;
}

// ----------------------------------------------------------------
extern "C" void kernel_launch(void* const* d_in, const int* in_sizes, int n_in,
                              void* d_out, int out_size, void* d_ws, size_t ws_size,
                              hipStream_t stream) {
    const float* tgt       = (const float*)d_in[0];
    const float* memory    = (const float*)d_in[1];
    const float* pos       = (const float*)d_in[2];
    const float* query_pos = (const float*)d_in[3];
    const float* w_in      = (const float*)d_in[4];
    const float* b_in      = (const float*)d_in[5];
    const float* w_out     = (const float*)d_in[6];
    const float* b_out     = (const float*)d_in[7];
    const float* ln1_g     = (const float*)d_in[8];
    const float* ln1_b     = (const float*)d_in[9];
    const float* ln2_g     = (const float*)d_in[10];
    const float* ln2_b     = (const float*)d_in[11];
    const float* dw_w      = (const float*)d_in[12];
    const float* bn1_g     = (const float*)d_in[13];
    const float* bn1_b     = (const float*)d_in[14];
    const float* bn1_m     = (const float*)d_in[15];
    const float* bn1_v     = (const float*)d_in[16];
    const float* pw_w      = (const float*)d_in[17];
    const float* bn2_g     = (const float*)d_in[18];
    const float* bn2_b     = (const float*)d_in[19];
    const float* bn2_m     = (const float*)d_in[20];
    const float* bn2_v     = (const float*)d_in[21];
    const float* mheads    = (const float*)d_in[22];
    const float* m1_lw1 = (const float*)d_in[23];
    const float* m1_lb1 = (const float*)d_in[24];
    const float* m1_lw2 = (const float*)d_in[25];
    const float* m1_lb2 = (const float*)d_in[26];
    const float* m1_gw1 = (const float*)d_in[27];
    const float* m1_gb1 = (const float*)d_in[28];
    const float* m1_gw2 = (const float*)d_in[29];
    const float* m1_gb2 = (const float*)d_in[30];
    const float* m2_lw1 = (const float*)d_in[31];
    const float* m2_lb1 = (const float*)d_in[32];
    const float* m2_lw2 = (const float*)d_in[33];
    const float* m2_lb2 = (const float*)d_in[34];
    const float* m2_gw1 = (const float*)d_in[35];
    const float* m2_gb1 = (const float*)d_in[36];
    const float* m2_gw2 = (const float*)d_in[37];
    const float* m2_gb2 = (const float*)d_in[38];

    float* ws = (float*)d_ws;
    float* out = (float*)d_out;
    unsigned short* keyb = (unsigned short*)(ws + OFF_KEY);
    unsigned short* kph  = (unsigned short*)(ws + OFF_KPH);
    unsigned short* vph  = (unsigned short*)(ws + OFF_VPH);
    unsigned short* wb   = (unsigned short*)(ws + OFF_WB);

    // zero atomic regions (pool + protos + Z, contiguous)
    hipMemsetAsync(ws + OFF_POOL, 0, 8832 * sizeof(float), stream);

    k_stage1<<<4327, 256, 0, stream>>>(memory, pos,
                                       m1_lw1, m1_lw2, w_in, pw_w, mheads, dw_w,
                                       bn1_g, bn1_b, bn1_m, bn1_v,
                                       bn2_g, bn2_b, bn2_m, bn2_v,
                                       m1_gw1, m1_gw2, m2_gw1, m2_gw2,
                                       m2_lw1, m2_lw2, w_out,
                                       tgt, query_pos, b_in,
                                       keyb, ws + OFF_POOL, wb, ws + OFF_CST,
                                       ws + OFF_QP, ws + OFF_QB);
    k_stage2<<<1536, 512, 0, stream>>>(keyb, ws + OFF_POOL,
                                       m1_lb1, m1_lb2, m1_gb1, m1_gb2, b_in,
                                       wb, ws + OFF_CST,
                                       kph, vph, ws + OFF_PROT, ws + OFF_ZZ);
    k_mha<<<512, 256, 0, stream>>>(ws + OFF_QP, kph, vph, ws + OFF_PART);
    k_final<<<8, 1024, 0, stream>>>(ws + OFF_QB, ws + OFF_PROT, ws + OFF_ZZ, ws + OFF_PART,
                                    ws + OFF_CST, b_out,
                                    ln1_g, ln1_b, ln2_g, ln2_b,
                                    m2_lb1, m2_lb2, m2_gb1, m2_gb2,
                                    out);
}

// Round 7
// 242.660 us; speedup vs baseline: 1.5472x; 1.0031x over previous
//
#include <hip/hip_runtime.h>
#include <math.h>

#define N1 16384
#define N2 4096

// Workspace layout (float offsets)
#define OFF_KEY   0L            // key bf16 [B][N1][8 oct swizzled][8] = 8,388,608 shorts
#define OFF_KPH   4194304L      // kp bf16 [B*H][4096][8]
#define OFF_VPH   5242880L
#define OFF_WB    6291456L      // bf16 weights (21504 shorts)
#define OFF_CST   6302208L      // fp32: dwTf[576],o1[64],s2[64],o2[64], then 7x4096 transposed mats
#define OFF_POOL  6331648L      // 512  (zeroed)
#define OFF_PROT  6332160L      // 8192 (zeroed)
#define OFF_ZZ    6340352L      // 128  (zeroed)
#define OFF_QP    6340480L
#define OFF_QB    6348672L
#define OFF_PART  6356864L      // [B*H][16 q][8 seg][12]

typedef __attribute__((ext_vector_type(8))) short bf16x8;
typedef __attribute__((ext_vector_type(4))) float floatx4;

#define MFMA16(a, b, c) __builtin_amdgcn_mfma_f32_16x16x32_bf16(a, b, c, 0, 0, 0)

__device__ __forceinline__ unsigned short f2bf(float f) {
    union { float f; unsigned u; } v; v.f = f;
    unsigned r = v.u + 0x7fffu + ((v.u >> 16) & 1u);
    return (unsigned short)(r >> 16);
}
__device__ __forceinline__ float bf2f(unsigned short s) {
    union { unsigned u; float f; } v; v.u = ((unsigned)s) << 16;
    return v.f;
}
__device__ __forceinline__ float sigmoidf_(float x) { return 1.f / (1.f + __expf(-x)); }
__device__ __forceinline__ bf16x8 ldg8b(const unsigned short* p) { return *(const bf16x8*)p; }
__device__ __forceinline__ void unpack8(uint4 v, float* f) {
    f[0] = bf2f((unsigned short)(v.x & 0xffff)); f[1] = bf2f((unsigned short)(v.x >> 16));
    f[2] = bf2f((unsigned short)(v.y & 0xffff)); f[3] = bf2f((unsigned short)(v.y >> 16));
    f[4] = bf2f((unsigned short)(v.z & 0xffff)); f[5] = bf2f((unsigned short)(v.z >> 16));
    f[6] = bf2f((unsigned short)(v.w & 0xffff)); f[7] = bf2f((unsigned short)(v.w >> 16));
}
// async global->LDS, 16B per lane; l must be wave-uniform, g per-lane
__device__ __forceinline__ void async16(const unsigned short* g, short* l) {
    __builtin_amdgcn_global_load_lds((const __attribute__((address_space(1))) unsigned int*)g,
                                     (__attribute__((address_space(3))) unsigned int*)l, 16, 0, 0);
}

// ---------------------------------------------------------------- stage1: key+pool (blocks 0..4095) | prep (4096..4326)
__global__ __launch_bounds__(256) void k_stage1(
        const float* __restrict__ mem, const float* __restrict__ pos,
        const float* __restrict__ m1lw1, const float* __restrict__ m1lw2,
        const float* __restrict__ w_in, const float* __restrict__ pw,
        const float* __restrict__ mh, const float* __restrict__ dw_w,
        const float* __restrict__ bn1_g, const float* __restrict__ bn1_b,
        const float* __restrict__ bn1_m, const float* __restrict__ bn1_v,
        const float* __restrict__ bn2_g, const float* __restrict__ bn2_b,
        const float* __restrict__ bn2_m, const float* __restrict__ bn2_v,
        const float* __restrict__ m1gw1, const float* __restrict__ m1gw2,
        const float* __restrict__ m2gw1, const float* __restrict__ m2gw2,
        const float* __restrict__ m2lw1, const float* __restrict__ m2lw2,
        const float* __restrict__ w_out,
        const float* __restrict__ tgt, const float* __restrict__ qpos,
        const float* __restrict__ b_in,
        unsigned short* __restrict__ key, float* __restrict__ pool1raw,
        unsigned short* __restrict__ wb, float* __restrict__ cst,
        float* __restrict__ qp, float* __restrict__ queryb) {
    int tid = threadIdx.x;
    if (blockIdx.x < 4096) {
        __shared__ float sh[16][64];
        int b = blockIdx.x >> 9;
        int n_base = (blockIdx.x & 511) * 32;
        int c8 = tid & 7, local_n = tid >> 3;
        int n = n_base + local_n;
        long s4 = ((long)n * 8 + b) * 16 + c8 * 2;
        float4 m0 = ((const float4*)mem)[s4], m1 = ((const float4*)mem)[s4 + 1];
        float4 p0 = ((const float4*)pos)[s4], p1 = ((const float4*)pos)[s4 + 1];
        float f[8];
        f[0] = m0.x + p0.x; f[1] = m0.y + p0.y; f[2] = m0.z + p0.z; f[3] = m0.w + p0.w;
        f[4] = m1.x + p1.x; f[5] = m1.y + p1.y; f[6] = m1.z + p1.z; f[7] = m1.w + p1.w;
        uint4 o;
        o.x = (unsigned)f2bf(f[0]) | ((unsigned)f2bf(f[1]) << 16);
        o.y = (unsigned)f2bf(f[2]) | ((unsigned)f2bf(f[3]) << 16);
        o.z = (unsigned)f2bf(f[4]) | ((unsigned)f2bf(f[5]) << 16);
        o.w = (unsigned)f2bf(f[6]) | ((unsigned)f2bf(f[7]) << 16);
        int c8s = c8 ^ ((local_n >> 1) & 7);   // octet swizzle
        ((uint4*)key)[(long)(b * 16384 + n) * 8 + c8s] = o;
        int parity = (n_base >> 7) & 1;
        if (parity) {
            if (local_n & 1) {
                #pragma unroll
                for (int j = 0; j < 8; j++) sh[local_n >> 1][c8 * 8 + j] = f[j];
            }
            __syncthreads();
            if (tid < 64) {
                float s = 0.f;
                #pragma unroll
                for (int k = 0; k < 16; k++) s += sh[k][tid];
                atomicAdd(pool1raw + b * 64 + tid, s);
            }
        }
        return;
    }
    int blk = blockIdx.x - 4096;
    if (blk < 84) {
        int i = blk * 256 + tid;
        float v;
        if (i < 4096) v = m1lw1[i];
        else if (i < 8192) v = m1lw2[i - 4096];
        else if (i < 16384) v = w_in[4096 + (i - 8192)];
        else if (i < 20480) v = pw[i - 16384];
        else v = mh[i - 20480];
        wb[i] = f2bf(v);
    } else if (blk < 199) {
        int j = (blk - 84) * 256 + tid;   // < 29440
        float v;
        if (j < 576) {
            int k = j >> 6, c = j & 63;
            float s1 = bn1_g[c] * rsqrtf(bn1_v[c] + 1e-5f);
            v = dw_w[c * 9 + k] * s1;
        } else if (j < 640) {
            int c = j - 576;
            float s1 = bn1_g[c] * rsqrtf(bn1_v[c] + 1e-5f);
            v = bn1_b[c] - bn1_m[c] * s1;
        } else if (j < 704) {
            int c = j - 640;
            v = bn2_g[c] * rsqrtf(bn2_v[c] + 1e-5f);
        } else if (j < 768) {
            int c = j - 704;
            float s2 = bn2_g[c] * rsqrtf(bn2_v[c] + 1e-5f);
            v = bn2_b[c] - bn2_m[c] * s2;
        } else {
            int jj = j - 768;
            int m = jj >> 12, idx = jj & 4095;
            int sidx = (idx & 63) * 64 + (idx >> 6);   // transpose
            const float* src;
            switch (m) {
                case 0: src = m1gw1; break;
                case 1: src = m1gw2; break;
                case 2: src = m2gw1; break;
                case 3: src = m2gw2; break;
                case 4: src = m2lw1; break;
                case 5: src = m2lw2; break;
                default: src = w_out; break;
            }
            v = src[sidx];
        }
        cst[j] = v;
    } else {
        __shared__ float qv[4][64];
        int g = tid >> 6, lane = tid & 63;
        int u = (blk - 199) * 4 + g;
        int b = u >> 4, q = u & 15;
        long src = ((long)q * 8 + b) * 64 + lane;
        float v = tgt[src] + qpos[src];
        qv[g][lane] = v;
        queryb[(b * 16 + q) * 64 + lane] = v;
        __syncthreads();
        float acc = b_in[lane];
        for (int cc = 0; cc < 64; cc++) acc += qv[g][cc] * w_in[lane * 64 + cc];
        qp[(b * 16 + q) * 64 + lane] = acc;
    }
}

// ---------------------------------------------------------------- stage2: mscw1 (blocks 0..511) | dsconv (512..1535)
// smem layout (bytes):
//  mscw1:  stage [0,32768) | hbuf [32768,41984) | wbuf [41984,51200) | parr/gtmp/gbuf [51200,51968)
//  dsconv: stage [0,49152) 3 rows x 16384 | y2buf=r0 [0,16384) | pbuf [16384,20736)
//          KT [32768,50176) | cbuf [50176,53248) | zred [53248,53760)
__global__ __launch_bounds__(512) void k_stage2(
        const unsigned short* __restrict__ keyb,
        const float* __restrict__ pool1raw,
        const float* __restrict__ lb1, const float* __restrict__ lb2,
        const float* __restrict__ gb1, const float* __restrict__ gb2,
        const float* __restrict__ b_in,
        const unsigned short* __restrict__ wb,
        const float* __restrict__ cst,
        unsigned short* __restrict__ kph, unsigned short* __restrict__ vph,
        float* __restrict__ protos, float* __restrict__ Z) {
    __shared__ __align__(16) char smem[53760];
    int tid = threadIdx.x;
    int w = tid >> 6, l = tid & 63;
    if (blockIdx.x < 512) {
        // ---------------- mscw1
        short* stage = (short*)smem;
        short* hbuf  = (short*)(smem + 32768);
        short* wbuf  = (short*)(smem + 41984);
        float* parr  = (float*)(smem + 51200);
        float* gtmp  = parr + 64;
        float* gbuf  = parr + 128;
        int b = blockIdx.x >> 6, tile = blockIdx.x & 63;
        int pairw = w >> 1, ch2 = w & 1;
        int m0 = pairw * 16, trow = l & 15, oct = l >> 4;
        const float* gw1T = cst + 768;
        const float* gw2T = cst + 4864;
        // async stage: 32 KB dense = 32 chunks of 1 KB; 8 waves x 4
        const unsigned short* src = keyb + ((long)b * 16384 + tile * 256) * 64;
        #pragma unroll
        for (int it = 0; it < 4; it++) {
            int chunk = w * 4 + it;
            async16(src + chunk * 512 + l * 8, stage + chunk * 512);
        }
        if (tid < 64) parr[tid] = pool1raw[b * 64 + tid] * (2.0f / 4096.0f);
        __syncthreads();   // sync1 (drains async loads)
        if (tid < 64) {
            float a = gb1[tid];
            for (int cc = 0; cc < 64; cc++) a += parr[cc] * gw1T[cc * 64 + tid];
            gtmp[tid] = fmaxf(a, 0.f);
        }
        int j = m0 + trow;
        int sw = j & 7;
        float x[16], S[16];
        bf16x8 ax[2];
        #pragma unroll
        for (int half = 0; half < 2; half++) {
            int oo = ((oct + half * 4) ^ sw) * 8;
            uint4 fa4 = *(const uint4*)(stage + (2 * j) * 64 + oo);
            uint4 fb4 = *(const uint4*)(stage + (2 * j + 1) * 64 + oo);
            uint4 fc4 = *(const uint4*)(stage + (128 + 2 * j) * 64 + oo);
            uint4 fd4 = *(const uint4*)(stage + (129 + 2 * j) * 64 + oo);
            float A[8], B[8], C[8], D[8];
            unpack8(fa4, A); unpack8(fb4, B); unpack8(fc4, C); unpack8(fd4, D);
            #pragma unroll
            for (int jj = 0; jj < 8; jj++) {
                float xd = 2.f * D[jj];
                x[half * 8 + jj] = xd;
                S[half * 8 + jj] = 0.5f * (A[jj] + B[jj] + C[jj] + D[jj]);
                ax[half][jj] = (short)f2bf(xd);
            }
        }
        const unsigned short* w1b = wb;
        const unsigned short* w2b = wb + 4096;
        const unsigned short* wkb = wb + 8192;
        const unsigned short* wvb = wb + 12288;
        // G1: hid = relu(x @ w1^T + b1), col tiles split by ch2
        #pragma unroll
        for (int t4i = 0; t4i < 2; t4i++) {
            int n = (ch2 * 2 + t4i) * 16 + trow;
            float bias = lb1[n];
            floatx4 acc = {bias, bias, bias, bias};
            acc = MFMA16(ax[0], ldg8b(w1b + n * 64 + oct * 8), acc);
            acc = MFMA16(ax[1], ldg8b(w1b + n * 64 + 32 + oct * 8), acc);
            #pragma unroll
            for (int r = 0; r < 4; r++)
                hbuf[(m0 + oct * 4 + r) * 72 + n] = (short)f2bf(fmaxf(acc[r], 0.f));
        }
        __syncthreads();   // sync2
        if (tid < 64) {
            float g = gb2[tid];
            for (int hh = 0; hh < 64; hh++) g += gtmp[hh] * gw2T[hh * 64 + tid];
            gbuf[tid] = g;
        }
        __syncthreads();   // sync2b
        // G2: wei = sigmoid(hid @ w2^T + b2 + glo)
        {
            bf16x8 ah0 = *(const bf16x8*)(hbuf + (m0 + trow) * 72 + oct * 8);
            bf16x8 ah1 = *(const bf16x8*)(hbuf + (m0 + trow) * 72 + 32 + oct * 8);
            #pragma unroll
            for (int t4i = 0; t4i < 2; t4i++) {
                int n = (ch2 * 2 + t4i) * 16 + trow;
                float bias = lb2[n];
                floatx4 acc = {bias, bias, bias, bias};
                acc = MFMA16(ah0, ldg8b(w2b + n * 64 + oct * 8), acc);
                acc = MFMA16(ah1, ldg8b(w2b + n * 64 + 32 + oct * 8), acc);
                float g = gbuf[n];
                #pragma unroll
                for (int r = 0; r < 4; r++)
                    wbuf[(m0 + oct * 4 + r) * 72 + n] = (short)f2bf(sigmoidf_(acc[r] + g));
            }
        }
        __syncthreads();   // sync3
        bf16x8 af0, af1;
        {
            bf16x8 w0 = *(const bf16x8*)(wbuf + (m0 + trow) * 72 + oct * 8);
            bf16x8 w1v = *(const bf16x8*)(wbuf + (m0 + trow) * 72 + 32 + oct * 8);
            #pragma unroll
            for (int jj = 0; jj < 8; jj++) {
                float we0 = bf2f((unsigned short)w0[jj]);
                float we1 = bf2f((unsigned short)w1v[jj]);
                af0[jj] = (short)f2bf(we0 * x[jj] + (1.f - we0) * S[jj]);
                af1[jj] = (short)f2bf(we1 * x[8 + jj] + (1.f - we1) * S[8 + jj]);
            }
        }
        __syncthreads();   // sync4: reuse hbuf/wbuf as kbuf/vbuf
        short* kbuf = hbuf; short* vbuf = wbuf;
        #pragma unroll
        for (int t4i = 0; t4i < 2; t4i++) {
            int ko = (ch2 * 2 + t4i) * 16 + trow;
            float bk = b_in[64 + ko], bv = b_in[128 + ko];
            floatx4 ak = {bk, bk, bk, bk};
            floatx4 av = {bv, bv, bv, bv};
            ak = MFMA16(af0, ldg8b(wkb + ko * 64 + oct * 8), ak);
            ak = MFMA16(af1, ldg8b(wkb + ko * 64 + 32 + oct * 8), ak);
            av = MFMA16(af0, ldg8b(wvb + ko * 64 + oct * 8), av);
            av = MFMA16(af1, ldg8b(wvb + ko * 64 + 32 + oct * 8), av);
            #pragma unroll
            for (int r = 0; r < 4; r++) {
                int row = m0 + oct * 4 + r;
                kbuf[row * 72 + ko] = (short)f2bf(ak[r]);
                vbuf[row * 72 + ko] = (short)f2bf(av[r]);
            }
        }
        __syncthreads();   // sync5
        {
            int h = tid >> 6, tok = tid & 63;
            uint4 kk = *(const uint4*)(kbuf + tok * 72 + h * 8);
            uint4 vv = *(const uint4*)(vbuf + tok * 72 + h * 8);
            long du = (long)(b * 8 + h) * 4096 + tile * 64 + tok;
            ((uint4*)kph)[du] = kk;
            ((uint4*)vph)[du] = vv;
        }
        return;
    }
    // ---------------- dsconv
    {
        short* stage = (short*)smem;                       // 3 rows x 8192 shorts, dense swizzled
        short* y2buf = (short*)smem;                       // aliases r0 after conv
        short* pbuf  = (short*)(smem + 16384);             // aliases r1 after transpose
        short* KT    = (short*)(smem + 32768);             // 64 x 136 shorts
        float* cbuf  = (float*)(smem + 50176);             // 768
        float* zred  = (float*)(smem + 53248);             // [8][16]
        int blk = blockIdx.x - 512;
        int b = blk >> 7, h = blk & 127;
        int p0 = w * 16, pr = l & 15, oct = l >> 4;
        const unsigned short* kb = keyb + (long)b * 1048576;
        // stage rows h-1..h+1 async; zero-fill boundaries
        #pragma unroll
        for (int r = 0; r < 3; r++) {
            int row = h - 1 + r;
            if ((unsigned)row < 128u) {
                const unsigned short* srcRow = kb + (long)row * 8192;
                short* dstRow = stage + r * 8192;
                #pragma unroll
                for (int it = 0; it < 2; it++) {
                    int chunk = w * 2 + it;
                    async16(srcRow + chunk * 512 + l * 8, dstRow + chunk * 512);
                }
            } else {
                uint4 zz = {0u, 0u, 0u, 0u};
                #pragma unroll
                for (int it = 0; it < 2; it++) {
                    int u = it * 512 + tid;
                    *(uint4*)(stage + r * 8192 + u * 8) = zz;
                }
            }
        }
        for (int k = tid; k < 768; k += 512) cbuf[k] = cst[k];
        __syncthreads();   // drains async loads
        // dw conv 3x3 from LDS (dense swizzled)
        float accf[2][8];
        #pragma unroll
        for (int half = 0; half < 2; half++)
            #pragma unroll
            for (int jj = 0; jj < 8; jj++) accf[half][jj] = 0.f;
        #pragma unroll
        for (int kk = 0; kk < 3; kk++) {
            int col = p0 + pr - 1 + kk;
            if ((unsigned)col < 128u) {
                int sw = (col >> 1) & 7;
                #pragma unroll
                for (int r = 0; r < 3; r++) {
                    #pragma unroll
                    for (int half = 0; half < 2; half++) {
                        int o = oct + half * 4;
                        uint4 d4 = *(const uint4*)(stage + r * 8192 + col * 64 + ((o ^ sw) * 8));
                        float f[8]; unpack8(d4, f);
                        float4 wa = *(const float4*)(cbuf + (r * 3 + kk) * 64 + o * 8);
                        float4 wc = *(const float4*)(cbuf + (r * 3 + kk) * 64 + o * 8 + 4);
                        accf[half][0] += f[0] * wa.x; accf[half][1] += f[1] * wa.y;
                        accf[half][2] += f[2] * wa.z; accf[half][3] += f[3] * wa.w;
                        accf[half][4] += f[4] * wc.x; accf[half][5] += f[5] * wc.y;
                        accf[half][6] += f[6] * wc.z; accf[half][7] += f[7] * wc.w;
                    }
                }
            }
        }
        bf16x8 af[2];
        #pragma unroll
        for (int half = 0; half < 2; half++) {
            int o = oct + half * 4;
            float4 oa = *(const float4*)(cbuf + 576 + o * 8);
            float4 ob = *(const float4*)(cbuf + 576 + o * 8 + 4);
            af[half][0] = (short)f2bf(fmaxf(accf[half][0] + oa.x, 0.f));
            af[half][1] = (short)f2bf(fmaxf(accf[half][1] + oa.y, 0.f));
            af[half][2] = (short)f2bf(fmaxf(accf[half][2] + oa.z, 0.f));
            af[half][3] = (short)f2bf(fmaxf(accf[half][3] + oa.w, 0.f));
            af[half][4] = (short)f2bf(fmaxf(accf[half][4] + ob.x, 0.f));
            af[half][5] = (short)f2bf(fmaxf(accf[half][5] + ob.y, 0.f));
            af[half][6] = (short)f2bf(fmaxf(accf[half][6] + ob.z, 0.f));
            af[half][7] = (short)f2bf(fmaxf(accf[half][7] + ob.w, 0.f));
        }
        __syncthreads();   // conv reads done
        // phase 3: pw GEMM -> y2buf (r0, dense swizzled); transpose center row -> KT
        {
            const unsigned short* pwb = wb + 16384;
            #pragma unroll
            for (int t4 = 0; t4 < 4; t4++) {
                int n = t4 * 16 + pr;
                floatx4 acc = {0.f, 0.f, 0.f, 0.f};
                acc = MFMA16(af[0], ldg8b(pwb + n * 64 + oct * 8), acc);
                acc = MFMA16(af[1], ldg8b(pwb + n * 64 + 32 + oct * 8), acc);
                float s2 = cbuf[640 + n], o2 = cbuf[704 + n];
                int nh = n >> 3, nl = n & 7;
                #pragma unroll
                for (int r = 0; r < 4; r++) {
                    int p = p0 + oct * 4 + r;
                    y2buf[p * 64 + ((nh ^ ((p >> 1) & 7)) * 8) + nl] =
                        (short)f2bf(fmaxf(acc[r] * s2 + o2, 0.f));
                }
            }
            // transpose center row (r1) -> KT[c][n ^ ((c>>3)<<3)]
            #pragma unroll
            for (int k2 = 0; k2 < 2; k2++) {
                int u = k2 * 512 + tid;          // 1024 (col, o)
                int col = u >> 3, o = u & 7;
                int sw = (col >> 1) & 7;
                uint4 v = *(const uint4*)(stage + 8192 + col * 64 + ((o ^ sw) * 8));
                int nx = col ^ (o << 3);
                KT[(o * 8 + 0) * 136 + nx] = (short)(v.x & 0xffff);
                KT[(o * 8 + 1) * 136 + nx] = (short)(v.x >> 16);
                KT[(o * 8 + 2) * 136 + nx] = (short)(v.y & 0xffff);
                KT[(o * 8 + 3) * 136 + nx] = (short)(v.y >> 16);
                KT[(o * 8 + 4) * 136 + nx] = (short)(v.z & 0xffff);
                KT[(o * 8 + 5) * 136 + nx] = (short)(v.z >> 16);
                KT[(o * 8 + 6) * 136 + nx] = (short)(v.w & 0xffff);
                KT[(o * 8 + 7) * 136 + nx] = (short)(v.w >> 16);
            }
        }
        __syncthreads();
        // phase 4: mask head + exp -> pbuf + zred
        {
            const unsigned short* mhb = wb + 20480;
            int p = p0 + pr, sw = (p >> 1) & 7;
            bf16x8 a0 = *(const bf16x8*)(y2buf + p * 64 + ((oct ^ sw) * 8));
            bf16x8 a1 = *(const bf16x8*)(y2buf + p * 64 + (((oct + 4) ^ sw) * 8));
            floatx4 lg = {0.f, 0.f, 0.f, 0.f};
            lg = MFMA16(a0, ldg8b(mhb + pr * 64 + oct * 8), lg);
            lg = MFMA16(a1, ldg8b(mhb + pr * 64 + 32 + oct * 8), lg);
            float zs = 0.f;
            #pragma unroll
            for (int r = 0; r < 4; r++) {
                float e = __expf(lg[r]);
                zs += e;
                pbuf[pr * 136 + p0 + oct * 4 + r] = (short)f2bf(e);
            }
            zs += __shfl_xor(zs, 16);
            zs += __shfl_xor(zs, 32);
            if (l < 16) zred[w * 16 + l] = zs;
        }
        __syncthreads();
        // phase 5: protos partial (waves 0-3) + Z atomic
        if (w < 4) {
            int c = w * 16 + pr;
            int xrc = ((c >> 3) & 7) << 3;
            floatx4 acc = {0.f, 0.f, 0.f, 0.f};
            #pragma unroll
            for (int s = 0; s < 4; s++) {
                bf16x8 A = *(const bf16x8*)(pbuf + pr * 136 + s * 32 + oct * 8);
                bf16x8 B = *(const bf16x8*)(KT + c * 136 + ((s * 32 + oct * 8) ^ xrc));
                acc = MFMA16(A, B, acc);
            }
            #pragma unroll
            for (int r = 0; r < 4; r++)
                atomicAdd(protos + (b * 16 + oct * 4 + r) * 64 + c, acc[r]);
        }
        if (tid < 16) {
            float zt = 0.f;
            #pragma unroll
            for (int ww = 0; ww < 8; ww++) zt += zred[ww * 16 + tid];
            atomicAdd(Z + b * 16 + tid, zt);
        }
    }
}

// ---------------------------------------------------------------- K6: MHA partials, no-max softmax (bounded logits)
__global__ __launch_bounds__(256) void k_mha(const float* __restrict__ qp,
                                             const unsigned short* __restrict__ kph,
                                             const unsigned short* __restrict__ vph,
                                             float* __restrict__ part) {
    int bh = blockIdx.x >> 3, seg = blockIdx.x & 7;
    int b = bh >> 3, hh = bh & 7;
    int tid = threadIdx.x;
    int q = tid >> 4, sub = tid & 15;
    const float* qv = qp + (long)(b * 16 + q) * 64 + hh * 8;
    float4 q0 = ((const float4*)qv)[0];
    float4 q1 = ((const float4*)qv)[1];
    const uint4* K4 = (const uint4*)kph + (long)bh * 4096;
    const uint4* V4 = (const uint4*)vph + (long)bh * 4096;
    const float scale = 0.35355339059327373f;
    float lsum = 0.f;
    float acc[8];
    #pragma unroll
    for (int d = 0; d < 8; d++) acc[d] = 0.f;
    for (int i = 0; i < 32; i++) {
        int n = seg * 512 + i * 16 + sub;
        float k8[8]; unpack8(K4[n], k8);
        float s = q0.x * k8[0] + q0.y * k8[1] + q0.z * k8[2] + q0.w * k8[3]
                + q1.x * k8[4] + q1.y * k8[5] + q1.z * k8[6] + q1.w * k8[7];
        float e = __expf(s * scale);
        lsum += e;
        float v8[8]; unpack8(V4[n], v8);
        #pragma unroll
        for (int d = 0; d < 8; d++) acc[d] += e * v8[d];
    }
    #pragma unroll
    for (int off = 1; off < 16; off <<= 1) {
        lsum += __shfl_xor(lsum, off);
        #pragma unroll
        for (int d = 0; d < 8; d++) acc[d] += __shfl_xor(acc[d], off);
    }
    if (sub == 0) {
        float* P = part + ((long)(bh * 16 + q) * 8 + seg) * 12;
        P[0] = lsum;
        #pragma unroll
        for (int d = 0; d < 8; d++) P[1 + d] = acc[d];
    }
}

// ---------------------------------------------------------------- K7: epilogue — merge MHA, mscw2, LNs
__global__ __launch_bounds__(1024) void k_final(
        const float* __restrict__ queryb, const float* __restrict__ protos,
        const float* __restrict__ Z, const float* __restrict__ part,
        const float* __restrict__ cst,
        const float* __restrict__ b_out,
        const float* __restrict__ ln1_g, const float* __restrict__ ln1_b,
        const float* __restrict__ ln2_g, const float* __restrict__ ln2_b,
        const float* __restrict__ lb1, const float* __restrict__ lb2,
        const float* __restrict__ gb1, const float* __restrict__ gb2,
        float* __restrict__ out) {
    const float* gw1T = cst + 8960;
    const float* gw2T = cst + 13056;
    const float* lw1T = cst + 17152;
    const float* lw2T = cst + 21248;
    const float* woT  = cst + 25344;
    int b = blockIdx.x;
    int t = threadIdx.x >> 6;
    int c = threadIdx.x & 63;
    __shared__ float xs[16][64], hid[16][64], os[16][64];
    __shared__ float pool[64], hidg[64], glo[64];
    float q = queryb[(long)(b * 16 + t) * 64 + c];
    float rz = 1.f / Z[b * 16 + t];
    float xin = protos[(long)(b * 16 + t) * 64 + c] * rz + q;
    xs[t][c] = xin;
    {
        int hh = c >> 3, d = c & 7;
        const float* P = part + ((long)((b * 8 + hh) * 16 + t) * 8) * 12;
        float ll = 0.f, aa = 0.f;
        #pragma unroll
        for (int s = 0; s < 8; s++) {
            ll += P[s * 12];
            aa += P[s * 12 + 1 + d];
        }
        os[t][c] = aa / ll;
    }
    __syncthreads();
    if (threadIdx.x < 64) {
        float s = 0.f;
        for (int tt = 0; tt < 16; tt++) s += xs[tt][threadIdx.x];
        pool[threadIdx.x] = s * (1.f / 16.f);
    }
    __syncthreads();
    if (threadIdx.x < 64) {
        int hh = threadIdx.x;
        float a = gb1[hh];
        for (int cc = 0; cc < 64; cc++) a += pool[cc] * gw1T[cc * 64 + hh];
        hidg[hh] = fmaxf(a, 0.f);
    }
    __syncthreads();
    if (threadIdx.x < 64) {
        int ccc = threadIdx.x;
        float a = gb2[ccc];
        for (int hh = 0; hh < 64; hh++) a += hidg[hh] * gw2T[hh * 64 + ccc];
        glo[ccc] = a;
    }
    float a = lb1[c];
    for (int cc = 0; cc < 64; cc++) a += xs[t][cc] * lw1T[cc * 64 + c];
    hid[t][c] = fmaxf(a, 0.f);
    __syncthreads();
    float loc = lb2[c];
    for (int hh = 0; hh < 64; hh++) loc += hid[t][hh] * lw2T[hh * 64 + c];
    float attn2 = sigmoidf_(loc + glo[c]);
    float x2p = q * attn2 + q;
    float mu = x2p;
    for (int off = 32; off; off >>= 1) mu += __shfl_down(mu, off);
    mu = __shfl(mu, 0) * (1.f / 64.f);
    float d0 = x2p - mu;
    float vv = d0 * d0;
    for (int off = 32; off; off >>= 1) vv += __shfl_down(vv, off);
    vv = __shfl(vv, 0) * (1.f / 64.f);
    float x2 = d0 * rsqrtf(vv + 1e-5f) * ln2_g[c] + ln2_b[c];
    float x1p = b_out[c];
    for (int k = 0; k < 64; k++) x1p += os[t][k] * woT[k * 64 + c];
    x1p += q;
    float mu1 = x1p;
    for (int off = 32; off; off >>= 1) mu1 += __shfl_down(mu1, off);
    mu1 = __shfl(mu1, 0) * (1.f / 64.f);
    float d1 = x1p - mu1;
    float v1 = d1 * d1;
    for (int off = 32; off; off >>= 1) v1 += __shfl_down(v1, off);
    v1 = __shfl(v1, 0) * (1.f / 64.f);
    float x1 = d1 * rsqrtf(v1 + 1e-5f) * ln1_g[c] + ln1_b[c];
    out[((long)t * 8 + b) * 64 + c] = x1 + x2;
}

// ----------------------------------------------------------------
extern "C" void kernel_launch(void* const* d_in, const int* in_sizes, int n_in,
                              void* d_out, int out_size, void* d_ws, size_t ws_size,
                              hipStream_t stream) {
    const float* tgt       = (const float*)d_in[0];
    const float* memory    = (const float*)d_in[1];
    const float* pos       = (const float*)d_in[2];
    const float* query_pos = (const float*)d_in[3];
    const float* w_in      = (const float*)d_in[4];
    const float* b_in      = (const float*)d_in[5];
    const float* w_out     = (const float*)d_in[6];
    const float* b_out     = (const float*)d_in[7];
    const float* ln1_g     = (const float*)d_in[8];
    const float* ln1_b     = (const float*)d_in[9];
    const float* ln2_g     = (const float*)d_in[10];
    const float* ln2_b     = (const float*)d_in[11];
    const float* dw_w      = (const float*)d_in[12];
    const float* bn1_g     = (const float*)d_in[13];
    const float* bn1_b     = (const float*)d_in[14];
    const float* bn1_m     = (const float*)d_in[15];
    const float* bn1_v     = (const float*)d_in[16];
    const float* pw_w      = (const float*)d_in[17];
    const float* bn2_g     = (const float*)d_in[18];
    const float* bn2_b     = (const float*)d_in[19];
    const float* bn2_m     = (const float*)d_in[20];
    const float* bn2_v     = (const float*)d_in[21];
    const float* mheads    = (const float*)d_in[22];
    const float* m1_lw1 = (const float*)d_in[23];
    const float* m1_lb1 = (const float*)d_in[24];
    const float* m1_lw2 = (const float*)d_in[25];
    const float* m1_lb2 = (const float*)d_in[26];
    const float* m1_gw1 = (const float*)d_in[27];
    const float* m1_gb1 = (const float*)d_in[28];
    const float* m1_gw2 = (const float*)d_in[29];
    const float* m1_gb2 = (const float*)d_in[30];
    const float* m2_lw1 = (const float*)d_in[31];
    const float* m2_lb1 = (const float*)d_in[32];
    const float* m2_lw2 = (const float*)d_in[33];
    const float* m2_lb2 = (const float*)d_in[34];
    const float* m2_gw1 = (const float*)d_in[35];
    const float* m2_gb1 = (const float*)d_in[36];
    const float* m2_gw2 = (const float*)d_in[37];
    const float* m2_gb2 = (const float*)d_in[38];

    float* ws = (float*)d_ws;
    float* out = (float*)d_out;
    unsigned short* keyb = (unsigned short*)(ws + OFF_KEY);
    unsigned short* kph  = (unsigned short*)(ws + OFF_KPH);
    unsigned short* vph  = (unsigned short*)(ws + OFF_VPH);
    unsigned short* wb   = (unsigned short*)(ws + OFF_WB);

    // zero atomic regions (pool + protos + Z, contiguous)
    hipMemsetAsync(ws + OFF_POOL, 0, 8832 * sizeof(float), stream);

    k_stage1<<<4327, 256, 0, stream>>>(memory, pos,
                                       m1_lw1, m1_lw2, w_in, pw_w, mheads, dw_w,
                                       bn1_g, bn1_b, bn1_m, bn1_v,
                                       bn2_g, bn2_b, bn2_m, bn2_v,
                                       m1_gw1, m1_gw2, m2_gw1, m2_gw2,
                                       m2_lw1, m2_lw2, w_out,
                                       tgt, query_pos, b_in,
                                       keyb, ws + OFF_POOL, wb, ws + OFF_CST,
                                       ws + OFF_QP, ws + OFF_QB);
    k_stage2<<<1536, 512, 0, stream>>>(keyb, ws + OFF_POOL,
                                       m1_lb1, m1_lb2, m1_gb1, m1_gb2, b_in,
                                       wb, ws + OFF_CST,
                                       kph, vph, ws + OFF_PROT, ws + OFF_ZZ);
    k_mha<<<512, 256, 0, stream>>>(ws + OFF_QP, kph, vph, ws + OFF_PART);
    k_final<<<8, 1024, 0, stream>>>(ws + OFF_QB, ws + OFF_PROT, ws + OFF_ZZ, ws + OFF_PART,
                                    ws + OFF_CST, b_out,
                                    ln1_g, ln1_b, ln2_g, ln2_b,
                                    m2_lb1, m2_lb2, m2_gb1, m2_gb2,
                                    out);
}